// Round 2
// baseline (584.256 us; speedup 1.0000x reference)
//
#include <hip/hip_runtime.h>
#include <stdint.h>

#define BS 2048   // B*S
#define E_ 512
#define NH 8
#define HD 64
#define TMAX 20

typedef unsigned long long u64;

// ---------------------------------------------------------------------------
// f32 tiled GEMM: C[M,N] = A[M,K] @ W[K,N] (+bias). BM=128 BN=64 BK=16,
// 256 threads, 8x4 micro-tile. All dims divide exactly for this problem.
// ---------------------------------------------------------------------------
__device__ __forceinline__ void gemm_body(const float* __restrict__ A,
    const float* __restrict__ W, const float* __restrict__ bias,
    float* __restrict__ C, int M, int N, int K)
{
    __shared__ __align__(16) float As[16][132];   // transposed A tile, padded
    __shared__ __align__(16) float Bs[16][64];
    int tid = threadIdx.x;
    int m0 = blockIdx.y * 128;
    int n0 = blockIdx.x * 64;
    int ty = tid >> 4, tx = tid & 15;
    float acc[8][4];
#pragma unroll
    for (int r = 0; r < 8; ++r)
#pragma unroll
        for (int c = 0; c < 4; ++c) acc[r][c] = 0.f;

    int arow = tid >> 2;       // 0..63
    int acol4 = tid & 3;       // 0..3
    int brow = tid >> 4;       // 0..15
    int bcol4 = tid & 15;

    for (int k0 = 0; k0 < K; k0 += 16) {
#pragma unroll
        for (int rr = 0; rr < 2; ++rr) {
            int r = arow + rr * 64;
            float4 va = *(const float4*)(&A[(size_t)(m0 + r) * K + k0 + acol4 * 4]);
            As[acol4 * 4 + 0][r] = va.x;
            As[acol4 * 4 + 1][r] = va.y;
            As[acol4 * 4 + 2][r] = va.z;
            As[acol4 * 4 + 3][r] = va.w;
        }
        float4 vb = *(const float4*)(&W[(size_t)(k0 + brow) * N + n0 + bcol4 * 4]);
        *(float4*)(&Bs[brow][bcol4 * 4]) = vb;
        __syncthreads();
#pragma unroll
        for (int kk = 0; kk < 16; ++kk) {
            float4 a0 = *(const float4*)(&As[kk][ty * 8]);
            float4 a1 = *(const float4*)(&As[kk][ty * 8 + 4]);
            float4 b4 = *(const float4*)(&Bs[kk][tx * 4]);
            float ar[8] = {a0.x, a0.y, a0.z, a0.w, a1.x, a1.y, a1.z, a1.w};
            float br[4] = {b4.x, b4.y, b4.z, b4.w};
#pragma unroll
            for (int r = 0; r < 8; ++r)
#pragma unroll
                for (int c = 0; c < 4; ++c)
                    acc[r][c] = fmaf(ar[r], br[c], acc[r][c]);
        }
        __syncthreads();
    }
#pragma unroll
    for (int r = 0; r < 8; ++r) {
        int row = m0 + ty * 8 + r;
        float4 o;
        o.x = acc[r][0]; o.y = acc[r][1]; o.z = acc[r][2]; o.w = acc[r][3];
        if (bias) {
            o.x += bias[n0 + tx * 4 + 0];
            o.y += bias[n0 + tx * 4 + 1];
            o.z += bias[n0 + tx * 4 + 2];
            o.w += bias[n0 + tx * 4 + 3];
        }
        *(float4*)(&C[(size_t)row * N + n0 + tx * 4]) = o;
    }
}

__global__ __launch_bounds__(256) void gemm_qkv_kernel(const float* __restrict__ x,
    const float* __restrict__ Wq, const float* __restrict__ Wk, const float* __restrict__ Wv,
    float* __restrict__ q, float* __restrict__ k, float* __restrict__ v)
{
    int z = blockIdx.z;
    const float* W = (z == 0) ? Wq : (z == 1) ? Wk : Wv;
    float* C = (z == 0) ? q : (z == 1) ? k : v;
    gemm_body(x, W, nullptr, C, BS, E_, E_);
}

__global__ __launch_bounds__(256) void gemm_out_kernel(const float* __restrict__ ctx,
    const float* __restrict__ Wo, const float* __restrict__ bo, float* __restrict__ out)
{
    gemm_body(ctx, Wo, bo, out, BS, E_, E_);
}

// ---------------------------------------------------------------------------
// Gate/complexity MLPs -> T_i. 16 tokens per 256-thread block.
// ---------------------------------------------------------------------------
__global__ __launch_bounds__(256) void mlp_gate_kernel(const float* __restrict__ x,
    const float* __restrict__ g1, const float* __restrict__ gb1,
    const float* __restrict__ g2, const float* __restrict__ gb2,
    const float* __restrict__ g3, const float* __restrict__ gb3,
    const float* __restrict__ c1, const float* __restrict__ cb1,
    const float* __restrict__ c2, const float* __restrict__ cb2,
    int* __restrict__ Ti)
{
    __shared__ __align__(16) float xsh[16][512];
    __shared__ float h1sh[16][64];
    __shared__ float h2sh[16][32];
    __shared__ float gsh[16];
    int tid = threadIdx.x;
    int tok0 = blockIdx.x * 16;

    const float4* xg = (const float4*)(&x[(size_t)tok0 * 512]);
    float4* xs4 = (float4*)(&xsh[0][0]);
    for (int i = tid; i < 16 * 128; i += 256) xs4[i] = xg[i];
    __syncthreads();

    {   // h1 = relu(x@g1+gb1): lane l = output ch, wave handles 4 tokens
        int l = tid & 63, tg = tid >> 6;
        float a0 = gb1[l], a1 = a0, a2 = a0, a3 = a0;
#pragma unroll 8
        for (int e = 0; e < 512; ++e) {
            float w = g1[e * 64 + l];
            a0 = fmaf(xsh[tg][e], w, a0);
            a1 = fmaf(xsh[tg + 4][e], w, a1);
            a2 = fmaf(xsh[tg + 8][e], w, a2);
            a3 = fmaf(xsh[tg + 12][e], w, a3);
        }
        h1sh[tg][l] = fmaxf(a0, 0.f);
        h1sh[tg + 4][l] = fmaxf(a1, 0.f);
        h1sh[tg + 8][l] = fmaxf(a2, 0.f);
        h1sh[tg + 12][l] = fmaxf(a3, 0.f);
    }
    __syncthreads();
    {   // h2 = relu(h1@g2+gb2)
        int m = tid & 31, tg = tid >> 5;
#pragma unroll
        for (int tt = 0; tt < 2; ++tt) {
            int tok = tg + tt * 8;
            float a = gb2[m];
#pragma unroll 8
            for (int l = 0; l < 64; ++l) a = fmaf(h1sh[tok][l], g2[l * 32 + m], a);
            h2sh[tok][m] = fmaxf(a, 0.f);
        }
    }
    __syncthreads();
    if (tid < 16) {
        float a = gb3[0];
#pragma unroll 8
        for (int m = 0; m < 32; ++m) a = fmaf(h2sh[tid][m], g3[m], a);
        gsh[tid] = 1.f / (1.f + expf(-a));
    }
    __syncthreads();
    {   // comp hidden = relu(x@c1+cb1)  (reuse h2sh)
        int m = tid & 31, tg = tid >> 5;
#pragma unroll
        for (int tt = 0; tt < 2; ++tt) {
            int tok = tg + tt * 8;
            float a = cb1[m];
#pragma unroll 8
            for (int e = 0; e < 512; ++e) a = fmaf(xsh[tok][e], c1[e * 32 + m], a);
            h2sh[tok][m] = fmaxf(a, 0.f);
        }
    }
    __syncthreads();
    if (tid < 16) {
        float a = cb2[0];
#pragma unroll 8
        for (int m = 0; m < 32; ++m) a = fmaf(h2sh[tid][m], c2[m], a);
        float comp = 1.f / (1.f + expf(-a));
        float comb = 0.7f * gsh[tid] + 0.3f * comp;
        int t = (int)ceilf(comb * 20.f);
        t = t < 1 ? 1 : (t > 20 ? 20 : t);
        Ti[tok0 + tid] = t;
    }
}

// ---------------------------------------------------------------------------
// LIF + window mask. One wave per (token, head). lane = channel within head.
// mode 0 (q): qpack[bh*512+i][t]   (row-major per token)
// mode 1 (k): kpackT[bh][t][j]     (t-major: coalesced j-column loads in attn)
// mode 2 (v): per-channel masked spike count -> vmean[bh*512+i][d]
// ---------------------------------------------------------------------------
__global__ __launch_bounds__(256) void lif_kernel(const float* __restrict__ q,
    const float* __restrict__ k, const float* __restrict__ v,
    const int* __restrict__ Ti,
    const float* __restrict__ alphap, const float* __restrict__ betap,
    u64* __restrict__ qpack, u64* __restrict__ kpackT,
    float* __restrict__ vmean)
{
    int mode = blockIdx.y;
    const float* src = (mode == 0) ? q : (mode == 1) ? k : v;
    int w = blockIdx.x * 4 + (threadIdx.x >> 6);   // 0..16383
    int lane = threadIdx.x & 63;
    int token = w >> 3;
    int h = w & 7;
    float xin = src[(size_t)token * 512 + h * 64 + lane];
    int T = Ti[token];
    float alpha = alphap[0], beta = betap[0];
    float vm = 0.f, isyn = 0.f;
    u64 myword = 0ull;
    int cnt = 0;
#pragma unroll
    for (int t = 0; t < TMAX; ++t) {
        isyn = alpha * isyn + xin;
        vm = beta * vm + isyn;
        bool sp = vm >= 1.0f;
        if (sp) vm = 0.f;
        bool msk = sp && (t < T);
        if (mode < 2) {
            u64 word = __ballot(msk ? 1 : 0);
            if (lane == t) myword = word;
        } else {
            cnt += msk ? 1 : 0;
        }
    }
    int b = token >> 9, i = token & 511;
    size_t bh = (size_t)(b * 8 + h);
    if (mode == 0) { if (lane < TMAX) qpack[(bh * 512 + i) * TMAX + lane] = myword; }
    else if (mode == 1) { if (lane < TMAX) kpackT[(bh * TMAX + lane) * 512 + i] = myword; }
    else { vmean[(bh * 512 + i) * 64 + lane] = (float)cnt * 0.05f; }
}

// ---------------------------------------------------------------------------
// scores (popcount, k in VGPRs, q broadcast from LDS) + in-register softmax
// + PV (p via LDS tile, V direct from global/L2). Block = (bh, 16 q-rows).
// ---------------------------------------------------------------------------
__global__ __launch_bounds__(256, 4) void attn_kernel(
    const u64* __restrict__ qpack,
    const u64* __restrict__ kpackT,
    const float* __restrict__ vmean,
    float* __restrict__ ctx)
{
    __shared__ __align__(16) u64 qw[16 * TMAX];    // [i][t], 2560 B
    __shared__ __align__(16) float p_lds[16][256]; // 16 KB
    __shared__ float wredm[16][4];
    __shared__ float wreds[16][4];

    int tid = threadIdx.x;
    int wv = tid >> 6;
    int bh = blockIdx.x >> 5;
    int i0 = (blockIdx.x & 31) << 4;

    // stage q words (16 rows x 20 words, contiguous)
    {
        const u64* qsrc = qpack + ((size_t)bh * 512 + i0) * TMAX;
        for (int idx = tid; idx < 16 * TMAX; idx += 256) qw[idx] = qsrc[idx];
    }
    __syncthreads();

    // ---- scores: thread owns column j = jp*256 + tid --------------------
    float sc[2][16];
#pragma unroll
    for (int jp = 0; jp < 2; ++jp) {
        int j = jp * 256 + tid;
        u64 kw[TMAX];
        const u64* kc = kpackT + (size_t)bh * TMAX * 512 + j;
#pragma unroll
        for (int t = 0; t < TMAX; ++t) kw[t] = kc[(size_t)t * 512];
#pragma unroll
        for (int i = 0; i < 16; ++i) {
            int acc = 0;
            const ulonglong2* q2 = (const ulonglong2*)&qw[i * TMAX];
#pragma unroll
            for (int t2 = 0; t2 < TMAX / 2; ++t2) {
                ulonglong2 qq = q2[t2];
                acc += __popcll(qq.x & kw[2 * t2]);
                acc += __popcll(qq.y & kw[2 * t2 + 1]);
            }
            sc[jp][i] = 0.125f * (float)acc;
        }
    }

    // ---- softmax across threads (each thread holds 2 j per i) ----------
    float mv[16];
#pragma unroll
    for (int i = 0; i < 16; ++i) {
        float m = fmaxf(sc[0][i], sc[1][i]);
#pragma unroll
        for (int o = 1; o < 64; o <<= 1) m = fmaxf(m, __shfl_xor(m, o));
        if ((tid & 63) == i) wredm[i][wv] = m;
    }
    __syncthreads();
#pragma unroll
    for (int i = 0; i < 16; ++i)
        mv[i] = fmaxf(fmaxf(wredm[i][0], wredm[i][1]),
                      fmaxf(wredm[i][2], wredm[i][3]));
    // exponentials + sum
#pragma unroll
    for (int i = 0; i < 16; ++i) {
        sc[0][i] = expf(sc[0][i] - mv[i]);
        sc[1][i] = expf(sc[1][i] - mv[i]);
        float s = sc[0][i] + sc[1][i];
#pragma unroll
        for (int o = 1; o < 64; o <<= 1) s += __shfl_xor(s, o);
        if ((tid & 63) == i) wreds[i][wv] = s;
    }
    __syncthreads();
#pragma unroll
    for (int i = 0; i < 16; ++i) {
        float inv = 1.f / (wreds[i][0] + wreds[i][1] + wreds[i][2] + wreds[i][3]);
        sc[0][i] *= inv;
        sc[1][i] *= inv;
    }

    // ---- PV: p through LDS tile, V direct from global (L2-resident) -----
    int i2 = tid >> 4, dc = tid & 15;
    float4 acc4 = {0.f, 0.f, 0.f, 0.f};
#pragma unroll
    for (int jp = 0; jp < 2; ++jp) {
        __syncthreads();
#pragma unroll
        for (int i = 0; i < 16; ++i) p_lds[i][tid] = sc[jp][i];
        __syncthreads();
        const float4* vrow = (const float4*)(vmean + ((size_t)bh * 512 + jp * 256) * 64) + dc;
#pragma unroll 2
        for (int j4 = 0; j4 < 256; j4 += 4) {
            float4 pp = *(const float4*)&p_lds[i2][j4];
            float4 v0 = vrow[(size_t)(j4 + 0) * 16];
            float4 v1 = vrow[(size_t)(j4 + 1) * 16];
            float4 v2 = vrow[(size_t)(j4 + 2) * 16];
            float4 v3 = vrow[(size_t)(j4 + 3) * 16];
            acc4.x = fmaf(pp.x, v0.x, acc4.x); acc4.y = fmaf(pp.x, v0.y, acc4.y);
            acc4.z = fmaf(pp.x, v0.z, acc4.z); acc4.w = fmaf(pp.x, v0.w, acc4.w);
            acc4.x = fmaf(pp.y, v1.x, acc4.x); acc4.y = fmaf(pp.y, v1.y, acc4.y);
            acc4.z = fmaf(pp.y, v1.z, acc4.z); acc4.w = fmaf(pp.y, v1.w, acc4.w);
            acc4.x = fmaf(pp.z, v2.x, acc4.x); acc4.y = fmaf(pp.z, v2.y, acc4.y);
            acc4.z = fmaf(pp.z, v2.z, acc4.z); acc4.w = fmaf(pp.z, v2.w, acc4.w);
            acc4.x = fmaf(pp.w, v3.x, acc4.x); acc4.y = fmaf(pp.w, v3.y, acc4.y);
            acc4.z = fmaf(pp.w, v3.z, acc4.z); acc4.w = fmaf(pp.w, v3.w, acc4.w);
        }
    }
    int b = bh >> 3, h = bh & 7;
    int row = b * 512 + i0 + i2;
    *(float4*)(&ctx[(size_t)row * 512 + h * 64 + dc * 4]) = acc4;
}

// ---------------------------------------------------------------------------
extern "C" void kernel_launch(void* const* d_in, const int* in_sizes, int n_in,
                              void* d_out, int out_size, void* d_ws, size_t ws_size,
                              hipStream_t stream) {
    const float* x   = (const float*)d_in[0];
    const float* Wq  = (const float*)d_in[1];
    const float* Wk  = (const float*)d_in[2];
    const float* Wv  = (const float*)d_in[3];
    const float* Wo  = (const float*)d_in[4];
    const float* bo  = (const float*)d_in[5];
    const float* g1  = (const float*)d_in[6];
    const float* gb1 = (const float*)d_in[7];
    const float* g2  = (const float*)d_in[8];
    const float* gb2 = (const float*)d_in[9];
    const float* g3  = (const float*)d_in[10];
    const float* gb3 = (const float*)d_in[11];
    const float* c1  = (const float*)d_in[12];
    const float* cb1 = (const float*)d_in[13];
    const float* c2  = (const float*)d_in[14];
    const float* cb2 = (const float*)d_in[15];
    const float* alpha = (const float*)d_in[16];
    const float* beta  = (const float*)d_in[17];
    float* out = (float*)d_out;

    char* w = (char*)d_ws;
    float* q    = (float*)w;                         w += (size_t)BS * E_ * 4;
    float* kbuf = (float*)w;                         w += (size_t)BS * E_ * 4;
    float* vbuf = (float*)w;                         w += (size_t)BS * E_ * 4;
    int* Ti     = (int*)w;                           w += (size_t)BS * 4;
    u64* qpack  = (u64*)w;                           w += (size_t)BS * NH * TMAX * 8;
    u64* kpackT = (u64*)w;                           w += (size_t)BS * NH * TMAX * 8;
    float* vmean = (float*)w;                        w += (size_t)BS * E_ * 4;
    float* ctx = q;   // safe alias: q fully consumed by lif_kernel before attn

    gemm_qkv_kernel<<<dim3(8, 16, 3), 256, 0, stream>>>(x, Wq, Wk, Wv, q, kbuf, vbuf);
    mlp_gate_kernel<<<128, 256, 0, stream>>>(x, g1, gb1, g2, gb2, g3, gb3,
                                             c1, cb1, c2, cb2, Ti);
    lif_kernel<<<dim3(4096, 3), 256, 0, stream>>>(q, kbuf, vbuf, Ti, alpha, beta,
                                                  qpack, kpackT, vmean);
    attn_kernel<<<1024, 256, 0, stream>>>(qpack, kpackT, vmean, ctx);
    gemm_out_kernel<<<dim3(8, 16), 256, 0, stream>>>(ctx, Wo, bo, out);
}

// Round 3
// 261.314 us; speedup vs baseline: 2.2358x; 2.2358x over previous
//
#include <hip/hip_runtime.h>
#include <stdint.h>

#define BS 2048   // B*S
#define E_ 512
#define NH 8
#define HD 64
#define TMAX 20

typedef unsigned long long u64;

// ---------------------------------------------------------------------------
// f32 tiled GEMM: C[M,N] = A[M,K] @ W[K,N] (+bias). BM=128 BN=64 BK=16,
// 256 threads, 8x4 micro-tile. All dims divide exactly for this problem.
// ---------------------------------------------------------------------------
__device__ __forceinline__ void gemm_body(const float* __restrict__ A,
    const float* __restrict__ W, const float* __restrict__ bias,
    float* __restrict__ C, int M, int N, int K)
{
    __shared__ __align__(16) float As[16][132];   // transposed A tile, padded
    __shared__ __align__(16) float Bs[16][64];
    int tid = threadIdx.x;
    int m0 = blockIdx.y * 128;
    int n0 = blockIdx.x * 64;
    int ty = tid >> 4, tx = tid & 15;
    float acc[8][4];
#pragma unroll
    for (int r = 0; r < 8; ++r)
#pragma unroll
        for (int c = 0; c < 4; ++c) acc[r][c] = 0.f;

    int arow = tid >> 2;       // 0..63
    int acol4 = tid & 3;       // 0..3
    int brow = tid >> 4;       // 0..15
    int bcol4 = tid & 15;

    for (int k0 = 0; k0 < K; k0 += 16) {
#pragma unroll
        for (int rr = 0; rr < 2; ++rr) {
            int r = arow + rr * 64;
            float4 va = *(const float4*)(&A[(size_t)(m0 + r) * K + k0 + acol4 * 4]);
            As[acol4 * 4 + 0][r] = va.x;
            As[acol4 * 4 + 1][r] = va.y;
            As[acol4 * 4 + 2][r] = va.z;
            As[acol4 * 4 + 3][r] = va.w;
        }
        float4 vb = *(const float4*)(&W[(size_t)(k0 + brow) * N + n0 + bcol4 * 4]);
        *(float4*)(&Bs[brow][bcol4 * 4]) = vb;
        __syncthreads();
#pragma unroll
        for (int kk = 0; kk < 16; ++kk) {
            float4 a0 = *(const float4*)(&As[kk][ty * 8]);
            float4 a1 = *(const float4*)(&As[kk][ty * 8 + 4]);
            float4 b4 = *(const float4*)(&Bs[kk][tx * 4]);
            float ar[8] = {a0.x, a0.y, a0.z, a0.w, a1.x, a1.y, a1.z, a1.w};
            float br[4] = {b4.x, b4.y, b4.z, b4.w};
#pragma unroll
            for (int r = 0; r < 8; ++r)
#pragma unroll
                for (int c = 0; c < 4; ++c)
                    acc[r][c] = fmaf(ar[r], br[c], acc[r][c]);
        }
        __syncthreads();
    }
#pragma unroll
    for (int r = 0; r < 8; ++r) {
        int row = m0 + ty * 8 + r;
        float4 o;
        o.x = acc[r][0]; o.y = acc[r][1]; o.z = acc[r][2]; o.w = acc[r][3];
        if (bias) {
            o.x += bias[n0 + tx * 4 + 0];
            o.y += bias[n0 + tx * 4 + 1];
            o.z += bias[n0 + tx * 4 + 2];
            o.w += bias[n0 + tx * 4 + 3];
        }
        *(float4*)(&C[(size_t)row * N + n0 + tx * 4]) = o;
    }
}

__global__ __launch_bounds__(256) void gemm_qkv_kernel(const float* __restrict__ x,
    const float* __restrict__ Wq, const float* __restrict__ Wk, const float* __restrict__ Wv,
    float* __restrict__ q, float* __restrict__ k, float* __restrict__ v)
{
    int z = blockIdx.z;
    const float* W = (z == 0) ? Wq : (z == 1) ? Wk : Wv;
    float* C = (z == 0) ? q : (z == 1) ? k : v;
    gemm_body(x, W, nullptr, C, BS, E_, E_);
}

__global__ __launch_bounds__(256) void gemm_out_kernel(const float* __restrict__ ctx,
    const float* __restrict__ Wo, const float* __restrict__ bo, float* __restrict__ out)
{
    gemm_body(ctx, Wo, bo, out, BS, E_, E_);
}

// ---------------------------------------------------------------------------
// Gate/complexity MLPs -> T_i. 16 tokens per 256-thread block.
// ---------------------------------------------------------------------------
__global__ __launch_bounds__(256) void mlp_gate_kernel(const float* __restrict__ x,
    const float* __restrict__ g1, const float* __restrict__ gb1,
    const float* __restrict__ g2, const float* __restrict__ gb2,
    const float* __restrict__ g3, const float* __restrict__ gb3,
    const float* __restrict__ c1, const float* __restrict__ cb1,
    const float* __restrict__ c2, const float* __restrict__ cb2,
    int* __restrict__ Ti)
{
    __shared__ __align__(16) float xsh[16][512];
    __shared__ float h1sh[16][64];
    __shared__ float h2sh[16][32];
    __shared__ float gsh[16];
    int tid = threadIdx.x;
    int tok0 = blockIdx.x * 16;

    const float4* xg = (const float4*)(&x[(size_t)tok0 * 512]);
    float4* xs4 = (float4*)(&xsh[0][0]);
    for (int i = tid; i < 16 * 128; i += 256) xs4[i] = xg[i];
    __syncthreads();

    {   // h1 = relu(x@g1+gb1): lane l = output ch, wave handles 4 tokens
        int l = tid & 63, tg = tid >> 6;
        float a0 = gb1[l], a1 = a0, a2 = a0, a3 = a0;
#pragma unroll 8
        for (int e = 0; e < 512; ++e) {
            float w = g1[e * 64 + l];
            a0 = fmaf(xsh[tg][e], w, a0);
            a1 = fmaf(xsh[tg + 4][e], w, a1);
            a2 = fmaf(xsh[tg + 8][e], w, a2);
            a3 = fmaf(xsh[tg + 12][e], w, a3);
        }
        h1sh[tg][l] = fmaxf(a0, 0.f);
        h1sh[tg + 4][l] = fmaxf(a1, 0.f);
        h1sh[tg + 8][l] = fmaxf(a2, 0.f);
        h1sh[tg + 12][l] = fmaxf(a3, 0.f);
    }
    __syncthreads();
    {   // h2 = relu(h1@g2+gb2)
        int m = tid & 31, tg = tid >> 5;
#pragma unroll
        for (int tt = 0; tt < 2; ++tt) {
            int tok = tg + tt * 8;
            float a = gb2[m];
#pragma unroll 8
            for (int l = 0; l < 64; ++l) a = fmaf(h1sh[tok][l], g2[l * 32 + m], a);
            h2sh[tok][m] = fmaxf(a, 0.f);
        }
    }
    __syncthreads();
    if (tid < 16) {
        float a = gb3[0];
#pragma unroll 8
        for (int m = 0; m < 32; ++m) a = fmaf(h2sh[tid][m], g3[m], a);
        gsh[tid] = 1.f / (1.f + expf(-a));
    }
    __syncthreads();
    {   // comp hidden = relu(x@c1+cb1)  (reuse h2sh)
        int m = tid & 31, tg = tid >> 5;
#pragma unroll
        for (int tt = 0; tt < 2; ++tt) {
            int tok = tg + tt * 8;
            float a = cb1[m];
#pragma unroll 8
            for (int e = 0; e < 512; ++e) a = fmaf(xsh[tok][e], c1[e * 32 + m], a);
            h2sh[tok][m] = fmaxf(a, 0.f);
        }
    }
    __syncthreads();
    if (tid < 16) {
        float a = cb2[0];
#pragma unroll 8
        for (int m = 0; m < 32; ++m) a = fmaf(h2sh[tid][m], c2[m], a);
        float comp = 1.f / (1.f + expf(-a));
        float comb = 0.7f * gsh[tid] + 0.3f * comp;
        int t = (int)ceilf(comb * 20.f);
        t = t < 1 ? 1 : (t > 20 ? 20 : t);
        Ti[tok0 + tid] = t;
    }
}

// ---------------------------------------------------------------------------
// LIF + window mask. One wave per (token, head). lane = channel within head.
// mode 0 (q): qpack[bh*512+i][t]   (row-major per token)
// mode 1 (k): kpackT[bh][t][j]     (t-major: coalesced j-column loads in attn)
// mode 2 (v): per-channel masked spike count -> vmean[bh*512+i][d]
// ---------------------------------------------------------------------------
__global__ __launch_bounds__(256) void lif_kernel(const float* __restrict__ q,
    const float* __restrict__ k, const float* __restrict__ v,
    const int* __restrict__ Ti,
    const float* __restrict__ alphap, const float* __restrict__ betap,
    u64* __restrict__ qpack, u64* __restrict__ kpackT,
    float* __restrict__ vmean)
{
    int mode = blockIdx.y;
    const float* src = (mode == 0) ? q : (mode == 1) ? k : v;
    int w = blockIdx.x * 4 + (threadIdx.x >> 6);   // 0..16383
    int lane = threadIdx.x & 63;
    int token = w >> 3;
    int h = w & 7;
    float xin = src[(size_t)token * 512 + h * 64 + lane];
    int T = Ti[token];
    float alpha = alphap[0], beta = betap[0];
    float vm = 0.f, isyn = 0.f;
    u64 myword = 0ull;
    int cnt = 0;
#pragma unroll
    for (int t = 0; t < TMAX; ++t) {
        isyn = alpha * isyn + xin;
        vm = beta * vm + isyn;
        bool sp = vm >= 1.0f;
        if (sp) vm = 0.f;
        bool msk = sp && (t < T);
        if (mode < 2) {
            u64 word = __ballot(msk ? 1 : 0);
            if (lane == t) myword = word;
        } else {
            cnt += msk ? 1 : 0;
        }
    }
    int b = token >> 9, i = token & 511;
    size_t bh = (size_t)(b * 8 + h);
    if (mode == 0) { if (lane < TMAX) qpack[(bh * 512 + i) * TMAX + lane] = myword; }
    else if (mode == 1) { if (lane < TMAX) kpackT[(bh * TMAX + lane) * 512 + i] = myword; }
    else { vmean[(bh * 512 + i) * 64 + lane] = (float)cnt * 0.05f; }
}

// ---------------------------------------------------------------------------
// scores (k in VGPRs, q via wave-uniform SCALAR loads -> SGPRs) + in-wave
// softmax (16 lanes own a row) + PV (p broadcast from LDS, V from L2).
// Block = (bh, 16 q-rows). One __syncthreads total. LDS = 33.4 KB.
// ---------------------------------------------------------------------------
__global__ __launch_bounds__(256) void attn_kernel(
    const u64* __restrict__ qpack,
    const u64* __restrict__ kpackT,
    const float* __restrict__ vmean,
    float* __restrict__ ctx)
{
    __shared__ float s_lds[16][520];   // scores then p; pad 520 -> ~2-way max
    __shared__ float inv_lds[16];

    int tid = threadIdx.x;
    // XCD-bijective swizzle: 1024 blocks = 8 XCDs x 128 -> each XCD sees
    // 4 consecutive bh (kpackT+vmean ~830 KB, L2-resident per XCD).
    int bid = blockIdx.x;
    int swz = (bid & 7) * 128 + (bid >> 3);
    int bh = swz >> 5;
    int i0 = (swz & 31) << 4;

    // ---- scores: thread owns column j; q rows are wave-uniform scalar loads
#pragma unroll
    for (int jp = 0; jp < 2; ++jp) {
        int j = jp * 256 + tid;
        u64 kw[TMAX];
        const u64* kc = kpackT + (size_t)bh * TMAX * 512 + j;
#pragma unroll
        for (int t = 0; t < TMAX; ++t) kw[t] = kc[(size_t)t * 512];
#pragma unroll
        for (int i = 0; i < 16; ++i) {
            const u64* qrow = qpack + ((size_t)bh * 512 + i0 + i) * TMAX;  // uniform
            int acc = 0;
#pragma unroll
            for (int t = 0; t < TMAX; ++t)
                acc += __popcll(qrow[t] & kw[t]);
            s_lds[i][j] = 0.125f * (float)acc;
        }
    }
    __syncthreads();

    // ---- softmax: 16 lanes per row, all within one wave (no barrier needed)
    {
        int irow = tid >> 4, jc = tid & 15;
        float m = -1e30f;
#pragma unroll 4
        for (int s = 0; s < 32; ++s) m = fmaxf(m, s_lds[irow][jc + s * 16]);
#pragma unroll
        for (int o = 1; o < 16; o <<= 1) m = fmaxf(m, __shfl_xor(m, o));
        float lsum = 0.f;
#pragma unroll 4
        for (int s = 0; s < 32; ++s) {
            int j = jc + s * 16;
            float p = __expf(s_lds[irow][j] - m);
            s_lds[irow][j] = p;
            lsum += p;
        }
#pragma unroll
        for (int o = 1; o < 16; o <<= 1) lsum += __shfl_xor(lsum, o);
        if (jc == 0) inv_lds[irow] = 1.f / lsum;
    }
    // PV reads only rows owned by this wave's lanes -> program order suffices.

    // ---- PV: p broadcast from LDS, V rows direct from global (L2)
    int i2 = tid >> 4, dc = tid & 15;
    float4 acc4 = {0.f, 0.f, 0.f, 0.f};
    const float4* vrow = (const float4*)(vmean + (size_t)bh * 512 * 64) + dc;
#pragma unroll 2
    for (int j = 0; j < 512; j += 4) {
        float4 pp = *(const float4*)&s_lds[i2][j];
        float4 v0 = vrow[(size_t)(j + 0) * 16];
        float4 v1 = vrow[(size_t)(j + 1) * 16];
        float4 v2 = vrow[(size_t)(j + 2) * 16];
        float4 v3 = vrow[(size_t)(j + 3) * 16];
        acc4.x = fmaf(pp.x, v0.x, acc4.x); acc4.y = fmaf(pp.x, v0.y, acc4.y);
        acc4.z = fmaf(pp.x, v0.z, acc4.z); acc4.w = fmaf(pp.x, v0.w, acc4.w);
        acc4.x = fmaf(pp.y, v1.x, acc4.x); acc4.y = fmaf(pp.y, v1.y, acc4.y);
        acc4.z = fmaf(pp.y, v1.z, acc4.z); acc4.w = fmaf(pp.y, v1.w, acc4.w);
        acc4.x = fmaf(pp.z, v2.x, acc4.x); acc4.y = fmaf(pp.z, v2.y, acc4.y);
        acc4.z = fmaf(pp.z, v2.z, acc4.z); acc4.w = fmaf(pp.z, v2.w, acc4.w);
        acc4.x = fmaf(pp.w, v3.x, acc4.x); acc4.y = fmaf(pp.w, v3.y, acc4.y);
        acc4.z = fmaf(pp.w, v3.z, acc4.z); acc4.w = fmaf(pp.w, v3.w, acc4.w);
    }
    float inv = inv_lds[i2];
    acc4.x *= inv; acc4.y *= inv; acc4.z *= inv; acc4.w *= inv;
    int b = bh >> 3, h = bh & 7;
    int row = b * 512 + i0 + i2;
    *(float4*)(&ctx[(size_t)row * 512 + h * 64 + dc * 4]) = acc4;
}

// ---------------------------------------------------------------------------
extern "C" void kernel_launch(void* const* d_in, const int* in_sizes, int n_in,
                              void* d_out, int out_size, void* d_ws, size_t ws_size,
                              hipStream_t stream) {
    const float* x   = (const float*)d_in[0];
    const float* Wq  = (const float*)d_in[1];
    const float* Wk  = (const float*)d_in[2];
    const float* Wv  = (const float*)d_in[3];
    const float* Wo  = (const float*)d_in[4];
    const float* bo  = (const float*)d_in[5];
    const float* g1  = (const float*)d_in[6];
    const float* gb1 = (const float*)d_in[7];
    const float* g2  = (const float*)d_in[8];
    const float* gb2 = (const float*)d_in[9];
    const float* g3  = (const float*)d_in[10];
    const float* gb3 = (const float*)d_in[11];
    const float* c1  = (const float*)d_in[12];
    const float* cb1 = (const float*)d_in[13];
    const float* c2  = (const float*)d_in[14];
    const float* cb2 = (const float*)d_in[15];
    const float* alpha = (const float*)d_in[16];
    const float* beta  = (const float*)d_in[17];
    float* out = (float*)d_out;

    char* w = (char*)d_ws;
    float* q    = (float*)w;                         w += (size_t)BS * E_ * 4;
    float* kbuf = (float*)w;                         w += (size_t)BS * E_ * 4;
    float* vbuf = (float*)w;                         w += (size_t)BS * E_ * 4;
    int* Ti     = (int*)w;                           w += (size_t)BS * 4;
    u64* qpack  = (u64*)w;                           w += (size_t)BS * NH * TMAX * 8;
    u64* kpackT = (u64*)w;                           w += (size_t)BS * NH * TMAX * 8;
    float* vmean = (float*)w;                        w += (size_t)BS * E_ * 4;
    float* ctx = q;   // safe alias: q fully consumed by lif_kernel before attn

    gemm_qkv_kernel<<<dim3(8, 16, 3), 256, 0, stream>>>(x, Wq, Wk, Wv, q, kbuf, vbuf);
    mlp_gate_kernel<<<128, 256, 0, stream>>>(x, g1, gb1, g2, gb2, g3, gb3,
                                             c1, cb1, c2, cb2, Ti);
    lif_kernel<<<dim3(4096, 3), 256, 0, stream>>>(q, kbuf, vbuf, Ti, alpha, beta,
                                                  qpack, kpackT, vmean);
    attn_kernel<<<1024, 256, 0, stream>>>(qpack, kpackT, vmean, ctx);
    gemm_out_kernel<<<dim3(8, 16), 256, 0, stream>>>(ctx, Wo, bo, out);
}

// Round 4
// 252.788 us; speedup vs baseline: 2.3112x; 1.0337x over previous
//
#include <hip/hip_runtime.h>
#include <stdint.h>

#define BS 2048   // B*S
#define E_ 512
#define NH 8
#define HD 64
#define TMAX 20

typedef unsigned long long u64;

// ---------------------------------------------------------------------------
// f32 tiled GEMM: C[M,N] = A[M,K] @ W[K,N] (+bias). BM=128 BN=64 BK=16,
// 256 threads, 8x4 micro-tile. All dims divide exactly for this problem.
// ---------------------------------------------------------------------------
__device__ __forceinline__ void gemm_body(const float* __restrict__ A,
    const float* __restrict__ W, const float* __restrict__ bias,
    float* __restrict__ C, int M, int N, int K)
{
    __shared__ __align__(16) float As[16][132];   // transposed A tile, padded
    __shared__ __align__(16) float Bs[16][64];
    int tid = threadIdx.x;
    int m0 = blockIdx.y * 128;
    int n0 = blockIdx.x * 64;
    int ty = tid >> 4, tx = tid & 15;
    float acc[8][4];
#pragma unroll
    for (int r = 0; r < 8; ++r)
#pragma unroll
        for (int c = 0; c < 4; ++c) acc[r][c] = 0.f;

    int arow = tid >> 2;       // 0..63
    int acol4 = tid & 3;       // 0..3
    int brow = tid >> 4;       // 0..15
    int bcol4 = tid & 15;

    for (int k0 = 0; k0 < K; k0 += 16) {
#pragma unroll
        for (int rr = 0; rr < 2; ++rr) {
            int r = arow + rr * 64;
            float4 va = *(const float4*)(&A[(size_t)(m0 + r) * K + k0 + acol4 * 4]);
            As[acol4 * 4 + 0][r] = va.x;
            As[acol4 * 4 + 1][r] = va.y;
            As[acol4 * 4 + 2][r] = va.z;
            As[acol4 * 4 + 3][r] = va.w;
        }
        float4 vb = *(const float4*)(&W[(size_t)(k0 + brow) * N + n0 + bcol4 * 4]);
        *(float4*)(&Bs[brow][bcol4 * 4]) = vb;
        __syncthreads();
#pragma unroll
        for (int kk = 0; kk < 16; ++kk) {
            float4 a0 = *(const float4*)(&As[kk][ty * 8]);
            float4 a1 = *(const float4*)(&As[kk][ty * 8 + 4]);
            float4 b4 = *(const float4*)(&Bs[kk][tx * 4]);
            float ar[8] = {a0.x, a0.y, a0.z, a0.w, a1.x, a1.y, a1.z, a1.w};
            float br[4] = {b4.x, b4.y, b4.z, b4.w};
#pragma unroll
            for (int r = 0; r < 8; ++r)
#pragma unroll
                for (int c = 0; c < 4; ++c)
                    acc[r][c] = fmaf(ar[r], br[c], acc[r][c]);
        }
        __syncthreads();
    }
#pragma unroll
    for (int r = 0; r < 8; ++r) {
        int row = m0 + ty * 8 + r;
        float4 o;
        o.x = acc[r][0]; o.y = acc[r][1]; o.z = acc[r][2]; o.w = acc[r][3];
        if (bias) {
            o.x += bias[n0 + tx * 4 + 0];
            o.y += bias[n0 + tx * 4 + 1];
            o.z += bias[n0 + tx * 4 + 2];
            o.w += bias[n0 + tx * 4 + 3];
        }
        *(float4*)(&C[(size_t)row * N + n0 + tx * 4]) = o;
    }
}

__global__ __launch_bounds__(256) void gemm_qkv_kernel(const float* __restrict__ x,
    const float* __restrict__ Wq, const float* __restrict__ Wk, const float* __restrict__ Wv,
    float* __restrict__ q, float* __restrict__ k, float* __restrict__ v)
{
    int z = blockIdx.z;
    const float* W = (z == 0) ? Wq : (z == 1) ? Wk : Wv;
    float* C = (z == 0) ? q : (z == 1) ? k : v;
    gemm_body(x, W, nullptr, C, BS, E_, E_);
}

__global__ __launch_bounds__(256) void gemm_out_kernel(const float* __restrict__ ctx,
    const float* __restrict__ Wo, const float* __restrict__ bo, float* __restrict__ out)
{
    gemm_body(ctx, Wo, bo, out, BS, E_, E_);
}

// ---------------------------------------------------------------------------
// Gate/complexity MLPs -> T_i. 16 tokens per 256-thread block.
// ---------------------------------------------------------------------------
__global__ __launch_bounds__(256) void mlp_gate_kernel(const float* __restrict__ x,
    const float* __restrict__ g1, const float* __restrict__ gb1,
    const float* __restrict__ g2, const float* __restrict__ gb2,
    const float* __restrict__ g3, const float* __restrict__ gb3,
    const float* __restrict__ c1, const float* __restrict__ cb1,
    const float* __restrict__ c2, const float* __restrict__ cb2,
    int* __restrict__ Ti)
{
    __shared__ __align__(16) float xsh[16][512];
    __shared__ float h1sh[16][64];
    __shared__ float h2sh[16][32];
    __shared__ float gsh[16];
    int tid = threadIdx.x;
    int tok0 = blockIdx.x * 16;

    const float4* xg = (const float4*)(&x[(size_t)tok0 * 512]);
    float4* xs4 = (float4*)(&xsh[0][0]);
    for (int i = tid; i < 16 * 128; i += 256) xs4[i] = xg[i];
    __syncthreads();

    {   // h1 = relu(x@g1+gb1): lane l = output ch, wave handles 4 tokens
        int l = tid & 63, tg = tid >> 6;
        float a0 = gb1[l], a1 = a0, a2 = a0, a3 = a0;
#pragma unroll 8
        for (int e = 0; e < 512; ++e) {
            float w = g1[e * 64 + l];
            a0 = fmaf(xsh[tg][e], w, a0);
            a1 = fmaf(xsh[tg + 4][e], w, a1);
            a2 = fmaf(xsh[tg + 8][e], w, a2);
            a3 = fmaf(xsh[tg + 12][e], w, a3);
        }
        h1sh[tg][l] = fmaxf(a0, 0.f);
        h1sh[tg + 4][l] = fmaxf(a1, 0.f);
        h1sh[tg + 8][l] = fmaxf(a2, 0.f);
        h1sh[tg + 12][l] = fmaxf(a3, 0.f);
    }
    __syncthreads();
    {   // h2 = relu(h1@g2+gb2)
        int m = tid & 31, tg = tid >> 5;
#pragma unroll
        for (int tt = 0; tt < 2; ++tt) {
            int tok = tg + tt * 8;
            float a = gb2[m];
#pragma unroll 8
            for (int l = 0; l < 64; ++l) a = fmaf(h1sh[tok][l], g2[l * 32 + m], a);
            h2sh[tok][m] = fmaxf(a, 0.f);
        }
    }
    __syncthreads();
    if (tid < 16) {
        float a = gb3[0];
#pragma unroll 8
        for (int m = 0; m < 32; ++m) a = fmaf(h2sh[tid][m], g3[m], a);
        gsh[tid] = 1.f / (1.f + expf(-a));
    }
    __syncthreads();
    {   // comp hidden = relu(x@c1+cb1)  (reuse h2sh)
        int m = tid & 31, tg = tid >> 5;
#pragma unroll
        for (int tt = 0; tt < 2; ++tt) {
            int tok = tg + tt * 8;
            float a = cb1[m];
#pragma unroll 8
            for (int e = 0; e < 512; ++e) a = fmaf(xsh[tok][e], c1[e * 32 + m], a);
            h2sh[tok][m] = fmaxf(a, 0.f);
        }
    }
    __syncthreads();
    if (tid < 16) {
        float a = cb2[0];
#pragma unroll 8
        for (int m = 0; m < 32; ++m) a = fmaf(h2sh[tid][m], c2[m], a);
        float comp = 1.f / (1.f + expf(-a));
        float comb = 0.7f * gsh[tid] + 0.3f * comp;
        int t = (int)ceilf(comb * 20.f);
        t = t < 1 ? 1 : (t > 20 ? 20 : t);
        Ti[tok0 + tid] = t;
    }
}

// ---------------------------------------------------------------------------
// LIF + window mask. One wave per (token, head). lane = channel within head.
// mode 0 (q): qpack[bh*512+i][t]  mode 1 (k): kpack[bh*512+j][t]  (same layout,
// 160B contiguous per row -> coalesced stores here, b128 row loads in attn)
// mode 2 (v): per-channel masked spike count -> vmean[bh*512+i][d]
// ---------------------------------------------------------------------------
__global__ __launch_bounds__(256) void lif_kernel(const float* __restrict__ q,
    const float* __restrict__ k, const float* __restrict__ v,
    const int* __restrict__ Ti,
    const float* __restrict__ alphap, const float* __restrict__ betap,
    u64* __restrict__ qpack, u64* __restrict__ kpack,
    float* __restrict__ vmean)
{
    int mode = blockIdx.y;
    const float* src = (mode == 0) ? q : (mode == 1) ? k : v;
    int w = blockIdx.x * 4 + (threadIdx.x >> 6);   // 0..16383
    int lane = threadIdx.x & 63;
    int token = w >> 3;
    int h = w & 7;
    float xin = src[(size_t)token * 512 + h * 64 + lane];
    int T = Ti[token];
    float alpha = alphap[0], beta = betap[0];
    float vm = 0.f, isyn = 0.f;
    u64 myword = 0ull;
    int cnt = 0;
#pragma unroll
    for (int t = 0; t < TMAX; ++t) {
        isyn = alpha * isyn + xin;
        vm = beta * vm + isyn;
        bool sp = vm >= 1.0f;
        if (sp) vm = 0.f;
        bool msk = sp && (t < T);
        if (mode < 2) {
            u64 word = __ballot(msk ? 1 : 0);
            if (lane == t) myword = word;
        } else {
            cnt += msk ? 1 : 0;
        }
    }
    int b = token >> 9, i = token & 511;
    size_t bh = (size_t)(b * 8 + h);
    if (mode == 0) { if (lane < TMAX) qpack[(bh * 512 + i) * TMAX + lane] = myword; }
    else if (mode == 1) { if (lane < TMAX) kpack[(bh * 512 + i) * TMAX + lane] = myword; }
    else { vmean[(bh * 512 + i) * 64 + lane] = (float)cnt * 0.05f; }
}

// ---------------------------------------------------------------------------
// attn: 512 threads (8 waves), 1024 blocks -> 4 blocks/CU, 32 waves/CU.
// scores: thread owns column j (k-row 160B contiguous in VGPRs, q rows via
// wave-uniform scalar loads). softmax: 32 lanes/row. PV: wave 0 only, thread
// (g,dc) accumulates rows {g,g+4,g+8,g+12} -> V slice read ONCE per block.
// ---------------------------------------------------------------------------
__global__ __launch_bounds__(512) void attn_kernel(
    const u64* __restrict__ qpack,
    const u64* __restrict__ kpack,
    const float* __restrict__ vmean,
    float* __restrict__ ctx)
{
    __shared__ float s_lds[16][520];   // 33.3 KB; 520 pad -> <=2-way banks
    __shared__ float inv_lds[16];

    int tid = threadIdx.x;
    // XCD-bijective swizzle: 1024 = 8 XCDs x 128 -> 4 consecutive bh per XCD
    int bid = blockIdx.x;
    int swz = (bid & 7) * 128 + (bid >> 3);
    int bh = swz >> 5;                 // 0..31 (B*NH = 32)
    int i0 = (swz & 31) << 4;

    // ---- scores: thread owns column j = tid ----------------------------
    {
        int j = tid;
        u64 kw[TMAX];
        const ulonglong2* kc = (const ulonglong2*)(kpack + ((size_t)bh * 512 + j) * TMAX);
#pragma unroll
        for (int t2 = 0; t2 < TMAX / 2; ++t2) {
            ulonglong2 u = kc[t2];
            kw[2 * t2] = u.x;
            kw[2 * t2 + 1] = u.y;
        }
#pragma unroll
        for (int i = 0; i < 16; ++i) {
            const u64* qrow = qpack + ((size_t)bh * 512 + i0 + i) * TMAX;  // uniform
            int a0 = 0, a1 = 0;
#pragma unroll
            for (int t = 0; t < TMAX; t += 2) {
                a0 += __popcll(qrow[t] & kw[t]);
                a1 += __popcll(qrow[t + 1] & kw[t + 1]);
            }
            s_lds[i][j] = 0.125f * (float)(a0 + a1);
        }
    }
    __syncthreads();

    // ---- softmax: 32 lanes per row ---------------------------------------
    {
        int row = tid >> 5, jc = tid & 31;
        float m = -1e30f;
#pragma unroll 4
        for (int s = 0; s < 16; ++s) m = fmaxf(m, s_lds[row][jc + s * 32]);
#pragma unroll
        for (int o = 1; o < 32; o <<= 1) m = fmaxf(m, __shfl_xor(m, o));
        float lsum = 0.f;
#pragma unroll 4
        for (int s = 0; s < 16; ++s) {
            int j = jc + s * 32;
            float p = __expf(s_lds[row][j] - m);
            s_lds[row][j] = p;
            lsum += p;
        }
#pragma unroll
        for (int o = 1; o < 32; o <<= 1) lsum += __shfl_xor(lsum, o);
        if (jc == 0) inv_lds[row] = 1.f / lsum;
    }
    __syncthreads();

    // ---- PV: wave 0 only; thread (g,dc) owns rows g,g+4,g+8,g+12 ---------
    if (tid < 64) {
        int g = tid >> 4, dc = tid & 15;
        float4 acc[4];
#pragma unroll
        for (int s = 0; s < 4; ++s) acc[s] = (float4){0.f, 0.f, 0.f, 0.f};
        const float4* vrow = (const float4*)(vmean + (size_t)bh * 512 * 64) + dc;
        for (int j4 = 0; j4 < 512; j4 += 4) {
            float4 v0 = vrow[(j4 + 0) * 16];
            float4 v1 = vrow[(j4 + 1) * 16];
            float4 v2 = vrow[(j4 + 2) * 16];
            float4 v3 = vrow[(j4 + 3) * 16];
#pragma unroll
            for (int s = 0; s < 4; ++s) {
                float4 pp = *(const float4*)&s_lds[g + 4 * s][j4];
                acc[s].x = fmaf(pp.x, v0.x, acc[s].x); acc[s].y = fmaf(pp.x, v0.y, acc[s].y);
                acc[s].z = fmaf(pp.x, v0.z, acc[s].z); acc[s].w = fmaf(pp.x, v0.w, acc[s].w);
                acc[s].x = fmaf(pp.y, v1.x, acc[s].x); acc[s].y = fmaf(pp.y, v1.y, acc[s].y);
                acc[s].z = fmaf(pp.y, v1.z, acc[s].z); acc[s].w = fmaf(pp.y, v1.w, acc[s].w);
                acc[s].x = fmaf(pp.z, v2.x, acc[s].x); acc[s].y = fmaf(pp.z, v2.y, acc[s].y);
                acc[s].z = fmaf(pp.z, v2.z, acc[s].z); acc[s].w = fmaf(pp.z, v2.w, acc[s].w);
                acc[s].x = fmaf(pp.w, v3.x, acc[s].x); acc[s].y = fmaf(pp.w, v3.y, acc[s].y);
                acc[s].z = fmaf(pp.w, v3.z, acc[s].z); acc[s].w = fmaf(pp.w, v3.w, acc[s].w);
            }
        }
        int b = bh >> 3, h = bh & 7;
#pragma unroll
        for (int s = 0; s < 4; ++s) {
            int i2 = g + 4 * s;
            float inv = inv_lds[i2];
            float4 o = acc[s];
            o.x *= inv; o.y *= inv; o.z *= inv; o.w *= inv;
            int row = b * 512 + i0 + i2;
            *(float4*)(&ctx[(size_t)row * 512 + h * 64 + dc * 4]) = o;
        }
    }
}

// ---------------------------------------------------------------------------
extern "C" void kernel_launch(void* const* d_in, const int* in_sizes, int n_in,
                              void* d_out, int out_size, void* d_ws, size_t ws_size,
                              hipStream_t stream) {
    const float* x   = (const float*)d_in[0];
    const float* Wq  = (const float*)d_in[1];
    const float* Wk  = (const float*)d_in[2];
    const float* Wv  = (const float*)d_in[3];
    const float* Wo  = (const float*)d_in[4];
    const float* bo  = (const float*)d_in[5];
    const float* g1  = (const float*)d_in[6];
    const float* gb1 = (const float*)d_in[7];
    const float* g2  = (const float*)d_in[8];
    const float* gb2 = (const float*)d_in[9];
    const float* g3  = (const float*)d_in[10];
    const float* gb3 = (const float*)d_in[11];
    const float* c1  = (const float*)d_in[12];
    const float* cb1 = (const float*)d_in[13];
    const float* c2  = (const float*)d_in[14];
    const float* cb2 = (const float*)d_in[15];
    const float* alpha = (const float*)d_in[16];
    const float* beta  = (const float*)d_in[17];
    float* out = (float*)d_out;

    char* w = (char*)d_ws;
    float* q    = (float*)w;                         w += (size_t)BS * E_ * 4;
    float* kbuf = (float*)w;                         w += (size_t)BS * E_ * 4;
    float* vbuf = (float*)w;                         w += (size_t)BS * E_ * 4;
    int* Ti     = (int*)w;                           w += (size_t)BS * 4;
    u64* qpack  = (u64*)w;                           w += (size_t)BS * NH * TMAX * 8;
    u64* kpack  = (u64*)w;                           w += (size_t)BS * NH * TMAX * 8;
    float* vmean = (float*)w;                        w += (size_t)BS * E_ * 4;
    float* ctx = q;   // safe alias: q fully consumed by lif_kernel before attn

    gemm_qkv_kernel<<<dim3(8, 16, 3), 256, 0, stream>>>(x, Wq, Wk, Wv, q, kbuf, vbuf);
    mlp_gate_kernel<<<128, 256, 0, stream>>>(x, g1, gb1, g2, gb2, g3, gb3,
                                             c1, cb1, c2, cb2, Ti);
    lif_kernel<<<dim3(4096, 3), 256, 0, stream>>>(q, kbuf, vbuf, Ti, alpha, beta,
                                                  qpack, kpack, vmean);
    attn_kernel<<<1024, 512, 0, stream>>>(qpack, kpack, vmean, ctx);
    gemm_out_kernel<<<dim3(8, 16), 256, 0, stream>>>(ctx, Wo, bo, out);
}

// Round 5
// 228.545 us; speedup vs baseline: 2.5564x; 1.1061x over previous
//
#include <hip/hip_runtime.h>
#include <stdint.h>

#define BS 2048   // B*S
#define E_ 512
#define NH 8
#define HD 64
#define TMAX 20

typedef unsigned long long u64;

// ---------------------------------------------------------------------------
// f32 tiled GEMM: C[M,N] = A[M,K] @ W[K,N] (+bias). BM=128 BN=64 BK=16,
// 256 threads, 8x4 micro-tile. All dims divide exactly for this problem.
// ---------------------------------------------------------------------------
__device__ __forceinline__ void gemm_body(const float* __restrict__ A,
    const float* __restrict__ W, const float* __restrict__ bias,
    float* __restrict__ C, int M, int N, int K)
{
    __shared__ __align__(16) float As[16][132];   // transposed A tile, padded
    __shared__ __align__(16) float Bs[16][64];
    int tid = threadIdx.x;
    int m0 = blockIdx.y * 128;
    int n0 = blockIdx.x * 64;
    int ty = tid >> 4, tx = tid & 15;
    float acc[8][4];
#pragma unroll
    for (int r = 0; r < 8; ++r)
#pragma unroll
        for (int c = 0; c < 4; ++c) acc[r][c] = 0.f;

    int arow = tid >> 2;       // 0..63
    int acol4 = tid & 3;       // 0..3
    int brow = tid >> 4;       // 0..15
    int bcol4 = tid & 15;

    for (int k0 = 0; k0 < K; k0 += 16) {
#pragma unroll
        for (int rr = 0; rr < 2; ++rr) {
            int r = arow + rr * 64;
            float4 va = *(const float4*)(&A[(size_t)(m0 + r) * K + k0 + acol4 * 4]);
            As[acol4 * 4 + 0][r] = va.x;
            As[acol4 * 4 + 1][r] = va.y;
            As[acol4 * 4 + 2][r] = va.z;
            As[acol4 * 4 + 3][r] = va.w;
        }
        float4 vb = *(const float4*)(&W[(size_t)(k0 + brow) * N + n0 + bcol4 * 4]);
        *(float4*)(&Bs[brow][bcol4 * 4]) = vb;
        __syncthreads();
#pragma unroll
        for (int kk = 0; kk < 16; ++kk) {
            float4 a0 = *(const float4*)(&As[kk][ty * 8]);
            float4 a1 = *(const float4*)(&As[kk][ty * 8 + 4]);
            float4 b4 = *(const float4*)(&Bs[kk][tx * 4]);
            float ar[8] = {a0.x, a0.y, a0.z, a0.w, a1.x, a1.y, a1.z, a1.w};
            float br[4] = {b4.x, b4.y, b4.z, b4.w};
#pragma unroll
            for (int r = 0; r < 8; ++r)
#pragma unroll
                for (int c = 0; c < 4; ++c)
                    acc[r][c] = fmaf(ar[r], br[c], acc[r][c]);
        }
        __syncthreads();
    }
#pragma unroll
    for (int r = 0; r < 8; ++r) {
        int row = m0 + ty * 8 + r;
        float4 o;
        o.x = acc[r][0]; o.y = acc[r][1]; o.z = acc[r][2]; o.w = acc[r][3];
        if (bias) {
            o.x += bias[n0 + tx * 4 + 0];
            o.y += bias[n0 + tx * 4 + 1];
            o.z += bias[n0 + tx * 4 + 2];
            o.w += bias[n0 + tx * 4 + 3];
        }
        *(float4*)(&C[(size_t)row * N + n0 + tx * 4]) = o;
    }
}

__global__ __launch_bounds__(256) void gemm_qkv_kernel(const float* __restrict__ x,
    const float* __restrict__ Wq, const float* __restrict__ Wk, const float* __restrict__ Wv,
    float* __restrict__ q, float* __restrict__ k, float* __restrict__ v)
{
    int z = blockIdx.z;
    const float* W = (z == 0) ? Wq : (z == 1) ? Wk : Wv;
    float* C = (z == 0) ? q : (z == 1) ? k : v;
    gemm_body(x, W, nullptr, C, BS, E_, E_);
}

__global__ __launch_bounds__(256) void gemm_out_kernel(const float* __restrict__ ctx,
    const float* __restrict__ Wo, const float* __restrict__ bo, float* __restrict__ out)
{
    gemm_body(ctx, Wo, bo, out, BS, E_, E_);
}

// ---------------------------------------------------------------------------
// Gate/complexity MLPs -> T_i. 8 tokens per 256-thread block (256 blocks).
// ---------------------------------------------------------------------------
__global__ __launch_bounds__(256) void mlp_gate_kernel(const float* __restrict__ x,
    const float* __restrict__ g1, const float* __restrict__ gb1,
    const float* __restrict__ g2, const float* __restrict__ gb2,
    const float* __restrict__ g3, const float* __restrict__ gb3,
    const float* __restrict__ c1, const float* __restrict__ cb1,
    const float* __restrict__ c2, const float* __restrict__ cb2,
    int* __restrict__ Ti)
{
    __shared__ __align__(16) float xsh[8][512];
    __shared__ float h1sh[8][64];
    __shared__ float h2sh[8][32];
    __shared__ float gsh[8];
    int tid = threadIdx.x;
    int tok0 = blockIdx.x * 8;

    const float4* xg = (const float4*)(&x[(size_t)tok0 * 512]);
    float4* xs4 = (float4*)(&xsh[0][0]);
    for (int i = tid; i < 8 * 128; i += 256) xs4[i] = xg[i];
    __syncthreads();

    {   // h1 = relu(x@g1+gb1): lane l = output ch, wave handles 2 tokens
        int l = tid & 63, tg = tid >> 6;
        float a0 = gb1[l], a1 = a0;
#pragma unroll 8
        for (int e = 0; e < 512; ++e) {
            float w = g1[e * 64 + l];
            a0 = fmaf(xsh[tg][e], w, a0);
            a1 = fmaf(xsh[tg + 4][e], w, a1);
        }
        h1sh[tg][l] = fmaxf(a0, 0.f);
        h1sh[tg + 4][l] = fmaxf(a1, 0.f);
    }
    __syncthreads();
    {   // h2 = relu(h1@g2+gb2): 8 groups of 32, one token each
        int m = tid & 31, tok = tid >> 5;
        float a = gb2[m];
#pragma unroll 8
        for (int l = 0; l < 64; ++l) a = fmaf(h1sh[tok][l], g2[l * 32 + m], a);
        h2sh[tok][m] = fmaxf(a, 0.f);
    }
    __syncthreads();
    if (tid < 8) {
        float a = gb3[0];
#pragma unroll 8
        for (int m = 0; m < 32; ++m) a = fmaf(h2sh[tid][m], g3[m], a);
        gsh[tid] = 1.f / (1.f + expf(-a));
    }
    __syncthreads();
    {   // comp hidden = relu(x@c1+cb1)  (reuse h2sh)
        int m = tid & 31, tok = tid >> 5;
        float a = cb1[m];
#pragma unroll 8
        for (int e = 0; e < 512; ++e) a = fmaf(xsh[tok][e], c1[e * 32 + m], a);
        h2sh[tok][m] = fmaxf(a, 0.f);
    }
    __syncthreads();
    if (tid < 8) {
        float a = cb2[0];
#pragma unroll 8
        for (int m = 0; m < 32; ++m) a = fmaf(h2sh[tid][m], c2[m], a);
        float comp = 1.f / (1.f + expf(-a));
        float comb = 0.7f * gsh[tid] + 0.3f * comp;
        int t = (int)ceilf(comb * 20.f);
        t = t < 1 ? 1 : (t > 20 ? 20 : t);
        Ti[tok0 + tid] = t;
    }
}

// ---------------------------------------------------------------------------
// LIF + window mask. One wave per (token, head). lane = channel within head.
// mode 0 (q): qpack[bh*512+i][t]  mode 1 (k): kpack[bh*512+j][t]
// mode 2 (v): per-channel masked spike count -> vmean[bh*512+i][d]
// ---------------------------------------------------------------------------
__global__ __launch_bounds__(256) void lif_kernel(const float* __restrict__ q,
    const float* __restrict__ k, const float* __restrict__ v,
    const int* __restrict__ Ti,
    const float* __restrict__ alphap, const float* __restrict__ betap,
    u64* __restrict__ qpack, u64* __restrict__ kpack,
    float* __restrict__ vmean)
{
    int mode = blockIdx.y;
    const float* src = (mode == 0) ? q : (mode == 1) ? k : v;
    int w = blockIdx.x * 4 + (threadIdx.x >> 6);   // 0..16383
    int lane = threadIdx.x & 63;
    int token = w >> 3;
    int h = w & 7;
    float xin = src[(size_t)token * 512 + h * 64 + lane];
    int T = Ti[token];
    float alpha = alphap[0], beta = betap[0];
    float vm = 0.f, isyn = 0.f;
    u64 myword = 0ull;
    int cnt = 0;
#pragma unroll
    for (int t = 0; t < TMAX; ++t) {
        isyn = alpha * isyn + xin;
        vm = beta * vm + isyn;
        bool sp = vm >= 1.0f;
        if (sp) vm = 0.f;
        bool msk = sp && (t < T);
        if (mode < 2) {
            u64 word = __ballot(msk ? 1 : 0);
            if (lane == t) myword = word;
        } else {
            cnt += msk ? 1 : 0;
        }
    }
    int b = token >> 9, i = token & 511;
    size_t bh = (size_t)(b * 8 + h);
    if (mode == 0) { if (lane < TMAX) qpack[(bh * 512 + i) * TMAX + lane] = myword; }
    else if (mode == 1) { if (lane < TMAX) kpack[(bh * 512 + i) * TMAX + lane] = myword; }
    else { vmean[(bh * 512 + i) * 64 + lane] = (float)cnt * 0.05f; }
}

// ---------------------------------------------------------------------------
// attn: 512 threads (8 waves), 1024 blocks -> 4 blocks/CU.
// Phase 1 scores: thread owns column j; q words wave-uniform (SGPR).
// Phase 2 softmax: thread (row, jc) holds 16 p in regs, writes in place.
// Phase 3 PV: thread (seg, d): 16 row-accumulators over 64-j segment;
//             V read once per block; p via wave-uniform LDS broadcast.
// Phase 4 reduce over 8 segments (partials reuse s_lds).
// ---------------------------------------------------------------------------
__global__ __launch_bounds__(512) void attn_kernel(
    const u64* __restrict__ qpack,
    const u64* __restrict__ kpack,
    const float* __restrict__ vmean,
    float* __restrict__ ctx)
{
    __shared__ float s_lds[16][520];   // 33.3 KB; also reused for PV partials
    __shared__ float inv_lds[16];

    int tid = threadIdx.x;
    // XCD-bijective swizzle: 1024 = 8 XCDs x 128 -> 4 consecutive bh per XCD
    int bid = blockIdx.x;
    int swz = (bid & 7) * 128 + (bid >> 3);
    int bh = swz >> 5;                 // 0..31 (B*NH = 32)
    int i0 = (swz & 31) << 4;

    // ---- Phase 1: scores; thread owns column j = tid (t-outer, 16 int accs)
    {
        int j = tid;
        const ulonglong2* kc = (const ulonglong2*)(kpack + ((size_t)bh * 512 + j) * TMAX);
        int acc[16];
#pragma unroll
        for (int i = 0; i < 16; ++i) acc[i] = 0;
#pragma unroll
        for (int t2 = 0; t2 < TMAX / 2; ++t2) {
            ulonglong2 u = kc[t2];
#pragma unroll
            for (int i = 0; i < 16; ++i) {
                const u64* qrow = qpack + ((size_t)bh * 512 + i0 + i) * TMAX;  // uniform
                acc[i] += __popcll(qrow[2 * t2] & u.x) + __popcll(qrow[2 * t2 + 1] & u.y);
            }
        }
#pragma unroll
        for (int i = 0; i < 16; ++i) s_lds[i][j] = 0.125f * (float)acc[i];
    }
    __syncthreads();

    // ---- Phase 2: softmax; thread (row, jc) holds its 16 p in registers
    {
        int row = tid >> 5, jc = tid & 31;
        float pv[16];
        float m = -1e30f;
#pragma unroll
        for (int s = 0; s < 16; ++s) {
            pv[s] = s_lds[row][jc + s * 32];
            m = fmaxf(m, pv[s]);
        }
#pragma unroll
        for (int o = 1; o < 32; o <<= 1) m = fmaxf(m, __shfl_xor(m, o));
        float lsum = 0.f;
#pragma unroll
        for (int s = 0; s < 16; ++s) {
            pv[s] = __expf(pv[s] - m);
            lsum += pv[s];
        }
#pragma unroll
        for (int o = 1; o < 32; o <<= 1) lsum += __shfl_xor(lsum, o);
        if (jc == 0) inv_lds[row] = 1.f / lsum;
        // in-place write (own addresses only -> no barrier needed before)
#pragma unroll
        for (int s = 0; s < 16; ++s) s_lds[row][jc + s * 32] = pv[s];
    }
    __syncthreads();

    // ---- Phase 3: PV; thread (seg, d) accumulates 16 rows over 64 j ------
    float pacc[16];
#pragma unroll
    for (int i = 0; i < 16; ++i) pacc[i] = 0.f;
    {
        int seg = tid >> 6, d = tid & 63;
        const float* vcol = vmean + (size_t)bh * 512 * 64 + d;
        int jbase = seg * 64;
        for (int jj = 0; jj < 64; ++jj) {
            int j = jbase + jj;
            float vv = vcol[(size_t)j * 64];
#pragma unroll
            for (int i = 0; i < 16; ++i)
                pacc[i] = fmaf(s_lds[i][j], vv, pacc[i]);   // p broadcast (uniform j)
        }
    }
    __syncthreads();

    // ---- Phase 4: partials -> s_lds (as raw), reduce over segs -----------
    {
        float* praw = &s_lds[0][0];
        int seg = tid >> 6, d = tid & 63;
#pragma unroll
        for (int i = 0; i < 16; ++i) praw[seg * 1024 + i * 64 + d] = pacc[i];
    }
    __syncthreads();
    {
        const float* praw = &s_lds[0][0];
        int i = tid >> 5, d2 = (tid & 31) * 2;
        float o0 = 0.f, o1 = 0.f;
#pragma unroll
        for (int seg = 0; seg < 8; ++seg) {
            const float2 pp = *(const float2*)&praw[seg * 1024 + i * 64 + d2];
            o0 += pp.x;
            o1 += pp.y;
        }
        float inv = inv_lds[i];
        o0 *= inv; o1 *= inv;
        int b = bh >> 3, h = bh & 7;
        int row = b * 512 + i0 + i;
        *(float2*)(&ctx[(size_t)row * 512 + h * 64 + d2]) = (float2){o0, o1};
    }
}

// ---------------------------------------------------------------------------
extern "C" void kernel_launch(void* const* d_in, const int* in_sizes, int n_in,
                              void* d_out, int out_size, void* d_ws, size_t ws_size,
                              hipStream_t stream) {
    const float* x   = (const float*)d_in[0];
    const float* Wq  = (const float*)d_in[1];
    const float* Wk  = (const float*)d_in[2];
    const float* Wv  = (const float*)d_in[3];
    const float* Wo  = (const float*)d_in[4];
    const float* bo  = (const float*)d_in[5];
    const float* g1  = (const float*)d_in[6];
    const float* gb1 = (const float*)d_in[7];
    const float* g2  = (const float*)d_in[8];
    const float* gb2 = (const float*)d_in[9];
    const float* g3  = (const float*)d_in[10];
    const float* gb3 = (const float*)d_in[11];
    const float* c1  = (const float*)d_in[12];
    const float* cb1 = (const float*)d_in[13];
    const float* c2  = (const float*)d_in[14];
    const float* cb2 = (const float*)d_in[15];
    const float* alpha = (const float*)d_in[16];
    const float* beta  = (const float*)d_in[17];
    float* out = (float*)d_out;

    char* w = (char*)d_ws;
    float* q    = (float*)w;                         w += (size_t)BS * E_ * 4;
    float* kbuf = (float*)w;                         w += (size_t)BS * E_ * 4;
    float* vbuf = (float*)w;                         w += (size_t)BS * E_ * 4;
    int* Ti     = (int*)w;                           w += (size_t)BS * 4;
    u64* qpack  = (u64*)w;                           w += (size_t)BS * NH * TMAX * 8;
    u64* kpack  = (u64*)w;                           w += (size_t)BS * NH * TMAX * 8;
    float* vmean = (float*)w;                        w += (size_t)BS * E_ * 4;
    float* ctx = q;   // safe alias: q fully consumed by lif_kernel before attn

    gemm_qkv_kernel<<<dim3(8, 16, 3), 256, 0, stream>>>(x, Wq, Wk, Wv, q, kbuf, vbuf);
    mlp_gate_kernel<<<256, 256, 0, stream>>>(x, g1, gb1, g2, gb2, g3, gb3,
                                             c1, cb1, c2, cb2, Ti);
    lif_kernel<<<dim3(4096, 3), 256, 0, stream>>>(q, kbuf, vbuf, Ti, alpha, beta,
                                                  qpack, kpack, vmean);
    attn_kernel<<<1024, 512, 0, stream>>>(qpack, kpack, vmean, ctx);
    gemm_out_kernel<<<dim3(8, 16), 256, 0, stream>>>(ctx, Wo, bo, out);
}

// Round 6
// 225.001 us; speedup vs baseline: 2.5967x; 1.0158x over previous
//
#include <hip/hip_runtime.h>
#include <stdint.h>

#define BS 2048   // B*S
#define E_ 512
#define NH 8
#define HD 64
#define TMAX 20

typedef unsigned long long u64;

// ---------------------------------------------------------------------------
// f32 tiled GEMM: C[M,N] = A[M,K] @ W[K,N] (+bias). BM=128 BN=64 BK=16,
// 256 threads, 8x4 micro-tile. All dims divide exactly for this problem.
// ---------------------------------------------------------------------------
__device__ __forceinline__ void gemm_body(const float* __restrict__ A,
    const float* __restrict__ W, const float* __restrict__ bias,
    float* __restrict__ C, int M, int N, int K)
{
    __shared__ __align__(16) float As[16][132];   // transposed A tile, padded
    __shared__ __align__(16) float Bs[16][64];
    int tid = threadIdx.x;
    int m0 = blockIdx.y * 128;
    int n0 = blockIdx.x * 64;
    int ty = tid >> 4, tx = tid & 15;
    float acc[8][4];
#pragma unroll
    for (int r = 0; r < 8; ++r)
#pragma unroll
        for (int c = 0; c < 4; ++c) acc[r][c] = 0.f;

    int arow = tid >> 2;       // 0..63
    int acol4 = tid & 3;       // 0..3
    int brow = tid >> 4;       // 0..15
    int bcol4 = tid & 15;

    for (int k0 = 0; k0 < K; k0 += 16) {
#pragma unroll
        for (int rr = 0; rr < 2; ++rr) {
            int r = arow + rr * 64;
            float4 va = *(const float4*)(&A[(size_t)(m0 + r) * K + k0 + acol4 * 4]);
            As[acol4 * 4 + 0][r] = va.x;
            As[acol4 * 4 + 1][r] = va.y;
            As[acol4 * 4 + 2][r] = va.z;
            As[acol4 * 4 + 3][r] = va.w;
        }
        float4 vb = *(const float4*)(&W[(size_t)(k0 + brow) * N + n0 + bcol4 * 4]);
        *(float4*)(&Bs[brow][bcol4 * 4]) = vb;
        __syncthreads();
#pragma unroll
        for (int kk = 0; kk < 16; ++kk) {
            float4 a0 = *(const float4*)(&As[kk][ty * 8]);
            float4 a1 = *(const float4*)(&As[kk][ty * 8 + 4]);
            float4 b4 = *(const float4*)(&Bs[kk][tx * 4]);
            float ar[8] = {a0.x, a0.y, a0.z, a0.w, a1.x, a1.y, a1.z, a1.w};
            float br[4] = {b4.x, b4.y, b4.z, b4.w};
#pragma unroll
            for (int r = 0; r < 8; ++r)
#pragma unroll
                for (int c = 0; c < 4; ++c)
                    acc[r][c] = fmaf(ar[r], br[c], acc[r][c]);
        }
        __syncthreads();
    }
#pragma unroll
    for (int r = 0; r < 8; ++r) {
        int row = m0 + ty * 8 + r;
        float4 o;
        o.x = acc[r][0]; o.y = acc[r][1]; o.z = acc[r][2]; o.w = acc[r][3];
        if (bias) {
            o.x += bias[n0 + tx * 4 + 0];
            o.y += bias[n0 + tx * 4 + 1];
            o.z += bias[n0 + tx * 4 + 2];
            o.w += bias[n0 + tx * 4 + 3];
        }
        *(float4*)(&C[(size_t)row * N + n0 + tx * 4]) = o;
    }
}

__global__ __launch_bounds__(256) void gemm_qkv_kernel(const float* __restrict__ x,
    const float* __restrict__ Wq, const float* __restrict__ Wk, const float* __restrict__ Wv,
    float* __restrict__ q, float* __restrict__ k, float* __restrict__ v)
{
    int z = blockIdx.z;
    const float* W = (z == 0) ? Wq : (z == 1) ? Wk : Wv;
    float* C = (z == 0) ? q : (z == 1) ? k : v;
    gemm_body(x, W, nullptr, C, BS, E_, E_);
}

__global__ __launch_bounds__(256) void gemm_out_kernel(const float* __restrict__ ctx,
    const float* __restrict__ Wo, const float* __restrict__ bo, float* __restrict__ out)
{
    gemm_body(ctx, Wo, bo, out, BS, E_, E_);
}

// ---------------------------------------------------------------------------
// Gate/complexity MLPs -> T_i. 8 tokens per 256-thread block (256 blocks).
// ---------------------------------------------------------------------------
__global__ __launch_bounds__(256) void mlp_gate_kernel(const float* __restrict__ x,
    const float* __restrict__ g1, const float* __restrict__ gb1,
    const float* __restrict__ g2, const float* __restrict__ gb2,
    const float* __restrict__ g3, const float* __restrict__ gb3,
    const float* __restrict__ c1, const float* __restrict__ cb1,
    const float* __restrict__ c2, const float* __restrict__ cb2,
    int* __restrict__ Ti)
{
    __shared__ __align__(16) float xsh[8][512];
    __shared__ float h1sh[8][64];
    __shared__ float h2sh[8][32];
    __shared__ float gsh[8];
    int tid = threadIdx.x;
    int tok0 = blockIdx.x * 8;

    const float4* xg = (const float4*)(&x[(size_t)tok0 * 512]);
    float4* xs4 = (float4*)(&xsh[0][0]);
    for (int i = tid; i < 8 * 128; i += 256) xs4[i] = xg[i];
    __syncthreads();

    {   // h1 = relu(x@g1+gb1): lane l = output ch, wave handles 2 tokens
        int l = tid & 63, tg = tid >> 6;
        float a0 = gb1[l], a1 = a0;
#pragma unroll 8
        for (int e = 0; e < 512; ++e) {
            float w = g1[e * 64 + l];
            a0 = fmaf(xsh[tg][e], w, a0);
            a1 = fmaf(xsh[tg + 4][e], w, a1);
        }
        h1sh[tg][l] = fmaxf(a0, 0.f);
        h1sh[tg + 4][l] = fmaxf(a1, 0.f);
    }
    __syncthreads();
    {   // h2 = relu(h1@g2+gb2): 8 groups of 32, one token each
        int m = tid & 31, tok = tid >> 5;
        float a = gb2[m];
#pragma unroll 8
        for (int l = 0; l < 64; ++l) a = fmaf(h1sh[tok][l], g2[l * 32 + m], a);
        h2sh[tok][m] = fmaxf(a, 0.f);
    }
    __syncthreads();
    if (tid < 8) {
        float a = gb3[0];
#pragma unroll 8
        for (int m = 0; m < 32; ++m) a = fmaf(h2sh[tid][m], g3[m], a);
        gsh[tid] = 1.f / (1.f + expf(-a));
    }
    __syncthreads();
    {   // comp hidden = relu(x@c1+cb1)  (reuse h2sh)
        int m = tid & 31, tok = tid >> 5;
        float a = cb1[m];
#pragma unroll 8
        for (int e = 0; e < 512; ++e) a = fmaf(xsh[tok][e], c1[e * 32 + m], a);
        h2sh[tok][m] = fmaxf(a, 0.f);
    }
    __syncthreads();
    if (tid < 8) {
        float a = cb2[0];
#pragma unroll 8
        for (int m = 0; m < 32; ++m) a = fmaf(h2sh[tid][m], c2[m], a);
        float comp = 1.f / (1.f + expf(-a));
        float comb = 0.7f * gsh[tid] + 0.3f * comp;
        int t = (int)ceilf(comb * 20.f);
        t = t < 1 ? 1 : (t > 20 ? 20 : t);
        Ti[tok0 + tid] = t;
    }
}

// ---------------------------------------------------------------------------
// LIF + window mask. One wave per (token, head). lane = channel within head.
// mode 0 (q): qpack[bh*512+i][t]  mode 1 (k): kpack[bh*512+j][t]
// mode 2 (v): per-channel masked spike count -> vmean[bh*512+i][d]
// ---------------------------------------------------------------------------
__global__ __launch_bounds__(256) void lif_kernel(const float* __restrict__ q,
    const float* __restrict__ k, const float* __restrict__ v,
    const int* __restrict__ Ti,
    const float* __restrict__ alphap, const float* __restrict__ betap,
    u64* __restrict__ qpack, u64* __restrict__ kpack,
    float* __restrict__ vmean)
{
    int mode = blockIdx.y;
    const float* src = (mode == 0) ? q : (mode == 1) ? k : v;
    int w = blockIdx.x * 4 + (threadIdx.x >> 6);   // 0..16383
    int lane = threadIdx.x & 63;
    int token = w >> 3;
    int h = w & 7;
    float xin = src[(size_t)token * 512 + h * 64 + lane];
    int T = Ti[token];
    float alpha = alphap[0], beta = betap[0];
    float vm = 0.f, isyn = 0.f;
    u64 myword = 0ull;
    int cnt = 0;
#pragma unroll
    for (int t = 0; t < TMAX; ++t) {
        isyn = alpha * isyn + xin;
        vm = beta * vm + isyn;
        bool sp = vm >= 1.0f;
        if (sp) vm = 0.f;
        bool msk = sp && (t < T);
        if (mode < 2) {
            u64 word = __ballot(msk ? 1 : 0);
            if (lane == t) myword = word;
        } else {
            cnt += msk ? 1 : 0;
        }
    }
    int b = token >> 9, i = token & 511;
    size_t bh = (size_t)(b * 8 + h);
    if (mode == 0) { if (lane < TMAX) qpack[(bh * 512 + i) * TMAX + lane] = myword; }
    else if (mode == 1) { if (lane < TMAX) kpack[(bh * 512 + i) * TMAX + lane] = myword; }
    else { vmean[(bh * 512 + i) * 64 + lane] = (float)cnt * 0.05f; }
}

// ---------------------------------------------------------------------------
// attn: 512 threads (8 waves), 1024 blocks, LDS = exactly 40960 B -> 4/CU.
// One overlaid LDS buffer praw[10240]:
//   Phase 1 scores  S[i][j]  at praw[i*544 + j]       (16x544, 34.8 KB)
//   Phase 2 softmax -> writes NORMALIZED p transposed p_t[j][i] at
//                    praw[j*20 + i]  (pitch 20 floats = 80 B, 16B-aligned;
//                    write conflict 4-way one-time; read = uniform b128)
//   Phase 3 PV: thread (seg,d) accumulates 16 rows over its 64-j segment;
//               p via 4x wave-uniform ds_read_b128 per j; V once per block.
//   Phase 4 partials at praw[seg*1024 + i*64 + d], reduce over 8 segs.
// ---------------------------------------------------------------------------
__global__ __launch_bounds__(512) void attn_kernel(
    const u64* __restrict__ qpack,
    const u64* __restrict__ kpack,
    const float* __restrict__ vmean,
    float* __restrict__ ctx)
{
    __shared__ __align__(16) float praw[10240];   // 40960 B exactly

    int tid = threadIdx.x;
    // XCD-bijective swizzle: 1024 = 8 XCDs x 128 -> 4 consecutive bh per XCD
    int bid = blockIdx.x;
    int swz = (bid & 7) * 128 + (bid >> 3);
    int bh = swz >> 5;                 // 0..31 (B*NH = 32)
    int i0 = (swz & 31) << 4;

    // ---- Phase 1: scores; thread owns column j = tid (t-outer, 16 int accs)
    {
        int j = tid;
        const ulonglong2* kc = (const ulonglong2*)(kpack + ((size_t)bh * 512 + j) * TMAX);
        int acc[16];
#pragma unroll
        for (int i = 0; i < 16; ++i) acc[i] = 0;
#pragma unroll
        for (int t2 = 0; t2 < TMAX / 2; ++t2) {
            ulonglong2 u = kc[t2];
#pragma unroll
            for (int i = 0; i < 16; ++i) {
                const u64* qrow = qpack + ((size_t)bh * 512 + i0 + i) * TMAX;  // uniform
                acc[i] += __popcll(qrow[2 * t2] & u.x) + __popcll(qrow[2 * t2 + 1] & u.y);
            }
        }
#pragma unroll
        for (int i = 0; i < 16; ++i) praw[i * 544 + j] = 0.125f * (float)acc[i];
    }
    __syncthreads();

    // ---- Phase 2: softmax; read strided, write back transposed+normalized
    {
        int row = tid >> 5, jc = tid & 31;
        float pv[16];
        float m = -1e30f;
#pragma unroll
        for (int s = 0; s < 16; ++s) {
            pv[s] = praw[row * 544 + jc + s * 32];
            m = fmaxf(m, pv[s]);
        }
#pragma unroll
        for (int o = 1; o < 32; o <<= 1) m = fmaxf(m, __shfl_xor(m, o));
        float lsum = 0.f;
#pragma unroll
        for (int s = 0; s < 16; ++s) {
            pv[s] = __expf(pv[s] - m);
            lsum += pv[s];
        }
#pragma unroll
        for (int o = 1; o < 32; o <<= 1) lsum += __shfl_xor(lsum, o);
        float inv = 1.f / lsum;
        __syncthreads();   // all strided reads done before transposed writes
#pragma unroll
        for (int s = 0; s < 16; ++s)
            praw[(jc + s * 32) * 20 + row] = pv[s] * inv;
    }
    __syncthreads();

    // ---- Phase 3: PV; thread (seg, d) accumulates 16 rows over 64 j ------
    float pacc[16];
#pragma unroll
    for (int i = 0; i < 16; ++i) pacc[i] = 0.f;
    {
        int seg = tid >> 6, d = tid & 63;
        const float* vcol = vmean + (size_t)bh * 512 * 64 + d;
        int jbase = seg * 64;
#pragma unroll 4
        for (int jj = 0; jj < 64; ++jj) {
            int j = jbase + jj;
            const float4* pt = (const float4*)&praw[j * 20];   // uniform addr
            float4 pa = pt[0], pb = pt[1], pc = pt[2], pd = pt[3];
            float vv = vcol[(size_t)j * 64];
            pacc[0]  = fmaf(pa.x, vv, pacc[0]);  pacc[1]  = fmaf(pa.y, vv, pacc[1]);
            pacc[2]  = fmaf(pa.z, vv, pacc[2]);  pacc[3]  = fmaf(pa.w, vv, pacc[3]);
            pacc[4]  = fmaf(pb.x, vv, pacc[4]);  pacc[5]  = fmaf(pb.y, vv, pacc[5]);
            pacc[6]  = fmaf(pb.z, vv, pacc[6]);  pacc[7]  = fmaf(pb.w, vv, pacc[7]);
            pacc[8]  = fmaf(pc.x, vv, pacc[8]);  pacc[9]  = fmaf(pc.y, vv, pacc[9]);
            pacc[10] = fmaf(pc.z, vv, pacc[10]); pacc[11] = fmaf(pc.w, vv, pacc[11]);
            pacc[12] = fmaf(pd.x, vv, pacc[12]); pacc[13] = fmaf(pd.y, vv, pacc[13]);
            pacc[14] = fmaf(pd.z, vv, pacc[14]); pacc[15] = fmaf(pd.w, vv, pacc[15]);
        }
    }
    __syncthreads();   // protect praw before overwriting with partials

    // ---- Phase 4: partials -> praw, reduce over 8 segments ---------------
    {
        int seg = tid >> 6, d = tid & 63;
#pragma unroll
        for (int i = 0; i < 16; ++i) praw[seg * 1024 + i * 64 + d] = pacc[i];
    }
    __syncthreads();
    {
        int i = tid >> 5, d2 = (tid & 31) * 2;
        float o0 = 0.f, o1 = 0.f;
#pragma unroll
        for (int seg = 0; seg < 8; ++seg) {
            const float2 pp = *(const float2*)&praw[seg * 1024 + i * 64 + d2];
            o0 += pp.x;
            o1 += pp.y;
        }
        int b = bh >> 3, h = bh & 7;
        int row = b * 512 + i0 + i;
        *(float2*)(&ctx[(size_t)row * 512 + h * 64 + d2]) = (float2){o0, o1};
    }
}

// ---------------------------------------------------------------------------
extern "C" void kernel_launch(void* const* d_in, const int* in_sizes, int n_in,
                              void* d_out, int out_size, void* d_ws, size_t ws_size,
                              hipStream_t stream) {
    const float* x   = (const float*)d_in[0];
    const float* Wq  = (const float*)d_in[1];
    const float* Wk  = (const float*)d_in[2];
    const float* Wv  = (const float*)d_in[3];
    const float* Wo  = (const float*)d_in[4];
    const float* bo  = (const float*)d_in[5];
    const float* g1  = (const float*)d_in[6];
    const float* gb1 = (const float*)d_in[7];
    const float* g2  = (const float*)d_in[8];
    const float* gb2 = (const float*)d_in[9];
    const float* g3  = (const float*)d_in[10];
    const float* gb3 = (const float*)d_in[11];
    const float* c1  = (const float*)d_in[12];
    const float* cb1 = (const float*)d_in[13];
    const float* c2  = (const float*)d_in[14];
    const float* cb2 = (const float*)d_in[15];
    const float* alpha = (const float*)d_in[16];
    const float* beta  = (const float*)d_in[17];
    float* out = (float*)d_out;

    char* w = (char*)d_ws;
    float* q    = (float*)w;                         w += (size_t)BS * E_ * 4;
    float* kbuf = (float*)w;                         w += (size_t)BS * E_ * 4;
    float* vbuf = (float*)w;                         w += (size_t)BS * E_ * 4;
    int* Ti     = (int*)w;                           w += (size_t)BS * 4;
    u64* qpack  = (u64*)w;                           w += (size_t)BS * NH * TMAX * 8;
    u64* kpack  = (u64*)w;                           w += (size_t)BS * NH * TMAX * 8;
    float* vmean = (float*)w;                        w += (size_t)BS * E_ * 4;
    float* ctx = q;   // safe alias: q fully consumed by lif_kernel before attn

    gemm_qkv_kernel<<<dim3(8, 16, 3), 256, 0, stream>>>(x, Wq, Wk, Wv, q, kbuf, vbuf);
    mlp_gate_kernel<<<256, 256, 0, stream>>>(x, g1, gb1, g2, gb2, g3, gb3,
                                             c1, cb1, c2, cb2, Ti);
    lif_kernel<<<dim3(4096, 3), 256, 0, stream>>>(q, kbuf, vbuf, Ti, alpha, beta,
                                                  qpack, kpack, vmean);
    attn_kernel<<<1024, 512, 0, stream>>>(qpack, kpack, vmean, ctx);
    gemm_out_kernel<<<dim3(8, 16), 256, 0, stream>>>(ctx, Wo, bo, out);
}

// Round 7
// 198.978 us; speedup vs baseline: 2.9363x; 1.1308x over previous
//
#include <hip/hip_runtime.h>
#include <stdint.h>

#define BS 2048   // B*S
#define E_ 512
#define NH 8
#define HD 64
#define TMAX 20

typedef unsigned long long u64;
typedef unsigned short ushort_t;

using bf8  = __attribute__((ext_vector_type(8))) short;   // 8 bf16 (4 VGPR)
using f4a  = __attribute__((ext_vector_type(4))) float;   // 4 f32 acc

// ---------------------------------------------------------------------------
// f32 <-> bf16 split helpers (RNE)
// ---------------------------------------------------------------------------
__device__ __forceinline__ unsigned short f2bf(float f) {
    unsigned u = __float_as_uint(f);
    return (unsigned short)((u + 0x7FFFu + ((u >> 16) & 1u)) >> 16);
}
__device__ __forceinline__ float bf2f(unsigned short h) {
    return __uint_as_float(((unsigned)h) << 16);
}
__device__ __forceinline__ void split1(float x, unsigned short& h, unsigned short& l) {
    h = f2bf(x);
    l = f2bf(x - bf2f(h));
}

// ---------------------------------------------------------------------------
// split x (or ctx): f32 [n] -> hi/lo bf16. n = BS*E_ = 1M, grid 1024x256 (f4)
// ---------------------------------------------------------------------------
__global__ __launch_bounds__(256) void xsplit_kernel(const float* __restrict__ src,
    unsigned short* __restrict__ hi, unsigned short* __restrict__ lo)
{
    int i = blockIdx.x * 256 + threadIdx.x;
    float4 v = ((const float4*)src)[i];
    ushort4 h, l;
    split1(v.x, h.x, l.x);
    split1(v.y, h.y, l.y);
    split1(v.z, h.z, l.z);
    split1(v.w, h.w, l.w);
    ((ushort4*)hi)[i] = h;
    ((ushort4*)lo)[i] = l;
}

// ---------------------------------------------------------------------------
// transpose + split W: W[k][n] f32 -> Wt_hi/lo[n][k] bf16. grid (8,8,4) 256thr
// z=0..2 -> qkv buffer [z][512][512]; z=3 -> Wo buffers.
// ---------------------------------------------------------------------------
__global__ __launch_bounds__(256) void wsplit_kernel(
    const float* __restrict__ Wq, const float* __restrict__ Wk,
    const float* __restrict__ Wv, const float* __restrict__ Wo,
    unsigned short* __restrict__ qkv_hi, unsigned short* __restrict__ qkv_lo,
    unsigned short* __restrict__ o_hi, unsigned short* __restrict__ o_lo)
{
    __shared__ float t[64][65];
    int z = blockIdx.z;
    const float* W = (z == 0) ? Wq : (z == 1) ? Wk : (z == 2) ? Wv : Wo;
    unsigned short* dhi = (z < 3) ? qkv_hi + (size_t)z * 512 * 512 : o_hi;
    unsigned short* dlo = (z < 3) ? qkv_lo + (size_t)z * 512 * 512 : o_lo;
    int k0 = blockIdx.y * 64, n0 = blockIdx.x * 64;
    int tid = threadIdx.x;
    int r = tid >> 4, c4 = (tid & 15) * 4;
#pragma unroll
    for (int j = 0; j < 4; ++j) {
        int row = r + j * 16;
        float4 v = *(const float4*)&W[(size_t)(k0 + row) * 512 + n0 + c4];
        t[row][c4 + 0] = v.x; t[row][c4 + 1] = v.y;
        t[row][c4 + 2] = v.z; t[row][c4 + 3] = v.w;
    }
    __syncthreads();
#pragma unroll
    for (int j = 0; j < 4; ++j) {
        int n = r + j * 16;
        ushort4 h, l;
        split1(t[c4 + 0][n], h.x, l.x);
        split1(t[c4 + 1][n], h.y, l.y);
        split1(t[c4 + 2][n], h.z, l.z);
        split1(t[c4 + 3][n], h.w, l.w);
        *(ushort4*)&dhi[(size_t)(n0 + n) * 512 + k0 + c4] = h;
        *(ushort4*)&dlo[(size_t)(n0 + n) * 512 + k0 + c4] = l;
    }
}

// ---------------------------------------------------------------------------
// split-bf16 MFMA GEMM: C[z] = A @ W[z] (+bias). A as hi/lo bf16 [2048][512],
// W as transposed hi/lo bf16 [z][512(n)][512(k)]. 3-term split:
// C = Ah.Bh + Ah.Bl + Al.Bh. LDS-free, barrier-free: wave = 32x32 out tile.
// grid (8 n64, 32 m64, z), 256 thr (4 waves). Frag mapping (m89-verified):
// A/B: elem[j] = M-or-N index lane&15, k = (lane>>4)*8+j; C: col=lane&15,
// row=(lane>>4)*4+reg.
// ---------------------------------------------------------------------------
__global__ __launch_bounds__(256) void gemm_mfma_kernel(
    const unsigned short* __restrict__ Ahi, const unsigned short* __restrict__ Alo,
    const unsigned short* __restrict__ Bthi, const unsigned short* __restrict__ Btlo,
    float* __restrict__ Cbase, const float* __restrict__ bias,
    int zstride_b, int zstride_c)
{
    int z = blockIdx.z;
    const unsigned short* bh = Bthi + (size_t)z * zstride_b;
    const unsigned short* bl = Btlo + (size_t)z * zstride_b;
    float* C = Cbase + (size_t)z * zstride_c;

    int tid = threadIdx.x;
    int w = tid >> 6, lane = tid & 63;
    int lrow = lane & 15;
    int lk = (lane >> 4) * 8;
    int m0 = blockIdx.y * 64 + ((w >> 1) << 5);
    int n0 = blockIdx.x * 64 + ((w & 1) << 5);

    const size_t ar0 = (size_t)(m0 + lrow) * 512 + lk;
    const size_t ar1 = ar0 + (size_t)16 * 512;
    const size_t br0 = (size_t)(n0 + lrow) * 512 + lk;
    const size_t br1 = br0 + (size_t)16 * 512;

    f4a z4 = {0.f, 0.f, 0.f, 0.f};
    f4a a00 = z4, a01 = z4, a10 = z4, a11 = z4;

#pragma unroll 2
    for (int k0 = 0; k0 < 512; k0 += 32) {
        bf8 ah0 = *(const bf8*)&Ahi[ar0 + k0];
        bf8 ah1 = *(const bf8*)&Ahi[ar1 + k0];
        bf8 al0 = *(const bf8*)&Alo[ar0 + k0];
        bf8 al1 = *(const bf8*)&Alo[ar1 + k0];
        bf8 bh0 = *(const bf8*)&bh[br0 + k0];
        bf8 bh1 = *(const bf8*)&bh[br1 + k0];
        bf8 bl0 = *(const bf8*)&bl[br0 + k0];
        bf8 bl1 = *(const bf8*)&bl[br1 + k0];
        // hi*hi
        a00 = __builtin_amdgcn_mfma_f32_16x16x32_bf16(ah0, bh0, a00, 0, 0, 0);
        a01 = __builtin_amdgcn_mfma_f32_16x16x32_bf16(ah0, bh1, a01, 0, 0, 0);
        a10 = __builtin_amdgcn_mfma_f32_16x16x32_bf16(ah1, bh0, a10, 0, 0, 0);
        a11 = __builtin_amdgcn_mfma_f32_16x16x32_bf16(ah1, bh1, a11, 0, 0, 0);
        // hi*lo
        a00 = __builtin_amdgcn_mfma_f32_16x16x32_bf16(ah0, bl0, a00, 0, 0, 0);
        a01 = __builtin_amdgcn_mfma_f32_16x16x32_bf16(ah0, bl1, a01, 0, 0, 0);
        a10 = __builtin_amdgcn_mfma_f32_16x16x32_bf16(ah1, bl0, a10, 0, 0, 0);
        a11 = __builtin_amdgcn_mfma_f32_16x16x32_bf16(ah1, bl1, a11, 0, 0, 0);
        // lo*hi
        a00 = __builtin_amdgcn_mfma_f32_16x16x32_bf16(al0, bh0, a00, 0, 0, 0);
        a01 = __builtin_amdgcn_mfma_f32_16x16x32_bf16(al0, bh1, a01, 0, 0, 0);
        a10 = __builtin_amdgcn_mfma_f32_16x16x32_bf16(al1, bh0, a10, 0, 0, 0);
        a11 = __builtin_amdgcn_mfma_f32_16x16x32_bf16(al1, bh1, a11, 0, 0, 0);
    }

    int orow = (lane >> 4) * 2;   // *4 /2 ... row base = (lane>>4)*4
    orow = (lane >> 4) * 4;
    {
        int col0 = n0 + lrow, col1 = n0 + 16 + lrow;
        float b0 = bias ? bias[col0] : 0.f;
        float b1 = bias ? bias[col1] : 0.f;
#pragma unroll
        for (int r = 0; r < 4; ++r) {
            C[(size_t)(m0 + orow + r) * 512 + col0]      = a00[r] + b0;
            C[(size_t)(m0 + orow + r) * 512 + col1]      = a01[r] + b1;
            C[(size_t)(m0 + 16 + orow + r) * 512 + col0] = a10[r] + b0;
            C[(size_t)(m0 + 16 + orow + r) * 512 + col1] = a11[r] + b1;
        }
    }
}

// ---------------------------------------------------------------------------
// Gate/complexity MLPs -> T_i. 8 tokens per 256-thread block (256 blocks).
// ---------------------------------------------------------------------------
__global__ __launch_bounds__(256) void mlp_gate_kernel(const float* __restrict__ x,
    const float* __restrict__ g1, const float* __restrict__ gb1,
    const float* __restrict__ g2, const float* __restrict__ gb2,
    const float* __restrict__ g3, const float* __restrict__ gb3,
    const float* __restrict__ c1, const float* __restrict__ cb1,
    const float* __restrict__ c2, const float* __restrict__ cb2,
    int* __restrict__ Ti)
{
    __shared__ __align__(16) float xsh[8][512];
    __shared__ float h1sh[8][64];
    __shared__ float h2sh[8][32];
    __shared__ float gsh[8];
    int tid = threadIdx.x;
    int tok0 = blockIdx.x * 8;

    const float4* xg = (const float4*)(&x[(size_t)tok0 * 512]);
    float4* xs4 = (float4*)(&xsh[0][0]);
    for (int i = tid; i < 8 * 128; i += 256) xs4[i] = xg[i];
    __syncthreads();

    {   // h1 = relu(x@g1+gb1): lane l = output ch, wave handles 2 tokens
        int l = tid & 63, tg = tid >> 6;
        float a0 = gb1[l], a1 = a0;
#pragma unroll 8
        for (int e = 0; e < 512; ++e) {
            float w = g1[e * 64 + l];
            a0 = fmaf(xsh[tg][e], w, a0);
            a1 = fmaf(xsh[tg + 4][e], w, a1);
        }
        h1sh[tg][l] = fmaxf(a0, 0.f);
        h1sh[tg + 4][l] = fmaxf(a1, 0.f);
    }
    __syncthreads();
    {   // h2 = relu(h1@g2+gb2): 8 groups of 32, one token each
        int m = tid & 31, tok = tid >> 5;
        float a = gb2[m];
#pragma unroll 8
        for (int l = 0; l < 64; ++l) a = fmaf(h1sh[tok][l], g2[l * 32 + m], a);
        h2sh[tok][m] = fmaxf(a, 0.f);
    }
    __syncthreads();
    if (tid < 8) {
        float a = gb3[0];
#pragma unroll 8
        for (int m = 0; m < 32; ++m) a = fmaf(h2sh[tid][m], g3[m], a);
        gsh[tid] = 1.f / (1.f + expf(-a));
    }
    __syncthreads();
    {   // comp hidden = relu(x@c1+cb1)  (reuse h2sh)
        int m = tid & 31, tok = tid >> 5;
        float a = cb1[m];
#pragma unroll 8
        for (int e = 0; e < 512; ++e) a = fmaf(xsh[tok][e], c1[e * 32 + m], a);
        h2sh[tok][m] = fmaxf(a, 0.f);
    }
    __syncthreads();
    if (tid < 8) {
        float a = cb2[0];
#pragma unroll 8
        for (int m = 0; m < 32; ++m) a = fmaf(h2sh[tid][m], c2[m], a);
        float comp = 1.f / (1.f + expf(-a));
        float comb = 0.7f * gsh[tid] + 0.3f * comp;
        int t = (int)ceilf(comb * 20.f);
        t = t < 1 ? 1 : (t > 20 ? 20 : t);
        Ti[tok0 + tid] = t;
    }
}

// ---------------------------------------------------------------------------
// LIF + window mask. One wave per (token, head). lane = channel within head.
// mode 0 (q): qpack[bh*512+i][t]  mode 1 (k): kpack[bh*512+j][t]
// mode 2 (v): per-channel masked spike count -> vmean[bh*512+i][d]
// ---------------------------------------------------------------------------
__global__ __launch_bounds__(256) void lif_kernel(const float* __restrict__ q,
    const float* __restrict__ k, const float* __restrict__ v,
    const int* __restrict__ Ti,
    const float* __restrict__ alphap, const float* __restrict__ betap,
    u64* __restrict__ qpack, u64* __restrict__ kpack,
    float* __restrict__ vmean)
{
    int mode = blockIdx.y;
    const float* src = (mode == 0) ? q : (mode == 1) ? k : v;
    int w = blockIdx.x * 4 + (threadIdx.x >> 6);   // 0..16383
    int lane = threadIdx.x & 63;
    int token = w >> 3;
    int h = w & 7;
    float xin = src[(size_t)token * 512 + h * 64 + lane];
    int T = Ti[token];
    float alpha = alphap[0], beta = betap[0];
    float vm = 0.f, isyn = 0.f;
    u64 myword = 0ull;
    int cnt = 0;
#pragma unroll
    for (int t = 0; t < TMAX; ++t) {
        isyn = alpha * isyn + xin;
        vm = beta * vm + isyn;
        bool sp = vm >= 1.0f;
        if (sp) vm = 0.f;
        bool msk = sp && (t < T);
        if (mode < 2) {
            u64 word = __ballot(msk ? 1 : 0);
            if (lane == t) myword = word;
        } else {
            cnt += msk ? 1 : 0;
        }
    }
    int b = token >> 9, i = token & 511;
    size_t bh = (size_t)(b * 8 + h);
    if (mode == 0) { if (lane < TMAX) qpack[(bh * 512 + i) * TMAX + lane] = myword; }
    else if (mode == 1) { if (lane < TMAX) kpack[(bh * 512 + i) * TMAX + lane] = myword; }
    else { vmean[(bh * 512 + i) * 64 + lane] = (float)cnt * 0.05f; }
}

// ---------------------------------------------------------------------------
// attn: 512 threads (8 waves), 1024 blocks, LDS = exactly 40960 B -> 4/CU.
// (unchanged from round 5)
// ---------------------------------------------------------------------------
__global__ __launch_bounds__(512) void attn_kernel(
    const u64* __restrict__ qpack,
    const u64* __restrict__ kpack,
    const float* __restrict__ vmean,
    float* __restrict__ ctx)
{
    __shared__ __align__(16) float praw[10240];   // 40960 B exactly

    int tid = threadIdx.x;
    int bid = blockIdx.x;
    int swz = (bid & 7) * 128 + (bid >> 3);
    int bh = swz >> 5;                 // 0..31 (B*NH = 32)
    int i0 = (swz & 31) << 4;

    // ---- Phase 1: scores; thread owns column j = tid
    {
        int j = tid;
        const ulonglong2* kc = (const ulonglong2*)(kpack + ((size_t)bh * 512 + j) * TMAX);
        int acc[16];
#pragma unroll
        for (int i = 0; i < 16; ++i) acc[i] = 0;
#pragma unroll
        for (int t2 = 0; t2 < TMAX / 2; ++t2) {
            ulonglong2 u = kc[t2];
#pragma unroll
            for (int i = 0; i < 16; ++i) {
                const u64* qrow = qpack + ((size_t)bh * 512 + i0 + i) * TMAX;  // uniform
                acc[i] += __popcll(qrow[2 * t2] & u.x) + __popcll(qrow[2 * t2 + 1] & u.y);
            }
        }
#pragma unroll
        for (int i = 0; i < 16; ++i) praw[i * 544 + j] = 0.125f * (float)acc[i];
    }
    __syncthreads();

    // ---- Phase 2: softmax; read strided, write back transposed+normalized
    {
        int row = tid >> 5, jc = tid & 31;
        float pv[16];
        float m = -1e30f;
#pragma unroll
        for (int s = 0; s < 16; ++s) {
            pv[s] = praw[row * 544 + jc + s * 32];
            m = fmaxf(m, pv[s]);
        }
#pragma unroll
        for (int o = 1; o < 32; o <<= 1) m = fmaxf(m, __shfl_xor(m, o));
        float lsum = 0.f;
#pragma unroll
        for (int s = 0; s < 16; ++s) {
            pv[s] = __expf(pv[s] - m);
            lsum += pv[s];
        }
#pragma unroll
        for (int o = 1; o < 32; o <<= 1) lsum += __shfl_xor(lsum, o);
        float inv = 1.f / lsum;
        __syncthreads();   // all strided reads done before transposed writes
#pragma unroll
        for (int s = 0; s < 16; ++s)
            praw[(jc + s * 32) * 20 + row] = pv[s] * inv;
    }
    __syncthreads();

    // ---- Phase 3: PV; thread (seg, d) accumulates 16 rows over 64 j ------
    float pacc[16];
#pragma unroll
    for (int i = 0; i < 16; ++i) pacc[i] = 0.f;
    {
        int seg = tid >> 6, d = tid & 63;
        const float* vcol = vmean + (size_t)bh * 512 * 64 + d;
        int jbase = seg * 64;
#pragma unroll 4
        for (int jj = 0; jj < 64; ++jj) {
            int j = jbase + jj;
            const float4* pt = (const float4*)&praw[j * 20];   // uniform addr
            float4 pa = pt[0], pb = pt[1], pc = pt[2], pd = pt[3];
            float vv = vcol[(size_t)j * 64];
            pacc[0]  = fmaf(pa.x, vv, pacc[0]);  pacc[1]  = fmaf(pa.y, vv, pacc[1]);
            pacc[2]  = fmaf(pa.z, vv, pacc[2]);  pacc[3]  = fmaf(pa.w, vv, pacc[3]);
            pacc[4]  = fmaf(pb.x, vv, pacc[4]);  pacc[5]  = fmaf(pb.y, vv, pacc[5]);
            pacc[6]  = fmaf(pb.z, vv, pacc[6]);  pacc[7]  = fmaf(pb.w, vv, pacc[7]);
            pacc[8]  = fmaf(pc.x, vv, pacc[8]);  pacc[9]  = fmaf(pc.y, vv, pacc[9]);
            pacc[10] = fmaf(pc.z, vv, pacc[10]); pacc[11] = fmaf(pc.w, vv, pacc[11]);
            pacc[12] = fmaf(pd.x, vv, pacc[12]); pacc[13] = fmaf(pd.y, vv, pacc[13]);
            pacc[14] = fmaf(pd.z, vv, pacc[14]); pacc[15] = fmaf(pd.w, vv, pacc[15]);
        }
    }
    __syncthreads();   // protect praw before overwriting with partials

    // ---- Phase 4: partials -> praw, reduce over 8 segments ---------------
    {
        int seg = tid >> 6, d = tid & 63;
#pragma unroll
        for (int i = 0; i < 16; ++i) praw[seg * 1024 + i * 64 + d] = pacc[i];
    }
    __syncthreads();
    {
        int i = tid >> 5, d2 = (tid & 31) * 2;
        float o0 = 0.f, o1 = 0.f;
#pragma unroll
        for (int seg = 0; seg < 8; ++seg) {
            const float2 pp = *(const float2*)&praw[seg * 1024 + i * 64 + d2];
            o0 += pp.x;
            o1 += pp.y;
        }
        int b = bh >> 3, h = bh & 7;
        int row = b * 512 + i0 + i;
        *(float2*)(&ctx[(size_t)row * 512 + h * 64 + d2]) = (float2){o0, o1};
    }
}

// ---------------------------------------------------------------------------
extern "C" void kernel_launch(void* const* d_in, const int* in_sizes, int n_in,
                              void* d_out, int out_size, void* d_ws, size_t ws_size,
                              hipStream_t stream) {
    const float* x   = (const float*)d_in[0];
    const float* Wq  = (const float*)d_in[1];
    const float* Wk  = (const float*)d_in[2];
    const float* Wv  = (const float*)d_in[3];
    const float* Wo  = (const float*)d_in[4];
    const float* bo  = (const float*)d_in[5];
    const float* g1  = (const float*)d_in[6];
    const float* gb1 = (const float*)d_in[7];
    const float* g2  = (const float*)d_in[8];
    const float* gb2 = (const float*)d_in[9];
    const float* g3  = (const float*)d_in[10];
    const float* gb3 = (const float*)d_in[11];
    const float* c1  = (const float*)d_in[12];
    const float* cb1 = (const float*)d_in[13];
    const float* c2  = (const float*)d_in[14];
    const float* cb2 = (const float*)d_in[15];
    const float* alpha = (const float*)d_in[16];
    const float* beta  = (const float*)d_in[17];
    float* out = (float*)d_out;

    char* w = (char*)d_ws;
    float* q    = (float*)w;                         w += (size_t)BS * E_ * 4;  // also ctx
    float* kbuf = (float*)w;                         w += (size_t)BS * E_ * 4;  // later ctx_hi/lo
    float* vbuf = (float*)w;                         w += (size_t)BS * E_ * 4;
    int* Ti     = (int*)w;                           w += (size_t)BS * 4;
    u64* qpack  = (u64*)w;                           w += (size_t)BS * NH * TMAX * 8;  // first: x_hi
    u64* kpack  = (u64*)w;                           w += (size_t)BS * NH * TMAX * 8;  // first: x_lo
    float* vmean = (float*)w;                        w += (size_t)BS * E_ * 4;  // first: Wt_qkv hi+lo
    unsigned short* wto_hi = (unsigned short*)w;     w += (size_t)512 * 512 * 2;
    unsigned short* wto_lo = (unsigned short*)w;     w += (size_t)512 * 512 * 2;

    unsigned short* x_hi = (unsigned short*)qpack;           // 2 MB (region 2.62 MB)
    unsigned short* x_lo = (unsigned short*)kpack;
    unsigned short* wtqkv_hi = (unsigned short*)vmean;       // 1.5 MB
    unsigned short* wtqkv_lo = (unsigned short*)vmean + (size_t)3 * 512 * 512;
    unsigned short* ctx_hi = (unsigned short*)kbuf;          // 2 MB
    unsigned short* ctx_lo = (unsigned short*)kbuf + (size_t)BS * E_;
    float* ctx = q;   // attn output aliases q (consumed by lif before attn)

    // 1) split x; transpose+split all W
    xsplit_kernel<<<1024, 256, 0, stream>>>(x, x_hi, x_lo);
    wsplit_kernel<<<dim3(8, 8, 4), 256, 0, stream>>>(Wq, Wk, Wv, Wo,
                                                     wtqkv_hi, wtqkv_lo, wto_hi, wto_lo);
    // 2) qkv projections (MFMA split)
    gemm_mfma_kernel<<<dim3(8, 32, 3), 256, 0, stream>>>(x_hi, x_lo,
        wtqkv_hi, wtqkv_lo, q, nullptr, 512 * 512, BS * E_);
    // 3) windows
    mlp_gate_kernel<<<256, 256, 0, stream>>>(x, g1, gb1, g2, gb2, g3, gb3,
                                             c1, cb1, c2, cb2, Ti);
    // 4) LIF (overwrites x_hi/lo and Wt_qkv regions - ordered after gemm)
    lif_kernel<<<dim3(4096, 3), 256, 0, stream>>>(q, kbuf, vbuf, Ti, alpha, beta,
                                                  qpack, kpack, vmean);
    // 5) attention
    attn_kernel<<<1024, 512, 0, stream>>>(qpack, kpack, vmean, ctx);
    // 6) output projection (MFMA split)
    xsplit_kernel<<<1024, 256, 0, stream>>>(ctx, ctx_hi, ctx_lo);
    gemm_mfma_kernel<<<dim3(8, 32, 1), 256, 0, stream>>>(ctx_hi, ctx_lo,
        wto_hi, wto_lo, out, bo, 0, 0);
}

// Round 8
// 188.966 us; speedup vs baseline: 3.0919x; 1.0530x over previous
//
#include <hip/hip_runtime.h>
#include <stdint.h>

#define BS 2048   // B*S
#define E_ 512
#define NH 8
#define HD 64
#define TMAX 20

typedef unsigned long long u64;

using bf8  = __attribute__((ext_vector_type(8))) short;   // 8 bf16 (4 VGPR)
using f4a  = __attribute__((ext_vector_type(4))) float;   // 4 f32 acc

// ---------------------------------------------------------------------------
// f32 <-> bf16 split helpers (RNE)
// ---------------------------------------------------------------------------
__device__ __forceinline__ unsigned short f2bf(float f) {
    unsigned u = __float_as_uint(f);
    return (unsigned short)((u + 0x7FFFu + ((u >> 16) & 1u)) >> 16);
}
__device__ __forceinline__ float bf2f(unsigned short h) {
    return __uint_as_float(((unsigned)h) << 16);
}
__device__ __forceinline__ void split1(float x, unsigned short& h, unsigned short& l) {
    h = f2bf(x);
    l = f2bf(x - bf2f(h));
}

// ---------------------------------------------------------------------------
// split x: f32 [n] -> hi/lo bf16. n = BS*E_ = 1M, grid 1024x256 (float4)
// ---------------------------------------------------------------------------
__global__ __launch_bounds__(256) void xsplit_kernel(const float* __restrict__ src,
    unsigned short* __restrict__ hi, unsigned short* __restrict__ lo)
{
    int i = blockIdx.x * 256 + threadIdx.x;
    float4 v = ((const float4*)src)[i];
    ushort4 h, l;
    split1(v.x, h.x, l.x);
    split1(v.y, h.y, l.y);
    split1(v.z, h.z, l.z);
    split1(v.w, h.w, l.w);
    ((ushort4*)hi)[i] = h;
    ((ushort4*)lo)[i] = l;
}

// ---------------------------------------------------------------------------
// transpose + split W: W[k][n] f32 -> Wt_hi/lo[n][k] bf16. grid (8,8,4) 256thr
// ---------------------------------------------------------------------------
__global__ __launch_bounds__(256) void wsplit_kernel(
    const float* __restrict__ Wq, const float* __restrict__ Wk,
    const float* __restrict__ Wv, const float* __restrict__ Wo,
    unsigned short* __restrict__ qkv_hi, unsigned short* __restrict__ qkv_lo,
    unsigned short* __restrict__ o_hi, unsigned short* __restrict__ o_lo)
{
    __shared__ float t[64][65];
    int z = blockIdx.z;
    const float* W = (z == 0) ? Wq : (z == 1) ? Wk : (z == 2) ? Wv : Wo;
    unsigned short* dhi = (z < 3) ? qkv_hi + (size_t)z * 512 * 512 : o_hi;
    unsigned short* dlo = (z < 3) ? qkv_lo + (size_t)z * 512 * 512 : o_lo;
    int k0 = blockIdx.y * 64, n0 = blockIdx.x * 64;
    int tid = threadIdx.x;
    int r = tid >> 4, c4 = (tid & 15) * 4;
#pragma unroll
    for (int j = 0; j < 4; ++j) {
        int row = r + j * 16;
        float4 v = *(const float4*)&W[(size_t)(k0 + row) * 512 + n0 + c4];
        t[row][c4 + 0] = v.x; t[row][c4 + 1] = v.y;
        t[row][c4 + 2] = v.z; t[row][c4 + 3] = v.w;
    }
    __syncthreads();
#pragma unroll
    for (int j = 0; j < 4; ++j) {
        int n = r + j * 16;
        ushort4 h, l;
        split1(t[c4 + 0][n], h.x, l.x);
        split1(t[c4 + 1][n], h.y, l.y);
        split1(t[c4 + 2][n], h.z, l.z);
        split1(t[c4 + 3][n], h.w, l.w);
        *(ushort4*)&dhi[(size_t)(n0 + n) * 512 + k0 + c4] = h;
        *(ushort4*)&dlo[(size_t)(n0 + n) * 512 + k0 + c4] = l;
    }
}

// ---------------------------------------------------------------------------
// split-bf16 MFMA GEMM (3-term): LDS-free, wave = 32x32 tile. Unchanged r6.
// ---------------------------------------------------------------------------
__global__ __launch_bounds__(256) void gemm_mfma_kernel(
    const unsigned short* __restrict__ Ahi, const unsigned short* __restrict__ Alo,
    const unsigned short* __restrict__ Bthi, const unsigned short* __restrict__ Btlo,
    float* __restrict__ Cbase, const float* __restrict__ bias,
    int zstride_b, int zstride_c)
{
    int z = blockIdx.z;
    const unsigned short* bh_ = Bthi + (size_t)z * zstride_b;
    const unsigned short* bl_ = Btlo + (size_t)z * zstride_b;
    float* C = Cbase + (size_t)z * zstride_c;

    int tid = threadIdx.x;
    int w = tid >> 6, lane = tid & 63;
    int lrow = lane & 15;
    int lk = (lane >> 4) * 8;
    int m0 = blockIdx.y * 64 + ((w >> 1) << 5);
    int n0 = blockIdx.x * 64 + ((w & 1) << 5);

    const size_t ar0 = (size_t)(m0 + lrow) * 512 + lk;
    const size_t ar1 = ar0 + (size_t)16 * 512;
    const size_t br0 = (size_t)(n0 + lrow) * 512 + lk;
    const size_t br1 = br0 + (size_t)16 * 512;

    f4a z4 = {0.f, 0.f, 0.f, 0.f};
    f4a a00 = z4, a01 = z4, a10 = z4, a11 = z4;

#pragma unroll 2
    for (int k0 = 0; k0 < 512; k0 += 32) {
        bf8 ah0 = *(const bf8*)&Ahi[ar0 + k0];
        bf8 ah1 = *(const bf8*)&Ahi[ar1 + k0];
        bf8 al0 = *(const bf8*)&Alo[ar0 + k0];
        bf8 al1 = *(const bf8*)&Alo[ar1 + k0];
        bf8 bh0 = *(const bf8*)&bh_[br0 + k0];
        bf8 bh1 = *(const bf8*)&bh_[br1 + k0];
        bf8 bl0 = *(const bf8*)&bl_[br0 + k0];
        bf8 bl1 = *(const bf8*)&bl_[br1 + k0];
        a00 = __builtin_amdgcn_mfma_f32_16x16x32_bf16(ah0, bh0, a00, 0, 0, 0);
        a01 = __builtin_amdgcn_mfma_f32_16x16x32_bf16(ah0, bh1, a01, 0, 0, 0);
        a10 = __builtin_amdgcn_mfma_f32_16x16x32_bf16(ah1, bh0, a10, 0, 0, 0);
        a11 = __builtin_amdgcn_mfma_f32_16x16x32_bf16(ah1, bh1, a11, 0, 0, 0);
        a00 = __builtin_amdgcn_mfma_f32_16x16x32_bf16(ah0, bl0, a00, 0, 0, 0);
        a01 = __builtin_amdgcn_mfma_f32_16x16x32_bf16(ah0, bl1, a01, 0, 0, 0);
        a10 = __builtin_amdgcn_mfma_f32_16x16x32_bf16(ah1, bl0, a10, 0, 0, 0);
        a11 = __builtin_amdgcn_mfma_f32_16x16x32_bf16(ah1, bl1, a11, 0, 0, 0);
        a00 = __builtin_amdgcn_mfma_f32_16x16x32_bf16(al0, bh0, a00, 0, 0, 0);
        a01 = __builtin_amdgcn_mfma_f32_16x16x32_bf16(al0, bh1, a01, 0, 0, 0);
        a10 = __builtin_amdgcn_mfma_f32_16x16x32_bf16(al1, bh0, a10, 0, 0, 0);
        a11 = __builtin_amdgcn_mfma_f32_16x16x32_bf16(al1, bh1, a11, 0, 0, 0);
    }

    int orow = (lane >> 4) * 4;
    int col0 = n0 + lrow, col1 = n0 + 16 + lrow;
    float b0 = bias ? bias[col0] : 0.f;
    float b1 = bias ? bias[col1] : 0.f;
#pragma unroll
    for (int r = 0; r < 4; ++r) {
        C[(size_t)(m0 + orow + r) * 512 + col0]      = a00[r] + b0;
        C[(size_t)(m0 + orow + r) * 512 + col1]      = a01[r] + b1;
        C[(size_t)(m0 + 16 + orow + r) * 512 + col0] = a10[r] + b0;
        C[(size_t)(m0 + 16 + orow + r) * 512 + col1] = a11[r] + b1;
    }
}

// ---------------------------------------------------------------------------
// Gate/complexity MLPs -> T_i. 8 tokens per 256-thread block (256 blocks).
// ---------------------------------------------------------------------------
__global__ __launch_bounds__(256) void mlp_gate_kernel(const float* __restrict__ x,
    const float* __restrict__ g1, const float* __restrict__ gb1,
    const float* __restrict__ g2, const float* __restrict__ gb2,
    const float* __restrict__ g3, const float* __restrict__ gb3,
    const float* __restrict__ c1, const float* __restrict__ cb1,
    const float* __restrict__ c2, const float* __restrict__ cb2,
    int* __restrict__ Ti)
{
    __shared__ __align__(16) float xsh[8][512];
    __shared__ float h1sh[8][64];
    __shared__ float h2sh[8][32];
    __shared__ float gsh[8];
    int tid = threadIdx.x;
    int tok0 = blockIdx.x * 8;

    const float4* xg = (const float4*)(&x[(size_t)tok0 * 512]);
    float4* xs4 = (float4*)(&xsh[0][0]);
    for (int i = tid; i < 8 * 128; i += 256) xs4[i] = xg[i];
    __syncthreads();

    {
        int l = tid & 63, tg = tid >> 6;
        float a0 = gb1[l], a1 = a0;
#pragma unroll 8
        for (int e = 0; e < 512; ++e) {
            float w = g1[e * 64 + l];
            a0 = fmaf(xsh[tg][e], w, a0);
            a1 = fmaf(xsh[tg + 4][e], w, a1);
        }
        h1sh[tg][l] = fmaxf(a0, 0.f);
        h1sh[tg + 4][l] = fmaxf(a1, 0.f);
    }
    __syncthreads();
    {
        int m = tid & 31, tok = tid >> 5;
        float a = gb2[m];
#pragma unroll 8
        for (int l = 0; l < 64; ++l) a = fmaf(h1sh[tok][l], g2[l * 32 + m], a);
        h2sh[tok][m] = fmaxf(a, 0.f);
    }
    __syncthreads();
    if (tid < 8) {
        float a = gb3[0];
#pragma unroll 8
        for (int m = 0; m < 32; ++m) a = fmaf(h2sh[tid][m], g3[m], a);
        gsh[tid] = 1.f / (1.f + expf(-a));
    }
    __syncthreads();
    {
        int m = tid & 31, tok = tid >> 5;
        float a = cb1[m];
#pragma unroll 8
        for (int e = 0; e < 512; ++e) a = fmaf(xsh[tok][e], c1[e * 32 + m], a);
        h2sh[tok][m] = fmaxf(a, 0.f);
    }
    __syncthreads();
    if (tid < 8) {
        float a = cb2[0];
#pragma unroll 8
        for (int m = 0; m < 32; ++m) a = fmaf(h2sh[tid][m], c2[m], a);
        float comp = 1.f / (1.f + expf(-a));
        float comb = 0.7f * gsh[tid] + 0.3f * comp;
        int t = (int)ceilf(comb * 20.f);
        t = t < 1 ? 1 : (t > 20 ? 20 : t);
        Ti[tok0 + tid] = t;
    }
}

// ---------------------------------------------------------------------------
// LIF + window mask. One wave per (token, head). lane = channel within head.
// ---------------------------------------------------------------------------
__global__ __launch_bounds__(256) void lif_kernel(const float* __restrict__ q,
    const float* __restrict__ k, const float* __restrict__ v,
    const int* __restrict__ Ti,
    const float* __restrict__ alphap, const float* __restrict__ betap,
    u64* __restrict__ qpack, u64* __restrict__ kpack,
    float* __restrict__ vmean)
{
    int mode = blockIdx.y;
    const float* src = (mode == 0) ? q : (mode == 1) ? k : v;
    int w = blockIdx.x * 4 + (threadIdx.x >> 6);   // 0..16383
    int lane = threadIdx.x & 63;
    int token = w >> 3;
    int h = w & 7;
    float xin = src[(size_t)token * 512 + h * 64 + lane];
    int T = Ti[token];
    float alpha = alphap[0], beta = betap[0];
    float vm = 0.f, isyn = 0.f;
    u64 myword = 0ull;
    int cnt = 0;
#pragma unroll
    for (int t = 0; t < TMAX; ++t) {
        isyn = alpha * isyn + xin;
        vm = beta * vm + isyn;
        bool sp = vm >= 1.0f;
        if (sp) vm = 0.f;
        bool msk = sp && (t < T);
        if (mode < 2) {
            u64 word = __ballot(msk ? 1 : 0);
            if (lane == t) myword = word;
        } else {
            cnt += msk ? 1 : 0;
        }
    }
    int b = token >> 9, i = token & 511;
    size_t bh = (size_t)(b * 8 + h);
    if (mode == 0) { if (lane < TMAX) qpack[(bh * 512 + i) * TMAX + lane] = myword; }
    else if (mode == 1) { if (lane < TMAX) kpack[(bh * 512 + i) * TMAX + lane] = myword; }
    else { vmean[(bh * 512 + i) * 64 + lane] = (float)cnt * 0.05f; }
}

// ---------------------------------------------------------------------------
// attn: 256 threads (4 waves), 2048 blocks, LDS 17408 B -> 8 blocks/CU
// (wave-cap limited, 32 waves/CU). Block = (bh, 8 q-rows).
// Phase 1 scores: thread covers j = tid, tid+256; q rows wave-uniform scalar.
// Phase 2 softmax: 8 rows x 32 lanes; writes p transposed (pitch 8) in place.
// Phase 3 PV: thread (seg 0..3, d 0..63), 128 j per seg; p via uniform b128.
// Phase 4 reduce over 4 segs; epilogue fuses hi/lo bf16 split of ctx.
// ---------------------------------------------------------------------------
__global__ __launch_bounds__(256) void attn_kernel(
    const u64* __restrict__ qpack,
    const u64* __restrict__ kpack,
    const float* __restrict__ vmean,
    unsigned short* __restrict__ ctx_hi,
    unsigned short* __restrict__ ctx_lo)
{
    __shared__ __align__(16) float praw[4352];   // 17408 B

    int tid = threadIdx.x;
    // XCD-bijective swizzle: 2048 = 8 XCDs x 256
    int bid = blockIdx.x;
    int swz = (bid & 7) * 256 + (bid >> 3);
    int bh = swz >> 6;                 // 0..31 (B*NH = 32)
    int i0 = (swz & 63) << 3;          // 8-row group

    // ---- Phase 1: scores ------------------------------------------------
#pragma unroll
    for (int jp = 0; jp < 2; ++jp) {
        int j = jp * 256 + tid;
        const ulonglong2* kc = (const ulonglong2*)(kpack + ((size_t)bh * 512 + j) * TMAX);
        int acc[8];
#pragma unroll
        for (int i = 0; i < 8; ++i) acc[i] = 0;
#pragma unroll
        for (int t2 = 0; t2 < TMAX / 2; ++t2) {
            ulonglong2 u = kc[t2];
#pragma unroll
            for (int i = 0; i < 8; ++i) {
                const u64* qrow = qpack + ((size_t)bh * 512 + i0 + i) * TMAX;  // uniform
                acc[i] += __popcll(qrow[2 * t2] & u.x) + __popcll(qrow[2 * t2 + 1] & u.y);
            }
        }
#pragma unroll
        for (int i = 0; i < 8; ++i) praw[i * 544 + j] = 0.125f * (float)acc[i];
    }
    __syncthreads();

    // ---- Phase 2: softmax (8 rows x 32 lanes), transposed normalized write
    {
        int row = tid >> 5, jc = tid & 31;
        float pv[16];
        float m = -1e30f;
#pragma unroll
        for (int s = 0; s < 16; ++s) {
            pv[s] = praw[row * 544 + jc + s * 32];
            m = fmaxf(m, pv[s]);
        }
#pragma unroll
        for (int o = 1; o < 32; o <<= 1) m = fmaxf(m, __shfl_xor(m, o));
        float lsum = 0.f;
#pragma unroll
        for (int s = 0; s < 16; ++s) {
            pv[s] = __expf(pv[s] - m);
            lsum += pv[s];
        }
#pragma unroll
        for (int o = 1; o < 32; o <<= 1) lsum += __shfl_xor(lsum, o);
        float inv = 1.f / lsum;
        __syncthreads();   // strided reads done before transposed writes
#pragma unroll
        for (int s = 0; s < 16; ++s)
            praw[(jc + s * 32) * 8 + row] = pv[s] * inv;
    }
    __syncthreads();

    // ---- Phase 3: PV; thread (seg, d) accumulates 8 rows over 128 j ------
    float pacc[8];
#pragma unroll
    for (int i = 0; i < 8; ++i) pacc[i] = 0.f;
    {
        int seg = tid >> 6, d = tid & 63;
        const float* vcol = vmean + (size_t)bh * 512 * 64 + d;
        int jbase = seg * 128;
#pragma unroll 4
        for (int jj = 0; jj < 128; ++jj) {
            int j = jbase + jj;
            const float4* pt = (const float4*)&praw[j * 8];   // uniform addr
            float4 pa = pt[0], pb = pt[1];
            float vv = vcol[(size_t)j * 64];
            pacc[0] = fmaf(pa.x, vv, pacc[0]); pacc[1] = fmaf(pa.y, vv, pacc[1]);
            pacc[2] = fmaf(pa.z, vv, pacc[2]); pacc[3] = fmaf(pa.w, vv, pacc[3]);
            pacc[4] = fmaf(pb.x, vv, pacc[4]); pacc[5] = fmaf(pb.y, vv, pacc[5]);
            pacc[6] = fmaf(pb.z, vv, pacc[6]); pacc[7] = fmaf(pb.w, vv, pacc[7]);
        }
    }
    __syncthreads();   // protect praw before overwriting with partials

    // ---- Phase 4: partials -> praw[seg*512 + i*64 + d], reduce 4 segs ----
    {
        int seg = tid >> 6, d = tid & 63;
#pragma unroll
        for (int i = 0; i < 8; ++i) praw[seg * 512 + i * 64 + d] = pacc[i];
    }
    __syncthreads();
    {
        int i = tid >> 5, d2 = (tid & 31) * 2;
        float o0 = 0.f, o1 = 0.f;
#pragma unroll
        for (int seg = 0; seg < 4; ++seg) {
            const float2 pp = *(const float2*)&praw[seg * 512 + i * 64 + d2];
            o0 += pp.x;
            o1 += pp.y;
        }
        // fused hi/lo bf16 split of ctx
        ushort2 h2v, l2v;
        split1(o0, h2v.x, l2v.x);
        split1(o1, h2v.y, l2v.y);
        int b = bh >> 3, h = bh & 7;
        size_t off = ((size_t)(b * 512 + i0 + i)) * 512 + h * 64 + d2;
        *(ushort2*)&ctx_hi[off] = h2v;
        *(ushort2*)&ctx_lo[off] = l2v;
    }
}

// ---------------------------------------------------------------------------
extern "C" void kernel_launch(void* const* d_in, const int* in_sizes, int n_in,
                              void* d_out, int out_size, void* d_ws, size_t ws_size,
                              hipStream_t stream) {
    const float* x   = (const float*)d_in[0];
    const float* Wq  = (const float*)d_in[1];
    const float* Wk  = (const float*)d_in[2];
    const float* Wv  = (const float*)d_in[3];
    const float* Wo  = (const float*)d_in[4];
    const float* bo  = (const float*)d_in[5];
    const float* g1  = (const float*)d_in[6];
    const float* gb1 = (const float*)d_in[7];
    const float* g2  = (const float*)d_in[8];
    const float* gb2 = (const float*)d_in[9];
    const float* g3  = (const float*)d_in[10];
    const float* gb3 = (const float*)d_in[11];
    const float* c1  = (const float*)d_in[12];
    const float* cb1 = (const float*)d_in[13];
    const float* c2  = (const float*)d_in[14];
    const float* cb2 = (const float*)d_in[15];
    const float* alpha = (const float*)d_in[16];
    const float* beta  = (const float*)d_in[17];
    float* out = (float*)d_out;

    char* w = (char*)d_ws;
    float* q    = (float*)w;                         w += (size_t)BS * E_ * 4;
    float* kbuf = (float*)w;                         w += (size_t)BS * E_ * 4;  // later ctx_hi/lo
    float* vbuf = (float*)w;                         w += (size_t)BS * E_ * 4;
    int* Ti     = (int*)w;                           w += (size_t)BS * 4;
    u64* qpack  = (u64*)w;                           w += (size_t)BS * NH * TMAX * 8;  // first: x_hi
    u64* kpack  = (u64*)w;                           w += (size_t)BS * NH * TMAX * 8;  // first: x_lo
    float* vmean = (float*)w;                        w += (size_t)BS * E_ * 4;  // first: Wt_qkv hi+lo
    unsigned short* wto_hi = (unsigned short*)w;     w += (size_t)512 * 512 * 2;
    unsigned short* wto_lo = (unsigned short*)w;     w += (size_t)512 * 512 * 2;

    unsigned short* x_hi = (unsigned short*)qpack;
    unsigned short* x_lo = (unsigned short*)kpack;
    unsigned short* wtqkv_hi = (unsigned short*)vmean;
    unsigned short* wtqkv_lo = (unsigned short*)vmean + (size_t)3 * 512 * 512;
    unsigned short* ctx_hi = (unsigned short*)kbuf;          // attn writes after lif reads kbuf
    unsigned short* ctx_lo = (unsigned short*)kbuf + (size_t)BS * E_;

    // 1) split x; transpose+split all W
    xsplit_kernel<<<1024, 256, 0, stream>>>(x, x_hi, x_lo);
    wsplit_kernel<<<dim3(8, 8, 4), 256, 0, stream>>>(Wq, Wk, Wv, Wo,
                                                     wtqkv_hi, wtqkv_lo, wto_hi, wto_lo);
    // 2) qkv projections (MFMA split)
    gemm_mfma_kernel<<<dim3(8, 32, 3), 256, 0, stream>>>(x_hi, x_lo,
        wtqkv_hi, wtqkv_lo, q, nullptr, 512 * 512, BS * E_);
    // 3) windows
    mlp_gate_kernel<<<256, 256, 0, stream>>>(x, g1, gb1, g2, gb2, g3, gb3,
                                             c1, cb1, c2, cb2, Ti);
    // 4) LIF (overwrites x_hi/lo and Wt_qkv regions - ordered after gemm)
    lif_kernel<<<dim3(4096, 3), 256, 0, stream>>>(q, kbuf, vbuf, Ti, alpha, beta,
                                                  qpack, kpack, vmean);
    // 5) attention (emits ctx hi/lo bf16 directly)
    attn_kernel<<<2048, 256, 0, stream>>>(qpack, kpack, vmean, ctx_hi, ctx_lo);
    // 6) output projection (MFMA split)
    gemm_mfma_kernel<<<dim3(8, 32, 1), 256, 0, stream>>>(ctx_hi, ctx_lo,
        wto_hi, wto_lo, out, bo, 0, 0);
}

// Round 9
// 162.584 us; speedup vs baseline: 3.5936x; 1.1623x over previous
//
#include <hip/hip_runtime.h>
#include <stdint.h>

#define BS 2048   // B*S
#define E_ 512
#define NH 8
#define HD 64
#define TMAX 20

typedef unsigned long long u64;

using bf8  = __attribute__((ext_vector_type(8))) short;   // 8 bf16 (4 VGPR)
using f4a  = __attribute__((ext_vector_type(4))) float;   // 4 f32 acc

// ---------------------------------------------------------------------------
// f32 <-> bf16 split helpers (RNE)
// ---------------------------------------------------------------------------
__device__ __forceinline__ unsigned short f2bf(float f) {
    unsigned u = __float_as_uint(f);
    return (unsigned short)((u + 0x7FFFu + ((u >> 16) & 1u)) >> 16);
}
__device__ __forceinline__ float bf2f(unsigned short h) {
    return __uint_as_float(((unsigned)h) << 16);
}
__device__ __forceinline__ void split1(float x, unsigned short& h, unsigned short& l) {
    h = f2bf(x);
    l = f2bf(x - bf2f(h));
}

// ---------------------------------------------------------------------------
// split x: f32 [n] -> hi/lo bf16. n = BS*E_ = 1M, grid 1024x256 (float4)
// ---------------------------------------------------------------------------
__global__ __launch_bounds__(256) void xsplit_kernel(const float* __restrict__ src,
    unsigned short* __restrict__ hi, unsigned short* __restrict__ lo)
{
    int i = blockIdx.x * 256 + threadIdx.x;
    float4 v = ((const float4*)src)[i];
    ushort4 h, l;
    split1(v.x, h.x, l.x);
    split1(v.y, h.y, l.y);
    split1(v.z, h.z, l.z);
    split1(v.w, h.w, l.w);
    ((ushort4*)hi)[i] = h;
    ((ushort4*)lo)[i] = l;
}

// ---------------------------------------------------------------------------
// transpose + split W: W[k][n] f32 -> Wt_hi/lo[n][k] bf16. grid (8,8,4) 256thr
// ---------------------------------------------------------------------------
__global__ __launch_bounds__(256) void wsplit_kernel(
    const float* __restrict__ Wq, const float* __restrict__ Wk,
    const float* __restrict__ Wv, const float* __restrict__ Wo,
    unsigned short* __restrict__ qkv_hi, unsigned short* __restrict__ qkv_lo,
    unsigned short* __restrict__ o_hi, unsigned short* __restrict__ o_lo)
{
    __shared__ float t[64][65];
    int z = blockIdx.z;
    const float* W = (z == 0) ? Wq : (z == 1) ? Wk : (z == 2) ? Wv : Wo;
    unsigned short* dhi = (z < 3) ? qkv_hi + (size_t)z * 512 * 512 : o_hi;
    unsigned short* dlo = (z < 3) ? qkv_lo + (size_t)z * 512 * 512 : o_lo;
    int k0 = blockIdx.y * 64, n0 = blockIdx.x * 64;
    int tid = threadIdx.x;
    int r = tid >> 4, c4 = (tid & 15) * 4;
#pragma unroll
    for (int j = 0; j < 4; ++j) {
        int row = r + j * 16;
        float4 v = *(const float4*)&W[(size_t)(k0 + row) * 512 + n0 + c4];
        t[row][c4 + 0] = v.x; t[row][c4 + 1] = v.y;
        t[row][c4 + 2] = v.z; t[row][c4 + 3] = v.w;
    }
    __syncthreads();
#pragma unroll
    for (int j = 0; j < 4; ++j) {
        int n = r + j * 16;
        ushort4 h, l;
        split1(t[c4 + 0][n], h.x, l.x);
        split1(t[c4 + 1][n], h.y, l.y);
        split1(t[c4 + 2][n], h.z, l.z);
        split1(t[c4 + 3][n], h.w, l.w);
        *(ushort4*)&dhi[(size_t)(n0 + n) * 512 + k0 + c4] = h;
        *(ushort4*)&dlo[(size_t)(n0 + n) * 512 + k0 + c4] = l;
    }
}

// ---------------------------------------------------------------------------
// split-bf16 MFMA GEMM (3-term): LDS-free, wave = 32x32 tile. Unchanged r6.
// ---------------------------------------------------------------------------
__global__ __launch_bounds__(256) void gemm_mfma_kernel(
    const unsigned short* __restrict__ Ahi, const unsigned short* __restrict__ Alo,
    const unsigned short* __restrict__ Bthi, const unsigned short* __restrict__ Btlo,
    float* __restrict__ Cbase, const float* __restrict__ bias,
    int zstride_b, int zstride_c)
{
    int z = blockIdx.z;
    const unsigned short* bh_ = Bthi + (size_t)z * zstride_b;
    const unsigned short* bl_ = Btlo + (size_t)z * zstride_b;
    float* C = Cbase + (size_t)z * zstride_c;

    int tid = threadIdx.x;
    int w = tid >> 6, lane = tid & 63;
    int lrow = lane & 15;
    int lk = (lane >> 4) * 8;
    int m0 = blockIdx.y * 64 + ((w >> 1) << 5);
    int n0 = blockIdx.x * 64 + ((w & 1) << 5);

    const size_t ar0 = (size_t)(m0 + lrow) * 512 + lk;
    const size_t ar1 = ar0 + (size_t)16 * 512;
    const size_t br0 = (size_t)(n0 + lrow) * 512 + lk;
    const size_t br1 = br0 + (size_t)16 * 512;

    f4a z4 = {0.f, 0.f, 0.f, 0.f};
    f4a a00 = z4, a01 = z4, a10 = z4, a11 = z4;

#pragma unroll 2
    for (int k0 = 0; k0 < 512; k0 += 32) {
        bf8 ah0 = *(const bf8*)&Ahi[ar0 + k0];
        bf8 ah1 = *(const bf8*)&Ahi[ar1 + k0];
        bf8 al0 = *(const bf8*)&Alo[ar0 + k0];
        bf8 al1 = *(const bf8*)&Alo[ar1 + k0];
        bf8 bh0 = *(const bf8*)&bh_[br0 + k0];
        bf8 bh1 = *(const bf8*)&bh_[br1 + k0];
        bf8 bl0 = *(const bf8*)&bl_[br0 + k0];
        bf8 bl1 = *(const bf8*)&bl_[br1 + k0];
        a00 = __builtin_amdgcn_mfma_f32_16x16x32_bf16(ah0, bh0, a00, 0, 0, 0);
        a01 = __builtin_amdgcn_mfma_f32_16x16x32_bf16(ah0, bh1, a01, 0, 0, 0);
        a10 = __builtin_amdgcn_mfma_f32_16x16x32_bf16(ah1, bh0, a10, 0, 0, 0);
        a11 = __builtin_amdgcn_mfma_f32_16x16x32_bf16(ah1, bh1, a11, 0, 0, 0);
        a00 = __builtin_amdgcn_mfma_f32_16x16x32_bf16(ah0, bl0, a00, 0, 0, 0);
        a01 = __builtin_amdgcn_mfma_f32_16x16x32_bf16(ah0, bl1, a01, 0, 0, 0);
        a10 = __builtin_amdgcn_mfma_f32_16x16x32_bf16(ah1, bl0, a10, 0, 0, 0);
        a11 = __builtin_amdgcn_mfma_f32_16x16x32_bf16(ah1, bl1, a11, 0, 0, 0);
        a00 = __builtin_amdgcn_mfma_f32_16x16x32_bf16(al0, bh0, a00, 0, 0, 0);
        a01 = __builtin_amdgcn_mfma_f32_16x16x32_bf16(al0, bh1, a01, 0, 0, 0);
        a10 = __builtin_amdgcn_mfma_f32_16x16x32_bf16(al1, bh0, a10, 0, 0, 0);
        a11 = __builtin_amdgcn_mfma_f32_16x16x32_bf16(al1, bh1, a11, 0, 0, 0);
    }

    int orow = (lane >> 4) * 4;
    int col0 = n0 + lrow, col1 = n0 + 16 + lrow;
    float b0 = bias ? bias[col0] : 0.f;
    float b1 = bias ? bias[col1] : 0.f;
#pragma unroll
    for (int r = 0; r < 4; ++r) {
        C[(size_t)(m0 + orow + r) * 512 + col0]      = a00[r] + b0;
        C[(size_t)(m0 + orow + r) * 512 + col1]      = a01[r] + b1;
        C[(size_t)(m0 + 16 + orow + r) * 512 + col0] = a10[r] + b0;
        C[(size_t)(m0 + 16 + orow + r) * 512 + col1] = a11[r] + b1;
    }
}

// ---------------------------------------------------------------------------
// Gate/complexity MLPs -> T_i. 2 tokens per 256-thread block, 1024 blocks.
// e-split reduction: wave w sums a 128-wide e-chunk; LDS partial reduce.
// ---------------------------------------------------------------------------
__global__ __launch_bounds__(256) void mlp_gate_kernel(const float* __restrict__ x,
    const float* __restrict__ g1, const float* __restrict__ gb1,
    const float* __restrict__ g2, const float* __restrict__ gb2,
    const float* __restrict__ g3, const float* __restrict__ gb3,
    const float* __restrict__ c1, const float* __restrict__ cb1,
    const float* __restrict__ c2, const float* __restrict__ cb2,
    int* __restrict__ Ti)
{
    __shared__ __align__(16) float xsh[2][512];
    __shared__ float p1[2][4][64];
    __shared__ float h1sh[2][64];
    __shared__ float p2[2][4][32];
    __shared__ float gsh[2];
    int tid = threadIdx.x;
    int tok0 = blockIdx.x * 2;

    // stage x (2 tokens = 256 float4)
    ((float4*)&xsh[0][0])[tid] = ((const float4*)&x[(size_t)tok0 * 512])[tid];
    __syncthreads();

    // h1 partials: wave ec covers e in [ec*128, ec*128+128), lane l = out ch
    {
        int l = tid & 63, ec = tid >> 6;
        float a0 = 0.f, a1 = 0.f;
        int e0 = ec * 128;
#pragma unroll 8
        for (int t = 0; t < 128; ++t) {
            int e = e0 + t;
            float w = g1[e * 64 + l];
            a0 = fmaf(xsh[0][e], w, a0);
            a1 = fmaf(xsh[1][e], w, a1);
        }
        p1[0][ec][l] = a0;
        p1[1][ec][l] = a1;
    }
    __syncthreads();
    if (tid < 128) {
        int tok = tid >> 6, l = tid & 63;
        float h = p1[tok][0][l] + p1[tok][1][l] + p1[tok][2][l] + p1[tok][3][l] + gb1[l];
        h1sh[tok][l] = fmaxf(h, 0.f);
    }
    __syncthreads();
    // h2: thread (m, g): tok=g&1, lc=g>>1 covers 16 l's
    {
        int m = tid & 31, g = tid >> 5, tok = g & 1, lc = g >> 1;
        float a = 0.f;
#pragma unroll
        for (int t = 0; t < 16; ++t) {
            int l = lc * 16 + t;
            a = fmaf(h1sh[tok][l], g2[l * 32 + m], a);
        }
        p2[tok][lc][m] = a;
    }
    __syncthreads();
    if (tid < 64) {
        int tok = tid >> 5, m = tid & 31;
        float h = p2[tok][0][m] + p2[tok][1][m] + p2[tok][2][m] + p2[tok][3][m] + gb2[m];
        h = fmaxf(h, 0.f);
        float v = h * g3[m];
#pragma unroll
        for (int o = 1; o < 32; o <<= 1) v += __shfl_xor(v, o);
        if (m == 0) gsh[tok] = 1.f / (1.f + expf(-(v + gb3[0])));
    }
    __syncthreads();
    // c1: thread (m, g): tok=g&1, ec=g>>1 covers 128 e's
    {
        int m = tid & 31, g = tid >> 5, tok = g & 1, ec = g >> 1;
        float a = 0.f;
        int e0 = ec * 128;
#pragma unroll 8
        for (int t = 0; t < 128; ++t) {
            int e = e0 + t;
            a = fmaf(xsh[tok][e], c1[e * 32 + m], a);
        }
        p2[tok][ec][m] = a;
    }
    __syncthreads();
    if (tid < 64) {
        int tok = tid >> 5, m = tid & 31;
        float h = p2[tok][0][m] + p2[tok][1][m] + p2[tok][2][m] + p2[tok][3][m] + cb1[m];
        h = fmaxf(h, 0.f);
        float v = h * c2[m];
#pragma unroll
        for (int o = 1; o < 32; o <<= 1) v += __shfl_xor(v, o);
        if (m == 0) {
            float comp = 1.f / (1.f + expf(-(v + cb2[0])));
            float comb = 0.7f * gsh[tok] + 0.3f * comp;
            int t = (int)ceilf(comb * 20.f);
            t = t < 1 ? 1 : (t > 20 ? 20 : t);
            Ti[tok0 + tok] = t;
        }
    }
}

// ---------------------------------------------------------------------------
// LIF + window mask. One wave per (token, head). lane = channel within head.
// ---------------------------------------------------------------------------
__global__ __launch_bounds__(256) void lif_kernel(const float* __restrict__ q,
    const float* __restrict__ k, const float* __restrict__ v,
    const int* __restrict__ Ti,
    const float* __restrict__ alphap, const float* __restrict__ betap,
    u64* __restrict__ qpack, u64* __restrict__ kpack,
    float* __restrict__ vmean)
{
    int mode = blockIdx.y;
    const float* src = (mode == 0) ? q : (mode == 1) ? k : v;
    int w = blockIdx.x * 4 + (threadIdx.x >> 6);   // 0..16383
    int lane = threadIdx.x & 63;
    int token = w >> 3;
    int h = w & 7;
    float xin = src[(size_t)token * 512 + h * 64 + lane];
    int T = Ti[token];
    float alpha = alphap[0], beta = betap[0];
    float vm = 0.f, isyn = 0.f;
    u64 myword = 0ull;
    int cnt = 0;
#pragma unroll
    for (int t = 0; t < TMAX; ++t) {
        isyn = alpha * isyn + xin;
        vm = beta * vm + isyn;
        bool sp = vm >= 1.0f;
        if (sp) vm = 0.f;
        bool msk = sp && (t < T);
        if (mode < 2) {
            u64 word = __ballot(msk ? 1 : 0);
            if (lane == t) myword = word;
        } else {
            cnt += msk ? 1 : 0;
        }
    }
    int b = token >> 9, i = token & 511;
    size_t bh = (size_t)(b * 8 + h);
    if (mode == 0) { if (lane < TMAX) qpack[(bh * 512 + i) * TMAX + lane] = myword; }
    else if (mode == 1) { if (lane < TMAX) kpack[(bh * 512 + i) * TMAX + lane] = myword; }
    else { vmean[(bh * 512 + i) * 64 + lane] = (float)cnt * 0.05f; }
}

// ---------------------------------------------------------------------------
// attn: 256 threads (4 waves), 2048 blocks, LDS 17408 B -> 8 blocks/CU.
// Phase 1 scores row-major; Phase 2 softmax in-place normalized (conflict-
// free); Phase 3 PV reads p ROW-MAJOR via wave-uniform b128 over 4 j's (no
// transpose buffer at all); Phase 4 segment reduce + fused ctx hi/lo split.
// ---------------------------------------------------------------------------
__global__ __launch_bounds__(256) void attn_kernel(
    const u64* __restrict__ qpack,
    const u64* __restrict__ kpack,
    const float* __restrict__ vmean,
    unsigned short* __restrict__ ctx_hi,
    unsigned short* __restrict__ ctx_lo)
{
    __shared__ __align__(16) float praw[4352];   // 17408 B (8 rows x 544)

    int tid = threadIdx.x;
    // XCD-bijective swizzle: 2048 = 8 XCDs x 256
    int bid = blockIdx.x;
    int swz = (bid & 7) * 256 + (bid >> 3);
    int bh = swz >> 6;                 // 0..31 (B*NH = 32)
    int i0 = (swz & 63) << 3;          // 8-row group

    // ---- Phase 1: scores ------------------------------------------------
#pragma unroll
    for (int jp = 0; jp < 2; ++jp) {
        int j = jp * 256 + tid;
        const ulonglong2* kc = (const ulonglong2*)(kpack + ((size_t)bh * 512 + j) * TMAX);
        int acc[8];
#pragma unroll
        for (int i = 0; i < 8; ++i) acc[i] = 0;
#pragma unroll
        for (int t2 = 0; t2 < TMAX / 2; ++t2) {
            ulonglong2 u = kc[t2];
#pragma unroll
            for (int i = 0; i < 8; ++i) {
                const u64* qrow = qpack + ((size_t)bh * 512 + i0 + i) * TMAX;  // uniform
                acc[i] += __popcll(qrow[2 * t2] & u.x) + __popcll(qrow[2 * t2 + 1] & u.y);
            }
        }
#pragma unroll
        for (int i = 0; i < 8; ++i) praw[i * 544 + j] = 0.125f * (float)acc[i];
    }
    __syncthreads();

    // ---- Phase 2: softmax (8 rows x 32 lanes), in-place normalized write
    {
        int row = tid >> 5, jc = tid & 31;
        float pv[16];
        float m = -1e30f;
#pragma unroll
        for (int s = 0; s < 16; ++s) {
            pv[s] = praw[row * 544 + jc + s * 32];
            m = fmaxf(m, pv[s]);
        }
#pragma unroll
        for (int o = 1; o < 32; o <<= 1) m = fmaxf(m, __shfl_xor(m, o));
        float lsum = 0.f;
#pragma unroll
        for (int s = 0; s < 16; ++s) {
            pv[s] = __expf(pv[s] - m);
            lsum += pv[s];
        }
#pragma unroll
        for (int o = 1; o < 32; o <<= 1) lsum += __shfl_xor(lsum, o);
        float inv = 1.f / lsum;
#pragma unroll
        for (int s = 0; s < 16; ++s)
            praw[row * 544 + jc + s * 32] = pv[s] * inv;   // own addresses, in place
    }
    __syncthreads();

    // ---- Phase 3: PV; wave = seg, p read row-major wave-uniform b128 -----
    float pacc[8];
#pragma unroll
    for (int i = 0; i < 8; ++i) pacc[i] = 0.f;
    {
        int seg = tid >> 6, d = tid & 63;
        const float* vcol = vmean + (size_t)bh * 512 * 64 + d;
        int jbase = seg * 128;
#pragma unroll 2
        for (int j4 = 0; j4 < 128; j4 += 4) {
            int j = jbase + j4;
            float4 p0 = *(const float4*)&praw[0 * 544 + j];
            float4 p1 = *(const float4*)&praw[1 * 544 + j];
            float4 p2 = *(const float4*)&praw[2 * 544 + j];
            float4 p3 = *(const float4*)&praw[3 * 544 + j];
            float4 p4 = *(const float4*)&praw[4 * 544 + j];
            float4 p5 = *(const float4*)&praw[5 * 544 + j];
            float4 p6 = *(const float4*)&praw[6 * 544 + j];
            float4 p7 = *(const float4*)&praw[7 * 544 + j];
            float v0 = vcol[(size_t)(j + 0) * 64];
            float v1 = vcol[(size_t)(j + 1) * 64];
            float v2 = vcol[(size_t)(j + 2) * 64];
            float v3 = vcol[(size_t)(j + 3) * 64];
            pacc[0] = fmaf(p0.x, v0, pacc[0]); pacc[0] = fmaf(p0.y, v1, pacc[0]);
            pacc[0] = fmaf(p0.z, v2, pacc[0]); pacc[0] = fmaf(p0.w, v3, pacc[0]);
            pacc[1] = fmaf(p1.x, v0, pacc[1]); pacc[1] = fmaf(p1.y, v1, pacc[1]);
            pacc[1] = fmaf(p1.z, v2, pacc[1]); pacc[1] = fmaf(p1.w, v3, pacc[1]);
            pacc[2] = fmaf(p2.x, v0, pacc[2]); pacc[2] = fmaf(p2.y, v1, pacc[2]);
            pacc[2] = fmaf(p2.z, v2, pacc[2]); pacc[2] = fmaf(p2.w, v3, pacc[2]);
            pacc[3] = fmaf(p3.x, v0, pacc[3]); pacc[3] = fmaf(p3.y, v1, pacc[3]);
            pacc[3] = fmaf(p3.z, v2, pacc[3]); pacc[3] = fmaf(p3.w, v3, pacc[3]);
            pacc[4] = fmaf(p4.x, v0, pacc[4]); pacc[4] = fmaf(p4.y, v1, pacc[4]);
            pacc[4] = fmaf(p4.z, v2, pacc[4]); pacc[4] = fmaf(p4.w, v3, pacc[4]);
            pacc[5] = fmaf(p5.x, v0, pacc[5]); pacc[5] = fmaf(p5.y, v1, pacc[5]);
            pacc[5] = fmaf(p5.z, v2, pacc[5]); pacc[5] = fmaf(p5.w, v3, pacc[5]);
            pacc[6] = fmaf(p6.x, v0, pacc[6]); pacc[6] = fmaf(p6.y, v1, pacc[6]);
            pacc[6] = fmaf(p6.z, v2, pacc[6]); pacc[6] = fmaf(p6.w, v3, pacc[6]);
            pacc[7] = fmaf(p7.x, v0, pacc[7]); pacc[7] = fmaf(p7.y, v1, pacc[7]);
            pacc[7] = fmaf(p7.z, v2, pacc[7]); pacc[7] = fmaf(p7.w, v3, pacc[7]);
        }
    }
    __syncthreads();   // protect praw before overwriting with partials

    // ---- Phase 4: partials -> praw[seg*512 + i*64 + d], reduce 4 segs ----
    {
        int seg = tid >> 6, d = tid & 63;
#pragma unroll
        for (int i = 0; i < 8; ++i) praw[seg * 512 + i * 64 + d] = pacc[i];
    }
    __syncthreads();
    {
        int i = tid >> 5, d2 = (tid & 31) * 2;
        float o0 = 0.f, o1 = 0.f;
#pragma unroll
        for (int seg = 0; seg < 4; ++seg) {
            const float2 pp = *(const float2*)&praw[seg * 512 + i * 64 + d2];
            o0 += pp.x;
            o1 += pp.y;
        }
        // fused hi/lo bf16 split of ctx
        ushort2 h2v, l2v;
        split1(o0, h2v.x, l2v.x);
        split1(o1, h2v.y, l2v.y);
        int b = bh >> 3, h = bh & 7;
        size_t off = ((size_t)(b * 512 + i0 + i)) * 512 + h * 64 + d2;
        *(ushort2*)&ctx_hi[off] = h2v;
        *(ushort2*)&ctx_lo[off] = l2v;
    }
}

// ---------------------------------------------------------------------------
extern "C" void kernel_launch(void* const* d_in, const int* in_sizes, int n_in,
                              void* d_out, int out_size, void* d_ws, size_t ws_size,
                              hipStream_t stream) {
    const float* x   = (const float*)d_in[0];
    const float* Wq  = (const float*)d_in[1];
    const float* Wk  = (const float*)d_in[2];
    const float* Wv  = (const float*)d_in[3];
    const float* Wo  = (const float*)d_in[4];
    const float* bo  = (const float*)d_in[5];
    const float* g1  = (const float*)d_in[6];
    const float* gb1 = (const float*)d_in[7];
    const float* g2  = (const float*)d_in[8];
    const float* gb2 = (const float*)d_in[9];
    const float* g3  = (const float*)d_in[10];
    const float* gb3 = (const float*)d_in[11];
    const float* c1  = (const float*)d_in[12];
    const float* cb1 = (const float*)d_in[13];
    const float* c2  = (const float*)d_in[14];
    const float* cb2 = (const float*)d_in[15];
    const float* alpha = (const float*)d_in[16];
    const float* beta  = (const float*)d_in[17];
    float* out = (float*)d_out;

    char* w = (char*)d_ws;
    float* q    = (float*)w;                         w += (size_t)BS * E_ * 4;
    float* kbuf = (float*)w;                         w += (size_t)BS * E_ * 4;  // later ctx_hi/lo
    float* vbuf = (float*)w;                         w += (size_t)BS * E_ * 4;
    int* Ti     = (int*)w;                           w += (size_t)BS * 4;
    u64* qpack  = (u64*)w;                           w += (size_t)BS * NH * TMAX * 8;  // first: x_hi
    u64* kpack  = (u64*)w;                           w += (size_t)BS * NH * TMAX * 8;  // first: x_lo
    float* vmean = (float*)w;                        w += (size_t)BS * E_ * 4;  // first: Wt_qkv hi+lo
    unsigned short* wto_hi = (unsigned short*)w;     w += (size_t)512 * 512 * 2;
    unsigned short* wto_lo = (unsigned short*)w;     w += (size_t)512 * 512 * 2;

    unsigned short* x_hi = (unsigned short*)qpack;
    unsigned short* x_lo = (unsigned short*)kpack;
    unsigned short* wtqkv_hi = (unsigned short*)vmean;
    unsigned short* wtqkv_lo = (unsigned short*)vmean + (size_t)3 * 512 * 512;
    unsigned short* ctx_hi = (unsigned short*)kbuf;          // attn writes after lif reads kbuf
    unsigned short* ctx_lo = (unsigned short*)kbuf + (size_t)BS * E_;

    // 1) split x; transpose+split all W
    xsplit_kernel<<<1024, 256, 0, stream>>>(x, x_hi, x_lo);
    wsplit_kernel<<<dim3(8, 8, 4), 256, 0, stream>>>(Wq, Wk, Wv, Wo,
                                                     wtqkv_hi, wtqkv_lo, wto_hi, wto_lo);
    // 2) qkv projections (MFMA split)
    gemm_mfma_kernel<<<dim3(8, 32, 3), 256, 0, stream>>>(x_hi, x_lo,
        wtqkv_hi, wtqkv_lo, q, nullptr, 512 * 512, BS * E_);
    // 3) windows
    mlp_gate_kernel<<<1024, 256, 0, stream>>>(x, g1, gb1, g2, gb2, g3, gb3,
                                              c1, cb1, c2, cb2, Ti);
    // 4) LIF (overwrites x_hi/lo and Wt_qkv regions - ordered after gemm)
    lif_kernel<<<dim3(4096, 3), 256, 0, stream>>>(q, kbuf, vbuf, Ti, alpha, beta,
                                                  qpack, kpack, vmean);
    // 5) attention (emits ctx hi/lo bf16 directly)
    attn_kernel<<<2048, 256, 0, stream>>>(qpack, kpack, vmean, ctx_hi, ctx_lo);
    // 6) output projection (MFMA split)
    gemm_mfma_kernel<<<dim3(8, 32, 1), 256, 0, stream>>>(ctx_hi, ctx_lo,
        wto_hi, wto_lo, out, bo, 0, 0);
}

// Round 10
// 150.092 us; speedup vs baseline: 3.8926x; 1.0832x over previous
//
#include <hip/hip_runtime.h>
#include <stdint.h>

#define BS 2048   // B*S
#define E_ 512
#define NH 8
#define HD 64
#define TMAX 20

typedef unsigned long long u64;

using bf8   = __attribute__((ext_vector_type(8))) short;          // 8 bf16
using f4a   = __attribute__((ext_vector_type(4))) float;          // 4 f32 acc
using u16x8 = __attribute__((ext_vector_type(8))) unsigned short;

// ---------------------------------------------------------------------------
// f32 <-> bf16 split helpers (RNE)
// ---------------------------------------------------------------------------
__device__ __forceinline__ unsigned short f2bf(float f) {
    unsigned u = __float_as_uint(f);
    return (unsigned short)((u + 0x7FFFu + ((u >> 16) & 1u)) >> 16);
}
__device__ __forceinline__ float bf2f(unsigned short h) {
    return __uint_as_float(((unsigned)h) << 16);
}
__device__ __forceinline__ void split1(float x, unsigned short& h, unsigned short& l) {
    h = f2bf(x);
    l = f2bf(x - bf2f(h));
}

// ---------------------------------------------------------------------------
// split x: f32 [n] -> hi/lo bf16. n = BS*E_ = 1M, grid 1024x256 (float4)
// ---------------------------------------------------------------------------
__global__ __launch_bounds__(256) void xsplit_kernel(const float* __restrict__ src,
    unsigned short* __restrict__ hi, unsigned short* __restrict__ lo)
{
    int i = blockIdx.x * 256 + threadIdx.x;
    float4 v = ((const float4*)src)[i];
    ushort4 h, l;
    split1(v.x, h.x, l.x);
    split1(v.y, h.y, l.y);
    split1(v.z, h.z, l.z);
    split1(v.w, h.w, l.w);
    ((ushort4*)hi)[i] = h;
    ((ushort4*)lo)[i] = l;
}

// ---------------------------------------------------------------------------
// transpose + split W: W[k][n] f32 -> Wt_hi/lo[n][k] bf16. grid (8,8,4) 256thr
// ---------------------------------------------------------------------------
__global__ __launch_bounds__(256) void wsplit_kernel(
    const float* __restrict__ Wq, const float* __restrict__ Wk,
    const float* __restrict__ Wv, const float* __restrict__ Wo,
    unsigned short* __restrict__ qkv_hi, unsigned short* __restrict__ qkv_lo,
    unsigned short* __restrict__ o_hi, unsigned short* __restrict__ o_lo)
{
    __shared__ float t[64][65];
    int z = blockIdx.z;
    const float* W = (z == 0) ? Wq : (z == 1) ? Wk : (z == 2) ? Wv : Wo;
    unsigned short* dhi = (z < 3) ? qkv_hi + (size_t)z * 512 * 512 : o_hi;
    unsigned short* dlo = (z < 3) ? qkv_lo + (size_t)z * 512 * 512 : o_lo;
    int k0 = blockIdx.y * 64, n0 = blockIdx.x * 64;
    int tid = threadIdx.x;
    int r = tid >> 4, c4 = (tid & 15) * 4;
#pragma unroll
    for (int j = 0; j < 4; ++j) {
        int row = r + j * 16;
        float4 v = *(const float4*)&W[(size_t)(k0 + row) * 512 + n0 + c4];
        t[row][c4 + 0] = v.x; t[row][c4 + 1] = v.y;
        t[row][c4 + 2] = v.z; t[row][c4 + 3] = v.w;
    }
    __syncthreads();
#pragma unroll
    for (int j = 0; j < 4; ++j) {
        int n = r + j * 16;
        ushort4 h, l;
        split1(t[c4 + 0][n], h.x, l.x);
        split1(t[c4 + 1][n], h.y, l.y);
        split1(t[c4 + 2][n], h.z, l.z);
        split1(t[c4 + 3][n], h.w, l.w);
        *(ushort4*)&dhi[(size_t)(n0 + n) * 512 + k0 + c4] = h;
        *(ushort4*)&dlo[(size_t)(n0 + n) * 512 + k0 + c4] = l;
    }
}

// ---------------------------------------------------------------------------
// split-bf16 MFMA GEMM (3-term): LDS-free, wave = 32x32 tile. Unchanged.
// ---------------------------------------------------------------------------
__global__ __launch_bounds__(256) void gemm_mfma_kernel(
    const unsigned short* __restrict__ Ahi, const unsigned short* __restrict__ Alo,
    const unsigned short* __restrict__ Bthi, const unsigned short* __restrict__ Btlo,
    float* __restrict__ Cbase, const float* __restrict__ bias,
    int zstride_b, int zstride_c)
{
    int z = blockIdx.z;
    const unsigned short* bh_ = Bthi + (size_t)z * zstride_b;
    const unsigned short* bl_ = Btlo + (size_t)z * zstride_b;
    float* C = Cbase + (size_t)z * zstride_c;

    int tid = threadIdx.x;
    int w = tid >> 6, lane = tid & 63;
    int lrow = lane & 15;
    int lk = (lane >> 4) * 8;
    int m0 = blockIdx.y * 64 + ((w >> 1) << 5);
    int n0 = blockIdx.x * 64 + ((w & 1) << 5);

    const size_t ar0 = (size_t)(m0 + lrow) * 512 + lk;
    const size_t ar1 = ar0 + (size_t)16 * 512;
    const size_t br0 = (size_t)(n0 + lrow) * 512 + lk;
    const size_t br1 = br0 + (size_t)16 * 512;

    f4a z4 = {0.f, 0.f, 0.f, 0.f};
    f4a a00 = z4, a01 = z4, a10 = z4, a11 = z4;

#pragma unroll 2
    for (int k0 = 0; k0 < 512; k0 += 32) {
        bf8 ah0 = *(const bf8*)&Ahi[ar0 + k0];
        bf8 ah1 = *(const bf8*)&Ahi[ar1 + k0];
        bf8 al0 = *(const bf8*)&Alo[ar0 + k0];
        bf8 al1 = *(const bf8*)&Alo[ar1 + k0];
        bf8 bh0 = *(const bf8*)&bh_[br0 + k0];
        bf8 bh1 = *(const bf8*)&bh_[br1 + k0];
        bf8 bl0 = *(const bf8*)&bl_[br0 + k0];
        bf8 bl1 = *(const bf8*)&bl_[br1 + k0];
        a00 = __builtin_amdgcn_mfma_f32_16x16x32_bf16(ah0, bh0, a00, 0, 0, 0);
        a01 = __builtin_amdgcn_mfma_f32_16x16x32_bf16(ah0, bh1, a01, 0, 0, 0);
        a10 = __builtin_amdgcn_mfma_f32_16x16x32_bf16(ah1, bh0, a10, 0, 0, 0);
        a11 = __builtin_amdgcn_mfma_f32_16x16x32_bf16(ah1, bh1, a11, 0, 0, 0);
        a00 = __builtin_amdgcn_mfma_f32_16x16x32_bf16(ah0, bl0, a00, 0, 0, 0);
        a01 = __builtin_amdgcn_mfma_f32_16x16x32_bf16(ah0, bl1, a01, 0, 0, 0);
        a10 = __builtin_amdgcn_mfma_f32_16x16x32_bf16(ah1, bl0, a10, 0, 0, 0);
        a11 = __builtin_amdgcn_mfma_f32_16x16x32_bf16(ah1, bl1, a11, 0, 0, 0);
        a00 = __builtin_amdgcn_mfma_f32_16x16x32_bf16(al0, bh0, a00, 0, 0, 0);
        a01 = __builtin_amdgcn_mfma_f32_16x16x32_bf16(al0, bh1, a01, 0, 0, 0);
        a10 = __builtin_amdgcn_mfma_f32_16x16x32_bf16(al1, bh0, a10, 0, 0, 0);
        a11 = __builtin_amdgcn_mfma_f32_16x16x32_bf16(al1, bh1, a11, 0, 0, 0);
    }

    int orow = (lane >> 4) * 4;
    int col0 = n0 + lrow, col1 = n0 + 16 + lrow;
    float b0 = bias ? bias[col0] : 0.f;
    float b1 = bias ? bias[col1] : 0.f;
#pragma unroll
    for (int r = 0; r < 4; ++r) {
        C[(size_t)(m0 + orow + r) * 512 + col0]      = a00[r] + b0;
        C[(size_t)(m0 + orow + r) * 512 + col1]      = a01[r] + b1;
        C[(size_t)(m0 + 16 + orow + r) * 512 + col0] = a10[r] + b0;
        C[(size_t)(m0 + 16 + orow + r) * 512 + col1] = a11[r] + b1;
    }
}

// ---------------------------------------------------------------------------
// Gate/complexity MLPs -> T_i. 2 tokens per 256-thread block, 1024 blocks.
// ---------------------------------------------------------------------------
__global__ __launch_bounds__(256) void mlp_gate_kernel(const float* __restrict__ x,
    const float* __restrict__ g1, const float* __restrict__ gb1,
    const float* __restrict__ g2, const float* __restrict__ gb2,
    const float* __restrict__ g3, const float* __restrict__ gb3,
    const float* __restrict__ c1, const float* __restrict__ cb1,
    const float* __restrict__ c2, const float* __restrict__ cb2,
    int* __restrict__ Ti)
{
    __shared__ __align__(16) float xsh[2][512];
    __shared__ float p1[2][4][64];
    __shared__ float h1sh[2][64];
    __shared__ float p2[2][4][32];
    __shared__ float gsh[2];
    int tid = threadIdx.x;
    int tok0 = blockIdx.x * 2;

    ((float4*)&xsh[0][0])[tid] = ((const float4*)&x[(size_t)tok0 * 512])[tid];
    __syncthreads();

    {
        int l = tid & 63, ec = tid >> 6;
        float a0 = 0.f, a1 = 0.f;
        int e0 = ec * 128;
#pragma unroll 8
        for (int t = 0; t < 128; ++t) {
            int e = e0 + t;
            float w = g1[e * 64 + l];
            a0 = fmaf(xsh[0][e], w, a0);
            a1 = fmaf(xsh[1][e], w, a1);
        }
        p1[0][ec][l] = a0;
        p1[1][ec][l] = a1;
    }
    __syncthreads();
    if (tid < 128) {
        int tok = tid >> 6, l = tid & 63;
        float h = p1[tok][0][l] + p1[tok][1][l] + p1[tok][2][l] + p1[tok][3][l] + gb1[l];
        h1sh[tok][l] = fmaxf(h, 0.f);
    }
    __syncthreads();
    {
        int m = tid & 31, g = tid >> 5, tok = g & 1, lc = g >> 1;
        float a = 0.f;
#pragma unroll
        for (int t = 0; t < 16; ++t) {
            int l = lc * 16 + t;
            a = fmaf(h1sh[tok][l], g2[l * 32 + m], a);
        }
        p2[tok][lc][m] = a;
    }
    __syncthreads();
    if (tid < 64) {
        int tok = tid >> 5, m = tid & 31;
        float h = p2[tok][0][m] + p2[tok][1][m] + p2[tok][2][m] + p2[tok][3][m] + gb2[m];
        h = fmaxf(h, 0.f);
        float v = h * g3[m];
#pragma unroll
        for (int o = 1; o < 32; o <<= 1) v += __shfl_xor(v, o);
        if (m == 0) gsh[tok] = 1.f / (1.f + expf(-(v + gb3[0])));
    }
    __syncthreads();
    {
        int m = tid & 31, g = tid >> 5, tok = g & 1, ec = g >> 1;
        float a = 0.f;
        int e0 = ec * 128;
#pragma unroll 8
        for (int t = 0; t < 128; ++t) {
            int e = e0 + t;
            a = fmaf(xsh[tok][e], c1[e * 32 + m], a);
        }
        p2[tok][ec][m] = a;
    }
    __syncthreads();
    if (tid < 64) {
        int tok = tid >> 5, m = tid & 31;
        float h = p2[tok][0][m] + p2[tok][1][m] + p2[tok][2][m] + p2[tok][3][m] + cb1[m];
        h = fmaxf(h, 0.f);
        float v = h * c2[m];
#pragma unroll
        for (int o = 1; o < 32; o <<= 1) v += __shfl_xor(v, o);
        if (m == 0) {
            float comp = 1.f / (1.f + expf(-(v + cb2[0])));
            float comb = 0.7f * gsh[tok] + 0.3f * comp;
            int t = (int)ceilf(comb * 20.f);
            t = t < 1 ? 1 : (t > 20 ? 20 : t);
            Ti[tok0 + tok] = t;
        }
    }
}

// ---------------------------------------------------------------------------
// LIF + window mask. One wave per (token, head). lane = channel within head.
// mode 0/1: bit-packed spikes. mode 2: spike COUNT as exact bf16 integer
// (the /TMAX is folded into p during attn softmax).
// ---------------------------------------------------------------------------
__global__ __launch_bounds__(256) void lif_kernel(const float* __restrict__ q,
    const float* __restrict__ k, const float* __restrict__ v,
    const int* __restrict__ Ti,
    const float* __restrict__ alphap, const float* __restrict__ betap,
    u64* __restrict__ qpack, u64* __restrict__ kpack,
    unsigned short* __restrict__ vcnt_bf16)
{
    int mode = blockIdx.y;
    const float* src = (mode == 0) ? q : (mode == 1) ? k : v;
    int w = blockIdx.x * 4 + (threadIdx.x >> 6);   // 0..16383
    int lane = threadIdx.x & 63;
    int token = w >> 3;
    int h = w & 7;
    float xin = src[(size_t)token * 512 + h * 64 + lane];
    int T = Ti[token];
    float alpha = alphap[0], beta = betap[0];
    float vm = 0.f, isyn = 0.f;
    u64 myword = 0ull;
    int cnt = 0;
#pragma unroll
    for (int t = 0; t < TMAX; ++t) {
        isyn = alpha * isyn + xin;
        vm = beta * vm + isyn;
        bool sp = vm >= 1.0f;
        if (sp) vm = 0.f;
        bool msk = sp && (t < T);
        if (mode < 2) {
            u64 word = __ballot(msk ? 1 : 0);
            if (lane == t) myword = word;
        } else {
            cnt += msk ? 1 : 0;
        }
    }
    int b = token >> 9, i = token & 511;
    size_t bh = (size_t)(b * 8 + h);
    if (mode == 0) { if (lane < TMAX) qpack[(bh * 512 + i) * TMAX + lane] = myword; }
    else if (mode == 1) { if (lane < TMAX) kpack[(bh * 512 + i) * TMAX + lane] = myword; }
    else { vcnt_bf16[(bh * 512 + i) * 64 + lane] = f2bf((float)cnt); }  // exact
}

// ---------------------------------------------------------------------------
// transpose vcnt: [bh][j][d] u16 -> vT[bh][d][j] u16. grid (8 jchunks, 32 bh).
// ---------------------------------------------------------------------------
__global__ __launch_bounds__(256) void vtrans_kernel(
    const unsigned short* __restrict__ vin, unsigned short* __restrict__ vout)
{
    __shared__ unsigned short t[64][80];   // pad 80: 16B-aligned rows
    int bh = blockIdx.y, j0 = blockIdx.x * 64;
    int tid = threadIdx.x;
    {
        int jl = tid >> 2, dc = (tid & 3) * 16;
        const unsigned short* src = vin + ((size_t)bh * 512 + j0 + jl) * 64 + dc;
        u16x8 a = *(const u16x8*)src;
        u16x8 b = *(const u16x8*)(src + 8);
#pragma unroll
        for (int k = 0; k < 8; ++k) t[dc + k][jl] = a[k];
#pragma unroll
        for (int k = 0; k < 8; ++k) t[dc + 8 + k][jl] = b[k];
    }
    __syncthreads();
    {
        int dl = tid >> 2, jc = (tid & 3) * 16;
        u16x8 o0 = *(const u16x8*)&t[dl][jc];
        u16x8 o1 = *(const u16x8*)&t[dl][jc + 8];
        unsigned short* dst = vout + ((size_t)bh * 64 + dl) * 512 + j0 + jc;
        *(u16x8*)dst = o0;
        *(u16x8*)(dst + 8) = o1;
    }
}

// ---------------------------------------------------------------------------
// attn: 256 threads (4 waves), 2048 blocks, LDS 17408 B -> 8 blocks/CU.
// Phase 1 scores with EXACT maxT clamp (q-words zero beyond T_i).
// Phase 2 softmax; writes p as bf16 [16][520] (x 0.05/lsum folded) overlaid
//         on the dead score buffer (pad 520 -> conflict-free b128 reads).
// Phase 3 PV via MFMA: wave w owns d-chunk 16; D[d][i] = sum_j V^T[d][j] p[j][i]
//         16x mfma_16x16x32_bf16, A = vT b128 global, B = p b128 LDS.
//         Garbage p rows 8-15 stay in unstored D columns (row/col isolation).
// Epilogue: fused ctx hi/lo bf16 split, ushort4 stores.
// ---------------------------------------------------------------------------
__global__ __launch_bounds__(256) void attn_kernel(
    const u64* __restrict__ qpack,
    const u64* __restrict__ kpack,
    const unsigned short* __restrict__ vT,
    const int* __restrict__ Ti,
    unsigned short* __restrict__ ctx_hi,
    unsigned short* __restrict__ ctx_lo)
{
    __shared__ __align__(16) float praw[4352];   // 17408 B (8 rows x 544 f32)
    unsigned short* pb = (unsigned short*)praw;  // overlay: p_bf16 [16][520]

    int tid = threadIdx.x;
    int bid = blockIdx.x;
    int swz = (bid & 7) * 256 + (bid >> 3);      // XCD-bijective
    int bh = swz >> 6;                 // 0..31
    int i0 = (swz & 63) << 3;          // 8-row group
    int b = bh >> 3, h = bh & 7;

    // ---- maxT over the 8 q-rows (wave-uniform scalar loads; EXACT clamp) --
    int maxT = 1;
    {
        const int* tp = Ti + b * 512 + i0;
#pragma unroll
        for (int i = 0; i < 8; ++i) maxT = max(maxT, tp[i]);
    }
    int t2max = (maxT + 1) >> 1;

    // ---- Phase 1: scores; thread owns columns j = tid, tid+256 ------------
#pragma unroll
    for (int jp = 0; jp < 2; ++jp) {
        int j = jp * 256 + tid;
        const ulonglong2* kc = (const ulonglong2*)(kpack + ((size_t)bh * 512 + j) * TMAX);
        const u64* qbase = qpack + ((size_t)bh * 512 + i0) * TMAX;   // uniform
        int acc[8];
#pragma unroll
        for (int i = 0; i < 8; ++i) acc[i] = 0;
        for (int t2 = 0; t2 < t2max; ++t2) {
            ulonglong2 u = kc[t2];
#pragma unroll
            for (int i = 0; i < 8; ++i) {
                const u64* qrow = qbase + (size_t)i * TMAX;
                acc[i] += __popcll(qrow[2 * t2] & u.x) + __popcll(qrow[2 * t2 + 1] & u.y);
            }
        }
#pragma unroll
        for (int i = 0; i < 8; ++i) praw[i * 544 + j] = 0.125f * (float)acc[i];
    }
    __syncthreads();

    // ---- Phase 2: softmax (8 rows x 32 lanes); p -> bf16 with 0.05/lsum ---
    {
        int row = tid >> 5, jc = tid & 31;
        float pv[16];
        float m = -1e30f;
#pragma unroll
        for (int s = 0; s < 16; ++s) {
            pv[s] = praw[row * 544 + jc + s * 32];
            m = fmaxf(m, pv[s]);
        }
#pragma unroll
        for (int o = 1; o < 32; o <<= 1) m = fmaxf(m, __shfl_xor(m, o));
        float lsum = 0.f;
#pragma unroll
        for (int s = 0; s < 16; ++s) {
            pv[s] = __expf(pv[s] - m);
            lsum += pv[s];
        }
#pragma unroll
        for (int o = 1; o < 32; o <<= 1) lsum += __shfl_xor(lsum, o);
        float inv = 0.05f / lsum;                  // includes the /TMAX of v_mean
        __syncthreads();   // ALL praw reads complete before pb overlay writes
#pragma unroll
        for (int s = 0; s < 16; ++s)
            pb[row * 520 + jc + s * 32] = f2bf(pv[s] * inv);
    }
    __syncthreads();

    // ---- Phase 3: PV via MFMA; wave w -> d-chunk [w*16, w*16+16) ----------
    {
        int wv = tid >> 6, lane = tid & 63;
        int d0 = wv * 16;
        const unsigned short* vrow =
            vT + ((size_t)bh * 64 + d0 + (lane & 15)) * 512 + (lane >> 4) * 8;
        const unsigned short* prow = pb + (lane & 15) * 520 + (lane >> 4) * 8;
        f4a acc = {0.f, 0.f, 0.f, 0.f};
#pragma unroll
        for (int ks = 0; ks < 16; ++ks) {
            bf8 af = *(const bf8*)(vrow + ks * 32);
            bf8 bf_ = *(const bf8*)(prow + ks * 32);
            acc = __builtin_amdgcn_mfma_f32_16x16x32_bf16(af, bf_, acc, 0, 0, 0);
        }
        // D: col = lane&15 = i (rows 0-7 valid), row = (lane>>4)*4+r = d
        int ic = lane & 15;
        if (ic < 8) {
            int dloc = d0 + (lane >> 4) * 4;
            ushort4 h4, l4;
            split1(acc[0], h4.x, l4.x);
            split1(acc[1], h4.y, l4.y);
            split1(acc[2], h4.z, l4.z);
            split1(acc[3], h4.w, l4.w);
            size_t off = ((size_t)(b * 512 + i0 + ic)) * 512 + h * 64 + dloc;
            *(ushort4*)&ctx_hi[off] = h4;
            *(ushort4*)&ctx_lo[off] = l4;
        }
    }
}

// ---------------------------------------------------------------------------
extern "C" void kernel_launch(void* const* d_in, const int* in_sizes, int n_in,
                              void* d_out, int out_size, void* d_ws, size_t ws_size,
                              hipStream_t stream) {
    const float* x   = (const float*)d_in[0];
    const float* Wq  = (const float*)d_in[1];
    const float* Wk  = (const float*)d_in[2];
    const float* Wv  = (const float*)d_in[3];
    const float* Wo  = (const float*)d_in[4];
    const float* bo  = (const float*)d_in[5];
    const float* g1  = (const float*)d_in[6];
    const float* gb1 = (const float*)d_in[7];
    const float* g2  = (const float*)d_in[8];
    const float* gb2 = (const float*)d_in[9];
    const float* g3  = (const float*)d_in[10];
    const float* gb3 = (const float*)d_in[11];
    const float* c1  = (const float*)d_in[12];
    const float* cb1 = (const float*)d_in[13];
    const float* c2  = (const float*)d_in[14];
    const float* cb2 = (const float*)d_in[15];
    const float* alpha = (const float*)d_in[16];
    const float* beta  = (const float*)d_in[17];
    float* out = (float*)d_out;

    char* w = (char*)d_ws;
    float* q    = (float*)w;                         w += (size_t)BS * E_ * 4;
    float* kbuf = (float*)w;                         w += (size_t)BS * E_ * 4;  // later ctx_hi/lo
    float* vbuf = (float*)w;                         w += (size_t)BS * E_ * 4;
    int* Ti     = (int*)w;                           w += (size_t)BS * 4;
    u64* qpack  = (u64*)w;                           w += (size_t)BS * NH * TMAX * 8;  // first: x_hi
    u64* kpack  = (u64*)w;                           w += (size_t)BS * NH * TMAX * 8;  // first: x_lo
    char* vregion = w;                               w += (size_t)BS * E_ * 4;  // wtqkv -> vcnt+vT
    unsigned short* wto_hi = (unsigned short*)w;     w += (size_t)512 * 512 * 2;
    unsigned short* wto_lo = (unsigned short*)w;     w += (size_t)512 * 512 * 2;

    unsigned short* x_hi = (unsigned short*)qpack;
    unsigned short* x_lo = (unsigned short*)kpack;
    unsigned short* wtqkv_hi = (unsigned short*)vregion;               // 1.5 MB
    unsigned short* wtqkv_lo = (unsigned short*)vregion + (size_t)3 * 512 * 512;
    unsigned short* vcnt = (unsigned short*)vregion;                   // 2 MB (after gemm)
    unsigned short* vT   = (unsigned short*)vregion + (size_t)BS * E_; // 2 MB
    unsigned short* ctx_hi = (unsigned short*)kbuf;
    unsigned short* ctx_lo = (unsigned short*)kbuf + (size_t)BS * E_;

    // 1) split x; transpose+split all W
    xsplit_kernel<<<1024, 256, 0, stream>>>(x, x_hi, x_lo);
    wsplit_kernel<<<dim3(8, 8, 4), 256, 0, stream>>>(Wq, Wk, Wv, Wo,
                                                     wtqkv_hi, wtqkv_lo, wto_hi, wto_lo);
    // 2) qkv projections (MFMA split)
    gemm_mfma_kernel<<<dim3(8, 32, 3), 256, 0, stream>>>(x_hi, x_lo,
        wtqkv_hi, wtqkv_lo, q, nullptr, 512 * 512, BS * E_);
    // 3) windows
    mlp_gate_kernel<<<1024, 256, 0, stream>>>(x, g1, gb1, g2, gb2, g3, gb3,
                                              c1, cb1, c2, cb2, Ti);
    // 4) LIF (overwrites x_hi/lo and wtqkv regions - stream-ordered after gemm)
    lif_kernel<<<dim3(4096, 3), 256, 0, stream>>>(q, kbuf, vbuf, Ti, alpha, beta,
                                                  qpack, kpack, vcnt);
    // 5) V transpose to [bh][d][j] bf16
    vtrans_kernel<<<dim3(8, 32), 256, 0, stream>>>(vcnt, vT);
    // 6) attention (emits ctx hi/lo bf16 directly)
    attn_kernel<<<2048, 256, 0, stream>>>(qpack, kpack, vT, Ti, ctx_hi, ctx_lo);
    // 7) output projection (MFMA split)
    gemm_mfma_kernel<<<dim3(8, 32, 1), 256, 0, stream>>>(ctx_hi, ctx_lo,
        wto_hi, wto_lo, out, bo, 0, 0);
}

// Round 11
// 148.455 us; speedup vs baseline: 3.9356x; 1.0110x over previous
//
#include <hip/hip_runtime.h>
#include <stdint.h>

#define BS 2048   // B*S
#define E_ 512
#define NH 8
#define HD 64
#define TMAX 20

typedef unsigned long long u64;

using bf8   = __attribute__((ext_vector_type(8))) short;          // 8 bf16
using f4a   = __attribute__((ext_vector_type(4))) float;          // 4 f32 acc
using u16x8 = __attribute__((ext_vector_type(8))) unsigned short;

// ---------------------------------------------------------------------------
// f32 <-> bf16 split helpers (RNE)
// ---------------------------------------------------------------------------
__device__ __forceinline__ unsigned short f2bf(float f) {
    unsigned u = __float_as_uint(f);
    return (unsigned short)((u + 0x7FFFu + ((u >> 16) & 1u)) >> 16);
}
__device__ __forceinline__ float bf2f(unsigned short h) {
    return __uint_as_float(((unsigned)h) << 16);
}
__device__ __forceinline__ void split1(float x, unsigned short& h, unsigned short& l) {
    h = f2bf(x);
    l = f2bf(x - bf2f(h));
}

// ---------------------------------------------------------------------------
// split x: f32 [n] -> hi/lo bf16. n = BS*E_ = 1M, grid 1024x256 (float4)
// ---------------------------------------------------------------------------
__global__ __launch_bounds__(256) void xsplit_kernel(const float* __restrict__ src,
    unsigned short* __restrict__ hi, unsigned short* __restrict__ lo)
{
    int i = blockIdx.x * 256 + threadIdx.x;
    float4 v = ((const float4*)src)[i];
    ushort4 h, l;
    split1(v.x, h.x, l.x);
    split1(v.y, h.y, l.y);
    split1(v.z, h.z, l.z);
    split1(v.w, h.w, l.w);
    ((ushort4*)hi)[i] = h;
    ((ushort4*)lo)[i] = l;
}

// ---------------------------------------------------------------------------
// transpose + split W: W[k][n] f32 -> Wt_hi/lo[n][k] bf16. grid (8,8,4) 256thr
// ---------------------------------------------------------------------------
__global__ __launch_bounds__(256) void wsplit_kernel(
    const float* __restrict__ Wq, const float* __restrict__ Wk,
    const float* __restrict__ Wv, const float* __restrict__ Wo,
    unsigned short* __restrict__ qkv_hi, unsigned short* __restrict__ qkv_lo,
    unsigned short* __restrict__ o_hi, unsigned short* __restrict__ o_lo)
{
    __shared__ float t[64][65];
    int z = blockIdx.z;
    const float* W = (z == 0) ? Wq : (z == 1) ? Wk : (z == 2) ? Wv : Wo;
    unsigned short* dhi = (z < 3) ? qkv_hi + (size_t)z * 512 * 512 : o_hi;
    unsigned short* dlo = (z < 3) ? qkv_lo + (size_t)z * 512 * 512 : o_lo;
    int k0 = blockIdx.y * 64, n0 = blockIdx.x * 64;
    int tid = threadIdx.x;
    int r = tid >> 4, c4 = (tid & 15) * 4;
#pragma unroll
    for (int j = 0; j < 4; ++j) {
        int row = r + j * 16;
        float4 v = *(const float4*)&W[(size_t)(k0 + row) * 512 + n0 + c4];
        t[row][c4 + 0] = v.x; t[row][c4 + 1] = v.y;
        t[row][c4 + 2] = v.z; t[row][c4 + 3] = v.w;
    }
    __syncthreads();
#pragma unroll
    for (int j = 0; j < 4; ++j) {
        int n = r + j * 16;
        ushort4 h, l;
        split1(t[c4 + 0][n], h.x, l.x);
        split1(t[c4 + 1][n], h.y, l.y);
        split1(t[c4 + 2][n], h.z, l.z);
        split1(t[c4 + 3][n], h.w, l.w);
        *(ushort4*)&dhi[(size_t)(n0 + n) * 512 + k0 + c4] = h;
        *(ushort4*)&dlo[(size_t)(n0 + n) * 512 + k0 + c4] = l;
    }
}

// ---------------------------------------------------------------------------
// split-bf16 MFMA GEMM (3-term), LDS-free, wave = 32x32 tile, with DEPTH-2
// register prefetch: fragments for k and k+32 live in regs; k+64's loads are
// issued before k's 12 MFMAs -> ~2 MFMA phases + TLP hide L2 latency.
// ---------------------------------------------------------------------------
struct Frags {
    bf8 ah0, ah1, al0, al1, bh0, bh1, bl0, bl1;
};

__device__ __forceinline__ Frags ldf(
    const unsigned short* __restrict__ Ahi, const unsigned short* __restrict__ Alo,
    const unsigned short* __restrict__ bh_, const unsigned short* __restrict__ bl_,
    size_t ar0, size_t ar1, size_t br0, size_t br1, int k0)
{
    Frags f;
    f.ah0 = *(const bf8*)&Ahi[ar0 + k0];
    f.ah1 = *(const bf8*)&Ahi[ar1 + k0];
    f.al0 = *(const bf8*)&Alo[ar0 + k0];
    f.al1 = *(const bf8*)&Alo[ar1 + k0];
    f.bh0 = *(const bf8*)&bh_[br0 + k0];
    f.bh1 = *(const bf8*)&bh_[br1 + k0];
    f.bl0 = *(const bf8*)&bl_[br0 + k0];
    f.bl1 = *(const bf8*)&bl_[br1 + k0];
    return f;
}

__device__ __forceinline__ void domfma(const Frags& f,
    f4a& a00, f4a& a01, f4a& a10, f4a& a11)
{
    a00 = __builtin_amdgcn_mfma_f32_16x16x32_bf16(f.ah0, f.bh0, a00, 0, 0, 0);
    a01 = __builtin_amdgcn_mfma_f32_16x16x32_bf16(f.ah0, f.bh1, a01, 0, 0, 0);
    a10 = __builtin_amdgcn_mfma_f32_16x16x32_bf16(f.ah1, f.bh0, a10, 0, 0, 0);
    a11 = __builtin_amdgcn_mfma_f32_16x16x32_bf16(f.ah1, f.bh1, a11, 0, 0, 0);
    a00 = __builtin_amdgcn_mfma_f32_16x16x32_bf16(f.ah0, f.bl0, a00, 0, 0, 0);
    a01 = __builtin_amdgcn_mfma_f32_16x16x32_bf16(f.ah0, f.bl1, a01, 0, 0, 0);
    a10 = __builtin_amdgcn_mfma_f32_16x16x32_bf16(f.ah1, f.bl0, a10, 0, 0, 0);
    a11 = __builtin_amdgcn_mfma_f32_16x16x32_bf16(f.ah1, f.bl1, a11, 0, 0, 0);
    a00 = __builtin_amdgcn_mfma_f32_16x16x32_bf16(f.al0, f.bh0, a00, 0, 0, 0);
    a01 = __builtin_amdgcn_mfma_f32_16x16x32_bf16(f.al0, f.bh1, a01, 0, 0, 0);
    a10 = __builtin_amdgcn_mfma_f32_16x16x32_bf16(f.al1, f.bh0, a10, 0, 0, 0);
    a11 = __builtin_amdgcn_mfma_f32_16x16x32_bf16(f.al1, f.bh1, a11, 0, 0, 0);
}

__global__ __launch_bounds__(256) void gemm_mfma_kernel(
    const unsigned short* __restrict__ Ahi, const unsigned short* __restrict__ Alo,
    const unsigned short* __restrict__ Bthi, const unsigned short* __restrict__ Btlo,
    float* __restrict__ Cbase, const float* __restrict__ bias,
    int zstride_b, int zstride_c)
{
    int z = blockIdx.z;
    const unsigned short* bh_ = Bthi + (size_t)z * zstride_b;
    const unsigned short* bl_ = Btlo + (size_t)z * zstride_b;
    float* C = Cbase + (size_t)z * zstride_c;

    int tid = threadIdx.x;
    int w = tid >> 6, lane = tid & 63;
    int lrow = lane & 15;
    int lk = (lane >> 4) * 8;
    int m0 = blockIdx.y * 64 + ((w >> 1) << 5);
    int n0 = blockIdx.x * 64 + ((w & 1) << 5);

    const size_t ar0 = (size_t)(m0 + lrow) * 512 + lk;
    const size_t ar1 = ar0 + (size_t)16 * 512;
    const size_t br0 = (size_t)(n0 + lrow) * 512 + lk;
    const size_t br1 = br0 + (size_t)16 * 512;

    f4a z4 = {0.f, 0.f, 0.f, 0.f};
    f4a a00 = z4, a01 = z4, a10 = z4, a11 = z4;

    Frags f0 = ldf(Ahi, Alo, bh_, bl_, ar0, ar1, br0, br1, 0);
    Frags f1 = ldf(Ahi, Alo, bh_, bl_, ar0, ar1, br0, br1, 32);
#pragma unroll 1
    for (int k0 = 0; k0 < 512 - 64; k0 += 32) {
        Frags fn = ldf(Ahi, Alo, bh_, bl_, ar0, ar1, br0, br1, k0 + 64);
        domfma(f0, a00, a01, a10, a11);
        f0 = f1;
        f1 = fn;
    }
    domfma(f0, a00, a01, a10, a11);
    domfma(f1, a00, a01, a10, a11);

    int orow = (lane >> 4) * 4;
    int col0 = n0 + lrow, col1 = n0 + 16 + lrow;
    float b0 = bias ? bias[col0] : 0.f;
    float b1 = bias ? bias[col1] : 0.f;
#pragma unroll
    for (int r = 0; r < 4; ++r) {
        C[(size_t)(m0 + orow + r) * 512 + col0]      = a00[r] + b0;
        C[(size_t)(m0 + orow + r) * 512 + col1]      = a01[r] + b1;
        C[(size_t)(m0 + 16 + orow + r) * 512 + col0] = a10[r] + b0;
        C[(size_t)(m0 + 16 + orow + r) * 512 + col1] = a11[r] + b1;
    }
}

// ---------------------------------------------------------------------------
// Gate/complexity MLPs -> T_i. 2 tokens per 256-thread block, 1024 blocks.
// ---------------------------------------------------------------------------
__global__ __launch_bounds__(256) void mlp_gate_kernel(const float* __restrict__ x,
    const float* __restrict__ g1, const float* __restrict__ gb1,
    const float* __restrict__ g2, const float* __restrict__ gb2,
    const float* __restrict__ g3, const float* __restrict__ gb3,
    const float* __restrict__ c1, const float* __restrict__ cb1,
    const float* __restrict__ c2, const float* __restrict__ cb2,
    int* __restrict__ Ti)
{
    __shared__ __align__(16) float xsh[2][512];
    __shared__ float p1[2][4][64];
    __shared__ float h1sh[2][64];
    __shared__ float p2[2][4][32];
    __shared__ float gsh[2];
    int tid = threadIdx.x;
    int tok0 = blockIdx.x * 2;

    ((float4*)&xsh[0][0])[tid] = ((const float4*)&x[(size_t)tok0 * 512])[tid];
    __syncthreads();

    {
        int l = tid & 63, ec = tid >> 6;
        float a0 = 0.f, a1 = 0.f;
        int e0 = ec * 128;
#pragma unroll 8
        for (int t = 0; t < 128; ++t) {
            int e = e0 + t;
            float w = g1[e * 64 + l];
            a0 = fmaf(xsh[0][e], w, a0);
            a1 = fmaf(xsh[1][e], w, a1);
        }
        p1[0][ec][l] = a0;
        p1[1][ec][l] = a1;
    }
    __syncthreads();
    if (tid < 128) {
        int tok = tid >> 6, l = tid & 63;
        float h = p1[tok][0][l] + p1[tok][1][l] + p1[tok][2][l] + p1[tok][3][l] + gb1[l];
        h1sh[tok][l] = fmaxf(h, 0.f);
    }
    __syncthreads();
    {
        int m = tid & 31, g = tid >> 5, tok = g & 1, lc = g >> 1;
        float a = 0.f;
#pragma unroll
        for (int t = 0; t < 16; ++t) {
            int l = lc * 16 + t;
            a = fmaf(h1sh[tok][l], g2[l * 32 + m], a);
        }
        p2[tok][lc][m] = a;
    }
    __syncthreads();
    if (tid < 64) {
        int tok = tid >> 5, m = tid & 31;
        float h = p2[tok][0][m] + p2[tok][1][m] + p2[tok][2][m] + p2[tok][3][m] + gb2[m];
        h = fmaxf(h, 0.f);
        float v = h * g3[m];
#pragma unroll
        for (int o = 1; o < 32; o <<= 1) v += __shfl_xor(v, o);
        if (m == 0) gsh[tok] = 1.f / (1.f + expf(-(v + gb3[0])));
    }
    __syncthreads();
    {
        int m = tid & 31, g = tid >> 5, tok = g & 1, ec = g >> 1;
        float a = 0.f;
        int e0 = ec * 128;
#pragma unroll 8
        for (int t = 0; t < 128; ++t) {
            int e = e0 + t;
            a = fmaf(xsh[tok][e], c1[e * 32 + m], a);
        }
        p2[tok][ec][m] = a;
    }
    __syncthreads();
    if (tid < 64) {
        int tok = tid >> 5, m = tid & 31;
        float h = p2[tok][0][m] + p2[tok][1][m] + p2[tok][2][m] + p2[tok][3][m] + cb1[m];
        h = fmaxf(h, 0.f);
        float v = h * c2[m];
#pragma unroll
        for (int o = 1; o < 32; o <<= 1) v += __shfl_xor(v, o);
        if (m == 0) {
            float comp = 1.f / (1.f + expf(-(v + cb2[0])));
            float comb = 0.7f * gsh[tok] + 0.3f * comp;
            int t = (int)ceilf(comb * 20.f);
            t = t < 1 ? 1 : (t > 20 ? 20 : t);
            Ti[tok0 + tok] = t;
        }
    }
}

// ---------------------------------------------------------------------------
// LIF + window mask. One wave per (token, head). lane = channel within head.
// ---------------------------------------------------------------------------
__global__ __launch_bounds__(256) void lif_kernel(const float* __restrict__ q,
    const float* __restrict__ k, const float* __restrict__ v,
    const int* __restrict__ Ti,
    const float* __restrict__ alphap, const float* __restrict__ betap,
    u64* __restrict__ qpack, u64* __restrict__ kpack,
    unsigned short* __restrict__ vcnt_bf16)
{
    int mode = blockIdx.y;
    const float* src = (mode == 0) ? q : (mode == 1) ? k : v;
    int w = blockIdx.x * 4 + (threadIdx.x >> 6);   // 0..16383
    int lane = threadIdx.x & 63;
    int token = w >> 3;
    int h = w & 7;
    float xin = src[(size_t)token * 512 + h * 64 + lane];
    int T = Ti[token];
    float alpha = alphap[0], beta = betap[0];
    float vm = 0.f, isyn = 0.f;
    u64 myword = 0ull;
    int cnt = 0;
#pragma unroll
    for (int t = 0; t < TMAX; ++t) {
        isyn = alpha * isyn + xin;
        vm = beta * vm + isyn;
        bool sp = vm >= 1.0f;
        if (sp) vm = 0.f;
        bool msk = sp && (t < T);
        if (mode < 2) {
            u64 word = __ballot(msk ? 1 : 0);
            if (lane == t) myword = word;
        } else {
            cnt += msk ? 1 : 0;
        }
    }
    int b = token >> 9, i = token & 511;
    size_t bh = (size_t)(b * 8 + h);
    if (mode == 0) { if (lane < TMAX) qpack[(bh * 512 + i) * TMAX + lane] = myword; }
    else if (mode == 1) { if (lane < TMAX) kpack[(bh * 512 + i) * TMAX + lane] = myword; }
    else { vcnt_bf16[(bh * 512 + i) * 64 + lane] = f2bf((float)cnt); }  // exact
}

// ---------------------------------------------------------------------------
// transpose vcnt: [bh][j][d] u16 -> vT[bh][d][j] u16. grid (8 jchunks, 32 bh).
// ---------------------------------------------------------------------------
__global__ __launch_bounds__(256) void vtrans_kernel(
    const unsigned short* __restrict__ vin, unsigned short* __restrict__ vout)
{
    __shared__ unsigned short t[64][80];   // pad 80: 16B-aligned rows
    int bh = blockIdx.y, j0 = blockIdx.x * 64;
    int tid = threadIdx.x;
    {
        int jl = tid >> 2, dc = (tid & 3) * 16;
        const unsigned short* src = vin + ((size_t)bh * 512 + j0 + jl) * 64 + dc;
        u16x8 a = *(const u16x8*)src;
        u16x8 b = *(const u16x8*)(src + 8);
#pragma unroll
        for (int k = 0; k < 8; ++k) t[dc + k][jl] = a[k];
#pragma unroll
        for (int k = 0; k < 8; ++k) t[dc + 8 + k][jl] = b[k];
    }
    __syncthreads();
    {
        int dl = tid >> 2, jc = (tid & 3) * 16;
        u16x8 o0 = *(const u16x8*)&t[dl][jc];
        u16x8 o1 = *(const u16x8*)&t[dl][jc + 8];
        unsigned short* dst = vout + ((size_t)bh * 64 + dl) * 512 + j0 + jc;
        *(u16x8*)dst = o0;
        *(u16x8*)(dst + 8) = o1;
    }
}

// ---------------------------------------------------------------------------
// attn: 256 threads (4 waves), 2048 blocks, LDS 17408 B -> 8 blocks/CU.
// (unchanged from round 9)
// ---------------------------------------------------------------------------
__global__ __launch_bounds__(256) void attn_kernel(
    const u64* __restrict__ qpack,
    const u64* __restrict__ kpack,
    const unsigned short* __restrict__ vT,
    const int* __restrict__ Ti,
    unsigned short* __restrict__ ctx_hi,
    unsigned short* __restrict__ ctx_lo)
{
    __shared__ __align__(16) float praw[4352];   // 17408 B (8 rows x 544 f32)
    unsigned short* pb = (unsigned short*)praw;  // overlay: p_bf16 [16][520]

    int tid = threadIdx.x;
    int bid = blockIdx.x;
    int swz = (bid & 7) * 256 + (bid >> 3);      // XCD-bijective
    int bh = swz >> 6;                 // 0..31
    int i0 = (swz & 63) << 3;          // 8-row group
    int b = bh >> 3, h = bh & 7;

    // ---- maxT over the 8 q-rows (wave-uniform scalar loads; EXACT clamp) --
    int maxT = 1;
    {
        const int* tp = Ti + b * 512 + i0;
#pragma unroll
        for (int i = 0; i < 8; ++i) maxT = max(maxT, tp[i]);
    }
    int t2max = (maxT + 1) >> 1;

    // ---- Phase 1: scores; thread owns columns j = tid, tid+256 ------------
#pragma unroll
    for (int jp = 0; jp < 2; ++jp) {
        int j = jp * 256 + tid;
        const ulonglong2* kc = (const ulonglong2*)(kpack + ((size_t)bh * 512 + j) * TMAX);
        const u64* qbase = qpack + ((size_t)bh * 512 + i0) * TMAX;   // uniform
        int acc[8];
#pragma unroll
        for (int i = 0; i < 8; ++i) acc[i] = 0;
        for (int t2 = 0; t2 < t2max; ++t2) {
            ulonglong2 u = kc[t2];
#pragma unroll
            for (int i = 0; i < 8; ++i) {
                const u64* qrow = qbase + (size_t)i * TMAX;
                acc[i] += __popcll(qrow[2 * t2] & u.x) + __popcll(qrow[2 * t2 + 1] & u.y);
            }
        }
#pragma unroll
        for (int i = 0; i < 8; ++i) praw[i * 544 + j] = 0.125f * (float)acc[i];
    }
    __syncthreads();

    // ---- Phase 2: softmax (8 rows x 32 lanes); p -> bf16 with 0.05/lsum ---
    {
        int row = tid >> 5, jc = tid & 31;
        float pv[16];
        float m = -1e30f;
#pragma unroll
        for (int s = 0; s < 16; ++s) {
            pv[s] = praw[row * 544 + jc + s * 32];
            m = fmaxf(m, pv[s]);
        }
#pragma unroll
        for (int o = 1; o < 32; o <<= 1) m = fmaxf(m, __shfl_xor(m, o));
        float lsum = 0.f;
#pragma unroll
        for (int s = 0; s < 16; ++s) {
            pv[s] = __expf(pv[s] - m);
            lsum += pv[s];
        }
#pragma unroll
        for (int o = 1; o < 32; o <<= 1) lsum += __shfl_xor(lsum, o);
        float inv = 0.05f / lsum;                  // includes the /TMAX of v_mean
        __syncthreads();   // ALL praw reads complete before pb overlay writes
#pragma unroll
        for (int s = 0; s < 16; ++s)
            pb[row * 520 + jc + s * 32] = f2bf(pv[s] * inv);
    }
    __syncthreads();

    // ---- Phase 3: PV via MFMA; wave w -> d-chunk [w*16, w*16+16) ----------
    {
        int wv = tid >> 6, lane = tid & 63;
        int d0 = wv * 16;
        const unsigned short* vrow =
            vT + ((size_t)bh * 64 + d0 + (lane & 15)) * 512 + (lane >> 4) * 8;
        const unsigned short* prow = pb + (lane & 15) * 520 + (lane >> 4) * 8;
        f4a acc = {0.f, 0.f, 0.f, 0.f};
#pragma unroll
        for (int ks = 0; ks < 16; ++ks) {
            bf8 af = *(const bf8*)(vrow + ks * 32);
            bf8 bf_ = *(const bf8*)(prow + ks * 32);
            acc = __builtin_amdgcn_mfma_f32_16x16x32_bf16(af, bf_, acc, 0, 0, 0);
        }
        // D: col = lane&15 = i (rows 0-7 valid), row = (lane>>4)*4+r = d
        int ic = lane & 15;
        if (ic < 8) {
            int dloc = d0 + (lane >> 4) * 4;
            ushort4 h4, l4;
            split1(acc[0], h4.x, l4.x);
            split1(acc[1], h4.y, l4.y);
            split1(acc[2], h4.z, l4.z);
            split1(acc[3], h4.w, l4.w);
            size_t off = ((size_t)(b * 512 + i0 + ic)) * 512 + h * 64 + dloc;
            *(ushort4*)&ctx_hi[off] = h4;
            *(ushort4*)&ctx_lo[off] = l4;
        }
    }
}

// ---------------------------------------------------------------------------
extern "C" void kernel_launch(void* const* d_in, const int* in_sizes, int n_in,
                              void* d_out, int out_size, void* d_ws, size_t ws_size,
                              hipStream_t stream) {
    const float* x   = (const float*)d_in[0];
    const float* Wq  = (const float*)d_in[1];
    const float* Wk  = (const float*)d_in[2];
    const float* Wv  = (const float*)d_in[3];
    const float* Wo  = (const float*)d_in[4];
    const float* bo  = (const float*)d_in[5];
    const float* g1  = (const float*)d_in[6];
    const float* gb1 = (const float*)d_in[7];
    const float* g2  = (const float*)d_in[8];
    const float* gb2 = (const float*)d_in[9];
    const float* g3  = (const float*)d_in[10];
    const float* gb3 = (const float*)d_in[11];
    const float* c1  = (const float*)d_in[12];
    const float* cb1 = (const float*)d_in[13];
    const float* c2  = (const float*)d_in[14];
    const float* cb2 = (const float*)d_in[15];
    const float* alpha = (const float*)d_in[16];
    const float* beta  = (const float*)d_in[17];
    float* out = (float*)d_out;

    char* w = (char*)d_ws;
    float* q    = (float*)w;                         w += (size_t)BS * E_ * 4;
    float* kbuf = (float*)w;                         w += (size_t)BS * E_ * 4;  // later ctx_hi/lo
    float* vbuf = (float*)w;                         w += (size_t)BS * E_ * 4;
    int* Ti     = (int*)w;                           w += (size_t)BS * 4;
    u64* qpack  = (u64*)w;                           w += (size_t)BS * NH * TMAX * 8;  // first: x_hi
    u64* kpack  = (u64*)w;                           w += (size_t)BS * NH * TMAX * 8;  // first: x_lo
    char* vregion = w;                               w += (size_t)BS * E_ * 4;  // wtqkv -> vcnt+vT
    unsigned short* wto_hi = (unsigned short*)w;     w += (size_t)512 * 512 * 2;
    unsigned short* wto_lo = (unsigned short*)w;     w += (size_t)512 * 512 * 2;

    unsigned short* x_hi = (unsigned short*)qpack;
    unsigned short* x_lo = (unsigned short*)kpack;
    unsigned short* wtqkv_hi = (unsigned short*)vregion;               // 1.5 MB
    unsigned short* wtqkv_lo = (unsigned short*)vregion + (size_t)3 * 512 * 512;
    unsigned short* vcnt = (unsigned short*)vregion;                   // 2 MB (after gemm)
    unsigned short* vT   = (unsigned short*)vregion + (size_t)BS * E_; // 2 MB
    unsigned short* ctx_hi = (unsigned short*)kbuf;
    unsigned short* ctx_lo = (unsigned short*)kbuf + (size_t)BS * E_;

    // 1) split x; transpose+split all W
    xsplit_kernel<<<1024, 256, 0, stream>>>(x, x_hi, x_lo);
    wsplit_kernel<<<dim3(8, 8, 4), 256, 0, stream>>>(Wq, Wk, Wv, Wo,
                                                     wtqkv_hi, wtqkv_lo, wto_hi, wto_lo);
    // 2) qkv projections (MFMA split, depth-2 prefetch)
    gemm_mfma_kernel<<<dim3(8, 32, 3), 256, 0, stream>>>(x_hi, x_lo,
        wtqkv_hi, wtqkv_lo, q, nullptr, 512 * 512, BS * E_);
    // 3) windows
    mlp_gate_kernel<<<1024, 256, 0, stream>>>(x, g1, gb1, g2, gb2, g3, gb3,
                                              c1, cb1, c2, cb2, Ti);
    // 4) LIF (overwrites x_hi/lo and wtqkv regions - stream-ordered after gemm)
    lif_kernel<<<dim3(4096, 3), 256, 0, stream>>>(q, kbuf, vbuf, Ti, alpha, beta,
                                                  qpack, kpack, vcnt);
    // 5) V transpose to [bh][d][j] bf16
    vtrans_kernel<<<dim3(8, 32), 256, 0, stream>>>(vcnt, vT);
    // 6) attention (emits ctx hi/lo bf16 directly)
    attn_kernel<<<2048, 256, 0, stream>>>(qpack, kpack, vT, Ti, ctx_hi, ctx_lo);
    // 7) output projection (MFMA split, depth-2 prefetch)
    gemm_mfma_kernel<<<dim3(8, 32, 1), 256, 0, stream>>>(ctx_hi, ctx_lo,
        wto_hi, wto_lo, out, bo, 0, 0);
}